// Round 3
// baseline (3770.391 us; speedup 1.0000x reference)
//
#include <hip/hip_runtime.h>
#include <cstdint>
#include <cstddef>

namespace {
constexpr int B_ = 16;
constexpr int N_ = 4096;
constexpr int D_ = 64;
constexpr int M_ = 1024;
constexpr int S_ = 32;
constexpr int NROWS_ = B_ * M_ * S_;   // 524288
constexpr int NBLK_ = NROWS_ / 256;    // 2048
constexpr float RR_ = 0.04f;           // radius^2 in f32

// ws offsets (bytes)
constexpr size_t OFF_SQN  = 0;                               // B*N*4      = 262144
constexpr size_t OFF_FPS  = 262144;                          // B*M*4      = 65536
constexpr size_t OFF_BALL = 327680;                          // B*M*S*4    = 2097152
constexpr size_t OFF_W0T  = 2424832;                         // 67*64*4    = 17152
constexpr size_t OFF_W1T  = OFF_W0T + 67 * 64 * 4;           // 64*64*4    = 16384
constexpr size_t OFF_W2T  = OFF_W1T + 64 * 64 * 4;           // 64*128*4   = 32768
constexpr size_t OFF_PART = OFF_W2T + 64 * 128 * 4;          // 2048*256*4 = 2097152
constexpr size_t OFF_BNP  = OFF_PART + (size_t)NBLK_ * 256 * 4; // 3*256*4 = 3072
}

// multiply with result pinned to a VGPR: blocks FMA contraction so we match
// numpy's individually-rounded  a*b  then separate add (ufunc-separated paths).
__device__ __forceinline__ float mul_nf(float a, float b) {
    float p = a * b;
    asm volatile("" : "+v"(p));
    return p;
}

// ---------------------------------------------------------------- sqnorm
__global__ __launch_bounds__(256) void k_sqnorm(const float* __restrict__ xyz,
                                                float* __restrict__ sqn) {
    int i = blockIdx.x * 256 + threadIdx.x;
    if (i >= B_ * N_) return;
    float x = xyz[3 * i], y = xyz[3 * i + 1], z = xyz[3 * i + 2];
    // np: square ufunc then separate sum reduce -> no FMA, forward order
    sqn[i] = (mul_nf(x, x) + mul_nf(y, y)) + mul_nf(z, z);
}

// ---------------------------------------------------------------- FPS
// one block per batch; 256 threads; each thread owns 16 strided points in regs.
// (bitwise-verified vs reference: separate square + forward sum, no FMA)
__global__ __launch_bounds__(256) void k_fps(const float* __restrict__ xyz,
                                             int* __restrict__ fps_idx) {
    const int b = blockIdx.x;
    const int t = threadIdx.x;
    const int lane = t & 63, w = t >> 6;
    const float* xb = xyz + (size_t)b * N_ * 3;

    float px[16], py[16], pz[16], dist[16];
#pragma unroll
    for (int k = 0; k < 16; k++) {
        int n = t + (k << 8);
        px[k] = xb[3 * n]; py[k] = xb[3 * n + 1]; pz[k] = xb[3 * n + 2];
        dist[k] = 1e10f;
    }
    __shared__ float bv[4]; __shared__ int bi[4];
    __shared__ float cx, cy, cz;
    int far = 0;
    if (t == 0) { cx = px[0]; cy = py[0]; cz = pz[0]; }
    __syncthreads();

    for (int i = 0; i < M_; i++) {
        if (t == 0) fps_idx[b * M_ + i] = far;   // scan emits farthest BEFORE update
        const float c0 = cx, c1 = cy, c2 = cz;
        float bestv = -1.0f; int besti = 0;
#pragma unroll
        for (int k = 0; k < 16; k++) {
            float d0 = px[k] - c0, d1 = py[k] - c1, d2 = pz[k] - c2;
            float dd = (mul_nf(d0, d0) + mul_nf(d1, d1)) + mul_nf(d2, d2);
            float dm = fminf(dist[k], dd);
            dist[k] = dm;
            int n = t + (k << 8);
            if (dm > bestv || (dm == bestv && n < besti)) { bestv = dm; besti = n; }
        }
        // wave allreduce (value, first-index tie-break)
#pragma unroll
        for (int off = 32; off >= 1; off >>= 1) {
            float ov = __shfl_xor(bestv, off);
            int   oi = __shfl_xor(besti, off);
            if (ov > bestv || (ov == bestv && oi < besti)) { bestv = ov; besti = oi; }
        }
        if (lane == 0) { bv[w] = bestv; bi[w] = besti; }
        __syncthreads();
        float fv = bv[0]; int fi = bi[0];
#pragma unroll
        for (int ww = 1; ww < 4; ww++) {
            float ov = bv[ww]; int oi = bi[ww];
            if (ov > fv || (ov == fv && oi < fi)) { fv = ov; fi = oi; }
        }
        far = fi;
        // owner thread publishes the new centroid's coords
        if ((far & 255) == t) {
            const int kk = far >> 8;
            float sx = px[0], sy = py[0], sz = pz[0];
#pragma unroll
            for (int k = 1; k < 16; k++) {
                bool e = (kk == k);
                sx = e ? px[k] : sx; sy = e ? py[k] : sy; sz = e ? pz[k] : sz;
            }
            cx = sx; cy = sy; cz = sz;
        }
        __syncthreads();
    }
}

// ---------------------------------------------------------------- gather new_xyz
__global__ __launch_bounds__(256) void k_newxyz(const float* __restrict__ xyz,
                                                const int* __restrict__ fps_idx,
                                                float* __restrict__ newxyz) {
    int i = blockIdx.x * 256 + threadIdx.x;
    if (i >= B_ * M_) return;
    int b = i >> 10;
    int f = fps_idx[i];
    const float* p = xyz + ((size_t)b * N_ + f) * 3;
    newxyz[3 * i] = p[0]; newxyz[3 * i + 1] = p[1]; newxyz[3 * i + 2] = p[2];
}

// ---------------------------------------------------------------- ball query
// one wave per query; scan points in index order, keep first 32 inside radius.
// einsum inner loop compiles with fp-contract: ascending FMA chain
//   acc = fma(q2,p2, fma(q1,p1, fl(q0*p0)))
__global__ __launch_bounds__(256) void k_ball(const float* __restrict__ xyz,
                                              const float* __restrict__ sqn,
                                              const int* __restrict__ fps_idx,
                                              const float* __restrict__ newxyz,
                                              int* __restrict__ ball) {
    const int w = threadIdx.x >> 6, lane = threadIdx.x & 63;
    const int q = blockIdx.x * 4 + w;       // 0..16383
    const int b = q >> 10;
    __shared__ int buf[4][32];
    const float* xb = xyz + (size_t)b * N_ * 3;
    const float* sb = sqn + (size_t)b * N_;
    const float q0 = newxyz[3 * q], q1 = newxyz[3 * q + 1], q2 = newxyz[3 * q + 2];
    const float sq = sb[fps_idx[q]];        // same bits as sum(new_xyz**2)

    int cnt = 0;
    for (int base = 0; base < N_ && cnt < 32; base += 64) {
        const int n = base + lane;
        const float p0 = xb[3 * n], p1 = xb[3 * n + 1], p2 = xb[3 * n + 2];
        // ascending FMA accumulation (k=0 product rounded once, then fma k=1, k=2)
        float dot = fmaf(q2, p2, fmaf(q1, p1, q0 * p0));
        float tt = -2.0f * dot;   // exact scaling (power of 2)
        tt = tt + sq;             // + sum(src^2)
        tt = tt + sb[n];          // + sum(dst^2)
        const bool pred = !(tt > RR_);      // include iff sqr <= r^2
        const unsigned long long mask = __ballot(pred);
        const int pos = cnt + __popcll(mask & ((1ull << lane) - 1ull));
        if (pred && pos < 32) buf[w][pos] = n;
        cnt += (int)__popcll(mask);
    }
    __syncthreads();
    if (lane < 32) {
        int e = buf[w][(lane < cnt) ? lane : 0];   // pad with first
        ball[(size_t)q * 32 + lane] = e;
    }
}

// ---------------------------------------------------------------- weight transpose
__global__ __launch_bounds__(256) void k_wtrans(const float* __restrict__ W0,
                                                const float* __restrict__ W1,
                                                const float* __restrict__ W2,
                                                float* __restrict__ W0T,
                                                float* __restrict__ W1T,
                                                float* __restrict__ W2T) {
    int t = blockIdx.x * 256 + threadIdx.x;
    if (t < 64 * 67) { int o = t / 67, c = t % 67; W0T[c * 64 + o] = W0[t]; }
    if (t < 64 * 64) { int o = t / 64, c = t % 64; W1T[c * 64 + o] = W1[t]; }
    if (t < 128 * 64) { int o = t / 64, c = t % 64; W2T[c * 128 + o] = W2[t]; }
}

// ---------------------------------------------------------------- MLP stages
template <int STAGE>
__global__ __launch_bounds__(256) void k_mlp(
    const float* __restrict__ points, const float* __restrict__ xyz,
    const float* __restrict__ newxyz, const int* __restrict__ ball,
    const float* __restrict__ W0T, const float* __restrict__ W1T,
    const float* __restrict__ W2T, const float* __restrict__ bnp,
    float* __restrict__ partials, float* __restrict__ out_np) {
    const int r = blockIdx.x * 256 + threadIdx.x;
    const int lane = threadIdx.x & 63;
    const int w = threadIdx.x >> 6;
    const int b = r >> 15;
    const int q = r >> 5;          // b*M + m
    const int s = r & 31;
    const int g = ball[r];
    const float* prow = points + ((size_t)(b * N_) + g) * D_;
    const float xg0 = xyz[((size_t)b * N_ + g) * 3 + 0] - newxyz[(size_t)q * 3 + 0];
    const float xg1 = xyz[((size_t)b * N_ + g) * 3 + 1] - newxyz[(size_t)q * 3 + 1];
    const float xg2 = xyz[((size_t)b * N_ + g) * 3 + 2] - newxyz[(size_t)q * 3 + 2];

    float h0[64];
#pragma unroll
    for (int o = 0; o < 64; o++) h0[o] = 0.f;
    for (int c = 0; c < 64; c += 4) {
        const float4 xv = *reinterpret_cast<const float4*>(prow + c);
        const float xs[4] = {xv.x, xv.y, xv.z, xv.w};
#pragma unroll
        for (int j = 0; j < 4; j++) {
            const float xc = xs[j];
            const float* wr = W0T + (c + j) * 64;
#pragma unroll
            for (int o = 0; o < 64; o++) h0[o] = fmaf(xc, wr[o], h0[o]);
        }
    }
    {
        const float* wa = W0T + 64 * 64;
        const float* wb = W0T + 65 * 64;
        const float* wc = W0T + 66 * 64;
#pragma unroll
        for (int o = 0; o < 64; o++) h0[o] = fmaf(xg0, wa[o], h0[o]);
#pragma unroll
        for (int o = 0; o < 64; o++) h0[o] = fmaf(xg1, wb[o], h0[o]);
#pragma unroll
        for (int o = 0; o < 64; o++) h0[o] = fmaf(xg2, wc[o], h0[o]);
    }

    if constexpr (STAGE == 0) {
        __shared__ float ls[256], lq[256];
        float rs = 0.f, rq = 0.f;
        for (int c = 0; c < 64; c++) {
            float sv = h0[c], qv = h0[c] * h0[c];
#pragma unroll
            for (int off = 32; off >= 1; off >>= 1) {
                sv += __shfl_xor(sv, off); qv += __shfl_xor(qv, off);
            }
            if (lane == c) { rs = sv; rq = qv; }
        }
        ls[w * 64 + lane] = rs; lq[w * 64 + lane] = rq;
        __syncthreads();
        if (threadIdx.x < 64) {
            const int t = threadIdx.x;
            partials[(size_t)blockIdx.x * 256 + t] = ls[t] + ls[64 + t] + ls[128 + t] + ls[192 + t];
            partials[(size_t)blockIdx.x * 256 + 128 + t] = lq[t] + lq[64 + t] + lq[128 + t] + lq[192 + t];
        }
        return;
    }

    // bn0 + relu
#pragma unroll
    for (int o = 0; o < 64; o++) h0[o] = fmaxf(0.f, fmaf(h0[o], bnp[o], bnp[128 + o]));

    float h1[64];
#pragma unroll
    for (int o = 0; o < 64; o++) h1[o] = 0.f;
    for (int c = 0; c < 64; c++) {
        const float xc = h0[c];
        const float* wr = W1T + c * 64;
#pragma unroll
        for (int o = 0; o < 64; o++) h1[o] = fmaf(xc, wr[o], h1[o]);
    }

    if constexpr (STAGE == 1) {
        __shared__ float ls[256], lq[256];
        float rs = 0.f, rq = 0.f;
        for (int c = 0; c < 64; c++) {
            float sv = h1[c], qv = h1[c] * h1[c];
#pragma unroll
            for (int off = 32; off >= 1; off >>= 1) {
                sv += __shfl_xor(sv, off); qv += __shfl_xor(qv, off);
            }
            if (lane == c) { rs = sv; rq = qv; }
        }
        ls[w * 64 + lane] = rs; lq[w * 64 + lane] = rq;
        __syncthreads();
        if (threadIdx.x < 64) {
            const int t = threadIdx.x;
            partials[(size_t)blockIdx.x * 256 + t] = ls[t] + ls[64 + t] + ls[128 + t] + ls[192 + t];
            partials[(size_t)blockIdx.x * 256 + 128 + t] = lq[t] + lq[64 + t] + lq[128 + t] + lq[192 + t];
        }
        return;
    }

    // bn1 + relu
#pragma unroll
    for (int o = 0; o < 64; o++) h1[o] = fmaxf(0.f, fmaf(h1[o], bnp[256 + o], bnp[256 + 128 + o]));

    if constexpr (STAGE == 2) {
        __shared__ float ls[512], lq[512];
        float rs0 = 0.f, rs1 = 0.f, rq0 = 0.f, rq1 = 0.f;
        for (int o = 0; o < 128; o += 4) {
            float a0 = 0.f, a1 = 0.f, a2 = 0.f, a3 = 0.f;
            for (int c = 0; c < 64; c++) {
                const float hc = h1[c];
                const float* wr = W2T + c * 128 + o;
                a0 = fmaf(hc, wr[0], a0); a1 = fmaf(hc, wr[1], a1);
                a2 = fmaf(hc, wr[2], a2); a3 = fmaf(hc, wr[3], a3);
            }
            const float accs[4] = {a0, a1, a2, a3};
#pragma unroll
            for (int j = 0; j < 4; j++) {
                float sv = accs[j], qv = accs[j] * accs[j];
#pragma unroll
                for (int off = 32; off >= 1; off >>= 1) {
                    sv += __shfl_xor(sv, off); qv += __shfl_xor(qv, off);
                }
                const int oo = o + j;
                if (lane == (oo & 63)) {
                    if (oo < 64) { rs0 = sv; rq0 = qv; } else { rs1 = sv; rq1 = qv; }
                }
            }
        }
        ls[w * 128 + lane] = rs0; ls[w * 128 + 64 + lane] = rs1;
        lq[w * 128 + lane] = rq0; lq[w * 128 + 64 + lane] = rq1;
        __syncthreads();
        if (threadIdx.x < 128) {
            const int t = threadIdx.x;
            partials[(size_t)blockIdx.x * 256 + t] = ls[t] + ls[128 + t] + ls[256 + t] + ls[384 + t];
            partials[(size_t)blockIdx.x * 256 + 128 + t] = lq[t] + lq[128 + t] + lq[256 + t] + lq[384 + t];
        }
        return;
    }

    if constexpr (STAGE == 3) {
        const float* bn2 = bnp + 512;
        for (int o = 0; o < 128; o += 4) {
            float a0 = 0.f, a1 = 0.f, a2 = 0.f, a3 = 0.f;
            for (int c = 0; c < 64; c++) {
                const float hc = h1[c];
                const float* wr = W2T + c * 128 + o;
                a0 = fmaf(hc, wr[0], a0); a1 = fmaf(hc, wr[1], a1);
                a2 = fmaf(hc, wr[2], a2); a3 = fmaf(hc, wr[3], a3);
            }
            const float accs[4] = {a0, a1, a2, a3};
#pragma unroll
            for (int j = 0; j < 4; j++) {
                float y = fmaxf(0.f, fmaf(accs[j], bn2[o + j], bn2[128 + o + j]));
#pragma unroll
                for (int off = 16; off >= 1; off >>= 1) y = fmaxf(y, __shfl_xor(y, off, 32));
                if (s == 0) out_np[(size_t)q * 128 + o + j] = y;
            }
        }
        return;
    }
}

// ---------------------------------------------------------------- BN finalize
template <int C>
__global__ __launch_bounds__(128) void k_bnfin(const float* __restrict__ partials,
                                               const float* __restrict__ gw,
                                               const float* __restrict__ bw,
                                               float* __restrict__ bnpL) {
    const int t = threadIdx.x;
    if (t >= C) return;
    double Ssum = 0.0, Q = 0.0;
    for (int blk = 0; blk < NBLK_; blk++) {
        Ssum += (double)partials[(size_t)blk * 256 + t];
        Q += (double)partials[(size_t)blk * 256 + 128 + t];
    }
    const double mean = Ssum / (double)NROWS_;
    const double var = Q / (double)NROWS_ - mean * mean;
    const float sc = (float)((double)gw[t] / sqrt(var + 1e-5));
    const float sh = (float)((double)bw[t] - mean * (double)sc);
    bnpL[t] = sc;
    bnpL[128 + t] = sh;
}

// ---------------------------------------------------------------- launch
extern "C" void kernel_launch(void* const* d_in, const int* in_sizes, int n_in,
                              void* d_out, int out_size, void* d_ws, size_t ws_size,
                              hipStream_t stream) {
    const float* xyz = (const float*)d_in[0];
    const float* points = (const float*)d_in[1];
    const float* W0 = (const float*)d_in[2];
    const float* g0 = (const float*)d_in[3];
    const float* b0 = (const float*)d_in[4];
    const float* W1 = (const float*)d_in[5];
    const float* g1 = (const float*)d_in[6];
    const float* b1 = (const float*)d_in[7];
    const float* W2 = (const float*)d_in[8];
    const float* g2 = (const float*)d_in[9];
    const float* b2 = (const float*)d_in[10];

    float* out = (float*)d_out;
    float* newxyz = out;                 // B*M*3
    float* out_np = out + B_ * M_ * 3;   // B*M*128

    char* ws = (char*)d_ws;
    float* sqn = (float*)(ws + OFF_SQN);
    int* fps_idx = (int*)(ws + OFF_FPS);
    int* ball = (int*)(ws + OFF_BALL);
    float* W0T = (float*)(ws + OFF_W0T);
    float* W1T = (float*)(ws + OFF_W1T);
    float* W2T = (float*)(ws + OFF_W2T);
    float* partials = (float*)(ws + OFF_PART);
    float* bnp = (float*)(ws + OFF_BNP);

    k_sqnorm<<<(B_ * N_ + 255) / 256, 256, 0, stream>>>(xyz, sqn);
    k_fps<<<B_, 256, 0, stream>>>(xyz, fps_idx);
    k_newxyz<<<(B_ * M_ + 255) / 256, 256, 0, stream>>>(xyz, fps_idx, newxyz);
    k_ball<<<B_ * M_ / 4, 256, 0, stream>>>(xyz, sqn, fps_idx, newxyz, ball);
    k_wtrans<<<32, 256, 0, stream>>>(W0, W1, W2, W0T, W1T, W2T);

    k_mlp<0><<<NBLK_, 256, 0, stream>>>(points, xyz, newxyz, ball, W0T, W1T, W2T, bnp, partials, out_np);
    k_bnfin<64><<<1, 128, 0, stream>>>(partials, g0, b0, bnp);
    k_mlp<1><<<NBLK_, 256, 0, stream>>>(points, xyz, newxyz, ball, W0T, W1T, W2T, bnp, partials, out_np);
    k_bnfin<64><<<1, 128, 0, stream>>>(partials, g1, b1, bnp + 256);
    k_mlp<2><<<NBLK_, 256, 0, stream>>>(points, xyz, newxyz, ball, W0T, W1T, W2T, bnp, partials, out_np);
    k_bnfin<128><<<1, 128, 0, stream>>>(partials, g2, b2, bnp + 512);
    k_mlp<3><<<NBLK_, 256, 0, stream>>>(points, xyz, newxyz, ball, W0T, W1T, W2T, bnp, partials, out_np);
}

// Round 4
// 2255.057 us; speedup vs baseline: 1.6720x; 1.6720x over previous
//
#include <hip/hip_runtime.h>
#include <cstdint>
#include <cstddef>

namespace {
constexpr int B_ = 16;
constexpr int N_ = 4096;
constexpr int D_ = 64;
constexpr int M_ = 1024;
constexpr int S_ = 32;
constexpr int NROWS_ = B_ * M_ * S_;   // 524288
constexpr int TPB_ = 128;
constexpr int NBLK_ = NROWS_ / TPB_;   // 4096
constexpr float RR_ = 0.04f;

// ws offsets (bytes)
constexpr size_t OFF_SQN  = 0;                                   // 262144
constexpr size_t OFF_FPS  = 262144;                              // 65536
constexpr size_t OFF_BALL = 327680;                              // 2097152
constexpr size_t OFF_W0T  = 2424832;                             // 17152
constexpr size_t OFF_W1T  = OFF_W0T + 67 * 64 * 4;               // 16384
constexpr size_t OFF_W2T  = OFF_W1T + 64 * 64 * 4;               // 32768
constexpr size_t OFF_PART = OFF_W2T + 64 * 128 * 4;              // 4096*256*4
constexpr size_t OFF_BNP  = OFF_PART + (size_t)NBLK_ * 256 * 4;  // 3072
}

// non-contractible multiply (separately-rounded product), scheduler-friendly
__device__ __forceinline__ float mul_nr(float a, float b) {
    float p = a * b;
    asm("" : "+v"(p));
    return p;
}
// volatile variant kept for the PROVEN-bitwise decision kernels (zero-risk)
__device__ __forceinline__ float mul_nf(float a, float b) {
    float p = a * b;
    asm volatile("" : "+v"(p));
    return p;
}

// ---------------------------------------------------------------- fold reduce
// Per-wave transpose-reduce: lane L holds v[0..63] (its row's channels).
// After fold, return value at lane L = op over the wave's 64 rows of channel L.
// Mutates cur[0..63]. All indices compile-time after unroll (no scratch).
__device__ __forceinline__ float fold_sum_wave(float* cur, int lane) {
#pragma unroll
    for (int k = 0; k < 6; k++) {
        const bool hi = (lane >> k) & 1;
#pragma unroll
        for (int m = 0; m < (32 >> k); m++) {
            const float a = cur[2 * m], b = cur[2 * m + 1];
            const float keep = hi ? b : a;
            const float give = hi ? a : b;
            const float got = __shfl_xor(give, 1 << k);
            cur[m] = keep + got;
        }
    }
    return cur[0];
}

// max over each 32-lane half-group; lane L gets channels (lane&31) and 32+(lane&31)
__device__ __forceinline__ void fold_max_half(float* cur, int lane, float& r0, float& r1) {
#pragma unroll
    for (int k = 0; k < 5; k++) {
        const bool hi = (lane >> k) & 1;
#pragma unroll
        for (int m = 0; m < (32 >> k); m++) {
            const float a = cur[2 * m], b = cur[2 * m + 1];
            const float keep = hi ? b : a;
            const float give = hi ? a : b;
            const float got = __shfl_xor(give, 1 << k);
            cur[m] = fmaxf(keep, got);
        }
    }
    r0 = cur[0]; r1 = cur[1];
}

// ---------------------------------------------------------------- sqnorm
__global__ __launch_bounds__(256) void k_sqnorm(const float* __restrict__ xyz,
                                                float* __restrict__ sqn) {
    int i = blockIdx.x * 256 + threadIdx.x;
    if (i >= B_ * N_) return;
    float x = xyz[3 * i], y = xyz[3 * i + 1], z = xyz[3 * i + 2];
    sqn[i] = (mul_nf(x, x) + mul_nf(y, y)) + mul_nf(z, z);
}

// ---------------------------------------------------------------- FPS
// one block/batch; points staged in LDS (uniform-address broadcast centroid
// reads); (dist,idx) packed in u64 key; one barrier per iteration.
__global__ __launch_bounds__(256) void k_fps(const float* __restrict__ xyz,
                                             int* __restrict__ fps_idx) {
    const int b = blockIdx.x, t = threadIdx.x;
    const int lane = t & 63, w = t >> 6;
    const float* xb = xyz + (size_t)b * N_ * 3;
    __shared__ float pts[N_ * 3];                     // 48 KB
    __shared__ unsigned long long slots[2][4];
    for (int i = t; i < N_ * 3; i += 256) pts[i] = xb[i];

    float px[16], py[16], pz[16], dist[16];
    unsigned key_lo[16];
#pragma unroll
    for (int k = 0; k < 16; k++) {
        const int n = t + (k << 8);
        px[k] = xb[3 * n]; py[k] = xb[3 * n + 1]; pz[k] = xb[3 * n + 2];
        dist[k] = 1e10f;
        key_lo[k] = ~(unsigned)n;                    // larger ~n == smaller n
    }
    __syncthreads();

    int far = 0;
    for (int i = 0; i < M_; i++) {
        if (t == 0) fps_idx[b * M_ + i] = far;       // emit BEFORE update
        const float c0 = pts[3 * far], c1 = pts[3 * far + 1], c2 = pts[3 * far + 2];
        unsigned long long best = 0;
#pragma unroll
        for (int k = 0; k < 16; k++) {
            const float d0 = px[k] - c0, d1 = py[k] - c1, d2 = pz[k] - c2;
            // reference: separately-rounded squares, forward 3-sum (bitwise-proven)
            const float dd = (mul_nr(d0, d0) + mul_nr(d1, d1)) + mul_nr(d2, d2);
            const float dm = fminf(dist[k], dd);
            dist[k] = dm;
            // dm >= 0 -> f32 bits monotone; key max == (max dist, then min idx)
            const unsigned long long key =
                ((unsigned long long)__float_as_uint(dm) << 32) | key_lo[k];
            best = (key > best) ? key : best;
        }
#pragma unroll
        for (int off = 32; off >= 1; off >>= 1) {
            unsigned lo = (unsigned)best, hi = (unsigned)(best >> 32);
            lo = __shfl_xor(lo, off); hi = __shfl_xor(hi, off);
            const unsigned long long o = ((unsigned long long)hi << 32) | lo;
            best = (o > best) ? o : best;
        }
        if (lane == 0) slots[i & 1][w] = best;
        __syncthreads();                              // the ONLY barrier per iter
        const unsigned long long s0 = slots[i & 1][0], s1 = slots[i & 1][1],
                                 s2 = slots[i & 1][2], s3 = slots[i & 1][3];
        const unsigned long long m01 = s0 > s1 ? s0 : s1;
        const unsigned long long m23 = s2 > s3 ? s2 : s3;
        const unsigned long long bb = m01 > m23 ? m01 : m23;
        far = (int)(~(unsigned)bb);
    }
}

// ---------------------------------------------------------------- gather new_xyz
__global__ __launch_bounds__(256) void k_newxyz(const float* __restrict__ xyz,
                                                const int* __restrict__ fps_idx,
                                                float* __restrict__ newxyz) {
    int i = blockIdx.x * 256 + threadIdx.x;
    if (i >= B_ * M_) return;
    int b = i >> 10;
    int f = fps_idx[i];
    const float* p = xyz + ((size_t)b * N_ + f) * 3;
    newxyz[3 * i] = p[0]; newxyz[3 * i + 1] = p[1]; newxyz[3 * i + 2] = p[2];
}

// ---------------------------------------------------------------- ball query (bitwise-frozen)
__global__ __launch_bounds__(256) void k_ball(const float* __restrict__ xyz,
                                              const float* __restrict__ sqn,
                                              const int* __restrict__ fps_idx,
                                              const float* __restrict__ newxyz,
                                              int* __restrict__ ball) {
    const int w = threadIdx.x >> 6, lane = threadIdx.x & 63;
    const int q = blockIdx.x * 4 + w;
    const int b = q >> 10;
    __shared__ int buf[4][32];
    const float* xb = xyz + (size_t)b * N_ * 3;
    const float* sb = sqn + (size_t)b * N_;
    const float q0 = newxyz[3 * q], q1 = newxyz[3 * q + 1], q2 = newxyz[3 * q + 2];
    const float sq = sb[fps_idx[q]];

    int cnt = 0;
    for (int base = 0; base < N_ && cnt < 32; base += 64) {
        const int n = base + lane;
        const float p0 = xb[3 * n], p1 = xb[3 * n + 1], p2 = xb[3 * n + 2];
        float dot = fmaf(q2, p2, fmaf(q1, p1, q0 * p0));   // ascending FMA (proven)
        float tt = -2.0f * dot;
        tt = tt + sq;
        tt = tt + sb[n];
        const bool pred = !(tt > RR_);
        const unsigned long long mask = __ballot(pred);
        const int pos = cnt + __popcll(mask & ((1ull << lane) - 1ull));
        if (pred && pos < 32) buf[w][pos] = n;
        cnt += (int)__popcll(mask);
    }
    __syncthreads();
    if (lane < 32) {
        int e = buf[w][(lane < cnt) ? lane : 0];
        ball[(size_t)q * 32 + lane] = e;
    }
}

// ---------------------------------------------------------------- weight transpose
__global__ __launch_bounds__(256) void k_wtrans(const float* __restrict__ W0,
                                                const float* __restrict__ W1,
                                                const float* __restrict__ W2,
                                                float* __restrict__ W0T,
                                                float* __restrict__ W1T,
                                                float* __restrict__ W2T) {
    int t = blockIdx.x * 256 + threadIdx.x;
    if (t < 64 * 67) { int o = t / 67, c = t % 67; W0T[c * 64 + o] = W0[t]; }
    if (t < 64 * 64) { int o = t / 64, c = t % 64; W1T[c * 64 + o] = W1[t]; }
    if (t < 128 * 64) { int o = t / 64, c = t % 64; W2T[c * 128 + o] = W2[t]; }
}

// ---------------------------------------------------------------- MLP stages
// All accumulators statically indexed (VGPR-resident). Runtime-c consumption
// goes through a per-thread LDS row (tile[128][65], 2-way aliasing = free).
// Stats via register fold-reduce (63 shuffles) — no scratch anywhere.
template <int STAGE>
__global__ __launch_bounds__(TPB_) void k_mlp(
    const float* __restrict__ points, const float* __restrict__ xyz,
    const float* __restrict__ newxyz, const int* __restrict__ ball,
    const float* __restrict__ W0T, const float* __restrict__ W1T,
    const float* __restrict__ W2T, const float* __restrict__ bnp,
    float* __restrict__ partials, float* __restrict__ out_np) {
    const int t = threadIdx.x;
    const int lane = t & 63, w = t >> 6;
    const int r = blockIdx.x * TPB_ + t;
    const int b = r >> 15;
    const int q = r >> 5;
    const int g = ball[r];
    const float* prow = points + ((size_t)(b * N_) + g) * D_;
    const float xg0 = xyz[((size_t)b * N_ + g) * 3 + 0] - newxyz[(size_t)q * 3 + 0];
    const float xg1 = xyz[((size_t)b * N_ + g) * 3 + 1] - newxyz[(size_t)q * 3 + 1];
    const float xg2 = xyz[((size_t)b * N_ + g) * 3 + 2] - newxyz[(size_t)q * 3 + 2];

    // ---- GEMM0 -> h0 (static indices only)
    float h0[64];
#pragma unroll
    for (int o = 0; o < 64; o++) h0[o] = 0.f;
    for (int c = 0; c < 64; c += 4) {
        const float4 xv = *reinterpret_cast<const float4*>(prow + c);
        const float xs[4] = {xv.x, xv.y, xv.z, xv.w};
#pragma unroll
        for (int j = 0; j < 4; j++) {
            const float xc = xs[j];
            const float* wr = W0T + (c + j) * 64;
#pragma unroll
            for (int o = 0; o < 64; o++) h0[o] = fmaf(xc, wr[o], h0[o]);
        }
    }
    {
        const float* wa = W0T + 64 * 64;
        const float* wb = W0T + 65 * 64;
        const float* wc = W0T + 66 * 64;
#pragma unroll
        for (int o = 0; o < 64; o++) h0[o] = fmaf(xg0, wa[o], h0[o]);
#pragma unroll
        for (int o = 0; o < 64; o++) h0[o] = fmaf(xg1, wb[o], h0[o]);
#pragma unroll
        for (int o = 0; o < 64; o++) h0[o] = fmaf(xg2, wc[o], h0[o]);
    }

    if constexpr (STAGE == 0) {
        __shared__ float ssum[2][64], ssq[2][64];
        float tmp[64];
#pragma unroll
        for (int i = 0; i < 64; i++) tmp[i] = h0[i] * h0[i];
        const float s = fold_sum_wave(h0, lane);
        const float sq = fold_sum_wave(tmp, lane);
        ssum[w][lane] = s; ssq[w][lane] = sq;
        __syncthreads();
        if (t < 64) {
            partials[(size_t)blockIdx.x * 256 + t] = ssum[0][t] + ssum[1][t];
            partials[(size_t)blockIdx.x * 256 + 128 + t] = ssq[0][t] + ssq[1][t];
        }
        return;
    } else {
        __shared__ float tile[TPB_ * 65];

        // bn0 + relu, stash row in LDS for runtime-c consumption
#pragma unroll
        for (int o = 0; o < 64; o++) {
            const float v = fmaxf(0.f, fmaf(h0[o], bnp[o], bnp[128 + o]));
            tile[t * 65 + o] = v;
        }

        // ---- GEMM1 -> h1
        float h1[64];
#pragma unroll
        for (int o = 0; o < 64; o++) h1[o] = 0.f;
        for (int c = 0; c < 64; c++) {
            const float xc = tile[t * 65 + c];
            const float* wr = W1T + c * 64;
#pragma unroll
            for (int o = 0; o < 64; o++) h1[o] = fmaf(xc, wr[o], h1[o]);
        }

        if constexpr (STAGE == 1) {
            __shared__ float ssum[2][64], ssq[2][64];
            float tmp[64];
#pragma unroll
            for (int i = 0; i < 64; i++) tmp[i] = h1[i] * h1[i];
            const float s = fold_sum_wave(h1, lane);
            const float sq = fold_sum_wave(tmp, lane);
            ssum[w][lane] = s; ssq[w][lane] = sq;
            __syncthreads();
            if (t < 64) {
                partials[(size_t)blockIdx.x * 256 + t] = ssum[0][t] + ssum[1][t];
                partials[(size_t)blockIdx.x * 256 + 128 + t] = ssq[0][t] + ssq[1][t];
            }
            return;
        } else {
            // bn1 + relu, stash row (own-row overwrite: no barrier needed)
#pragma unroll
            for (int o = 0; o < 64; o++) {
                const float v = fmaxf(0.f, fmaf(h1[o], bnp[256 + o], bnp[256 + 128 + o]));
                tile[t * 65 + o] = v;
            }

            // ---- GEMM2 -> h2[128]
            float h2[128];
#pragma unroll
            for (int o = 0; o < 128; o++) h2[o] = 0.f;
            for (int c = 0; c < 64; c++) {
                const float hc = tile[t * 65 + c];
                const float* wr = W2T + c * 128;
#pragma unroll
                for (int o = 0; o < 128; o++) h2[o] = fmaf(hc, wr[o], h2[o]);
            }

            if constexpr (STAGE == 2) {
                __shared__ float s2[2][128], q2[2][128];
                float tmp[64];
#pragma unroll
                for (int i = 0; i < 64; i++) tmp[i] = h2[i] * h2[i];
                const float sA = fold_sum_wave(h2, lane);       // mutates h2[0..63]
                const float qA = fold_sum_wave(tmp, lane);
                s2[w][lane] = sA; q2[w][lane] = qA;
#pragma unroll
                for (int i = 0; i < 64; i++) tmp[i] = h2[64 + i] * h2[64 + i];
                const float sB = fold_sum_wave(h2 + 64, lane);
                const float qB = fold_sum_wave(tmp, lane);
                s2[w][64 + lane] = sB; q2[w][64 + lane] = qB;
                __syncthreads();
                if (t < 128) {
                    partials[(size_t)blockIdx.x * 256 + t] = s2[0][t] + s2[1][t];
                    partials[(size_t)blockIdx.x * 256 + 128 + t] = q2[0][t] + q2[1][t];
                }
                return;
            } else {
                // ---- STAGE 3: bn2 + relu + max over the 32-sample group
                const float* bn2 = bnp + 512;
#pragma unroll
                for (int o = 0; o < 128; o++)
                    h2[o] = fmaxf(0.f, fmaf(h2[o], bn2[o], bn2[128 + o]));

                const int qq = blockIdx.x * 4 + w * 2 + (lane >> 5);
                float r0, r1;
                fold_max_half(h2, lane, r0, r1);
                out_np[(size_t)qq * 128 + (lane & 31)] = r0;
                out_np[(size_t)qq * 128 + 32 + (lane & 31)] = r1;
                fold_max_half(h2 + 64, lane, r0, r1);
                out_np[(size_t)qq * 128 + 64 + (lane & 31)] = r0;
                out_np[(size_t)qq * 128 + 96 + (lane & 31)] = r1;
                return;
            }
        }
    }
}

// ---------------------------------------------------------------- BN finalize
template <int C>
__global__ __launch_bounds__(128) void k_bnfin(const float* __restrict__ partials,
                                               const float* __restrict__ gw,
                                               const float* __restrict__ bw,
                                               float* __restrict__ bnpL) {
    const int t = threadIdx.x;
    if (t >= C) return;
    double Ssum = 0.0, Q = 0.0;
    for (int blk = 0; blk < NBLK_; blk++) {
        Ssum += (double)partials[(size_t)blk * 256 + t];
        Q += (double)partials[(size_t)blk * 256 + 128 + t];
    }
    const double mean = Ssum / (double)NROWS_;
    const double var = Q / (double)NROWS_ - mean * mean;
    const float sc = (float)((double)gw[t] / sqrt(var + 1e-5));
    const float sh = (float)((double)bw[t] - mean * (double)sc);
    bnpL[t] = sc;
    bnpL[128 + t] = sh;
}

// ---------------------------------------------------------------- launch
extern "C" void kernel_launch(void* const* d_in, const int* in_sizes, int n_in,
                              void* d_out, int out_size, void* d_ws, size_t ws_size,
                              hipStream_t stream) {
    const float* xyz = (const float*)d_in[0];
    const float* points = (const float*)d_in[1];
    const float* W0 = (const float*)d_in[2];
    const float* g0 = (const float*)d_in[3];
    const float* b0 = (const float*)d_in[4];
    const float* W1 = (const float*)d_in[5];
    const float* g1 = (const float*)d_in[6];
    const float* b1 = (const float*)d_in[7];
    const float* W2 = (const float*)d_in[8];
    const float* g2 = (const float*)d_in[9];
    const float* b2 = (const float*)d_in[10];

    float* out = (float*)d_out;
    float* newxyz = out;
    float* out_np = out + B_ * M_ * 3;

    char* ws = (char*)d_ws;
    float* sqn = (float*)(ws + OFF_SQN);
    int* fps_idx = (int*)(ws + OFF_FPS);
    int* ball = (int*)(ws + OFF_BALL);
    float* W0T = (float*)(ws + OFF_W0T);
    float* W1T = (float*)(ws + OFF_W1T);
    float* W2T = (float*)(ws + OFF_W2T);
    float* partials = (float*)(ws + OFF_PART);
    float* bnp = (float*)(ws + OFF_BNP);

    k_sqnorm<<<(B_ * N_ + 255) / 256, 256, 0, stream>>>(xyz, sqn);
    k_fps<<<B_, 256, 0, stream>>>(xyz, fps_idx);
    k_newxyz<<<(B_ * M_ + 255) / 256, 256, 0, stream>>>(xyz, fps_idx, newxyz);
    k_ball<<<B_ * M_ / 4, 256, 0, stream>>>(xyz, sqn, fps_idx, newxyz, ball);
    k_wtrans<<<32, 256, 0, stream>>>(W0, W1, W2, W0T, W1T, W2T);

    k_mlp<0><<<NBLK_, TPB_, 0, stream>>>(points, xyz, newxyz, ball, W0T, W1T, W2T, bnp, partials, out_np);
    k_bnfin<64><<<1, 128, 0, stream>>>(partials, g0, b0, bnp);
    k_mlp<1><<<NBLK_, TPB_, 0, stream>>>(points, xyz, newxyz, ball, W0T, W1T, W2T, bnp, partials, out_np);
    k_bnfin<64><<<1, 128, 0, stream>>>(partials, g1, b1, bnp + 256);
    k_mlp<2><<<NBLK_, TPB_, 0, stream>>>(points, xyz, newxyz, ball, W0T, W1T, W2T, bnp, partials, out_np);
    k_bnfin<128><<<1, 128, 0, stream>>>(partials, g2, b2, bnp + 512);
    k_mlp<3><<<NBLK_, TPB_, 0, stream>>>(points, xyz, newxyz, ball, W0T, W1T, W2T, bnp, partials, out_np);
}

// Round 5
// 1930.371 us; speedup vs baseline: 1.9532x; 1.1682x over previous
//
#include <hip/hip_runtime.h>
#include <cstdint>
#include <cstddef>

namespace {
constexpr int B_ = 16;
constexpr int N_ = 4096;
constexpr int D_ = 64;
constexpr int M_ = 1024;
constexpr int S_ = 32;
constexpr int NROWS_ = B_ * M_ * S_;   // 524288
constexpr int TPB_ = 128;
constexpr int NBLK_ = NROWS_ / TPB_;   // 4096
constexpr float RR_ = 0.04f;

// ws offsets (bytes)
constexpr size_t OFF_SQN  = 0;                                   // 262144
constexpr size_t OFF_FPS  = 262144;                              // 65536
constexpr size_t OFF_BALL = 327680;                              // 2097152
constexpr size_t OFF_W0T  = 2424832;                             // 17152
constexpr size_t OFF_W1T  = OFF_W0T + 67 * 64 * 4;               // 16384
constexpr size_t OFF_W2T  = OFF_W1T + 64 * 64 * 4;               // 32768
constexpr size_t OFF_PART = OFF_W2T + 64 * 128 * 4;              // 4096*256*4
constexpr size_t OFF_BNP  = OFF_PART + (size_t)NBLK_ * 256 * 4;  // 3072
}

// non-contractible multiply (separately-rounded product), scheduler-friendly
__device__ __forceinline__ float mul_nr(float a, float b) {
    float p = a * b;
    asm("" : "+v"(p));
    return p;
}
// volatile variant kept for the PROVEN-bitwise decision kernels (zero-risk)
__device__ __forceinline__ float mul_nf(float a, float b) {
    float p = a * b;
    asm volatile("" : "+v"(p));
    return p;
}

// DPP lane move: result = src[selected lane] per dpp ctrl (VALU-rate, no LDS)
template <int CTRL>
__device__ __forceinline__ float dpp_movf(float x) {
    return __int_as_float(
        __builtin_amdgcn_update_dpp(0, __float_as_int(x), CTRL, 0xF, 0xF, true));
}
// xor-exchange: k=0 -> quad_perm[1,0,3,2]=0xB1, k=1 -> quad_perm[2,3,0,1]=0x4E,
// k>=2 -> __shfl_xor (LDS permute)
__device__ __forceinline__ float xor_exch(float x, int k) {
    if (k == 0) return dpp_movf<0xB1>(x);
    if (k == 1) return dpp_movf<0x4E>(x);
    return __shfl_xor(x, 1 << k);
}

// ---------------------------------------------------------------- fold reduce
// Per-wave transpose-reduce: lane L holds v[0..63] (its row's channels).
// After fold, value at lane L = op over the wave's 64 rows of channel L.
__device__ __forceinline__ float fold_sum_wave(float* cur, int lane) {
#pragma unroll
    for (int k = 0; k < 6; k++) {
        const bool hi = (lane >> k) & 1;
#pragma unroll
        for (int m = 0; m < (32 >> k); m++) {
            const float a = cur[2 * m], b = cur[2 * m + 1];
            const float keep = hi ? b : a;
            const float give = hi ? a : b;
            const float got = xor_exch(give, k);
            cur[m] = keep + got;
        }
    }
    return cur[0];
}

__device__ __forceinline__ void fold_max_half(float* cur, int lane, float& r0, float& r1) {
#pragma unroll
    for (int k = 0; k < 5; k++) {
        const bool hi = (lane >> k) & 1;
#pragma unroll
        for (int m = 0; m < (32 >> k); m++) {
            const float a = cur[2 * m], b = cur[2 * m + 1];
            const float keep = hi ? b : a;
            const float give = hi ? a : b;
            const float got = xor_exch(give, k);
            cur[m] = fmaxf(keep, got);
        }
    }
    r0 = cur[0]; r1 = cur[1];
}

// ---------------------------------------------------------------- sqnorm
__global__ __launch_bounds__(256) void k_sqnorm(const float* __restrict__ xyz,
                                                float* __restrict__ sqn) {
    int i = blockIdx.x * 256 + threadIdx.x;
    if (i >= B_ * N_) return;
    float x = xyz[3 * i], y = xyz[3 * i + 1], z = xyz[3 * i + 2];
    sqn[i] = (mul_nf(x, x) + mul_nf(y, y)) + mul_nf(z, z);
}

// ---------------------------------------------------------------- FPS v2
// 512 threads (8 waves), 8 CONTIGUOUS points per thread (lane order == index
// order). Wave argmax: DPP f32 max (VALU) + ballot/readlane for the index;
// cross-wave via u64 (distbits<<32 | ~idx) slots; one barrier per iteration.
__global__ __launch_bounds__(512) void k_fps(const float* __restrict__ xyz,
                                             int* __restrict__ fps_idx) {
    const int b = blockIdx.x, t = threadIdx.x;
    const int lane = t & 63, w = t >> 6;
    const float* xb = xyz + (size_t)b * N_ * 3;
    __shared__ float pts[N_ * 3];                 // 48 KB
    __shared__ unsigned long long slots[2][8];
    for (int i = t; i < N_ * 3; i += 512) pts[i] = xb[i];
    __syncthreads();

    const int n0 = t * 8;
    float px[8], py[8], pz[8], dist[8];
#pragma unroll
    for (int k = 0; k < 8; k++) {
        px[k] = pts[3 * (n0 + k)];
        py[k] = pts[3 * (n0 + k) + 1];
        pz[k] = pts[3 * (n0 + k) + 2];
        dist[k] = 1e10f;
    }

    int far = 0;
    for (int i = 0; i < M_; i++) {
        if (t == 0) fps_idx[b * M_ + i] = far;    // emit BEFORE update
        const float c0 = pts[3 * far], c1 = pts[3 * far + 1], c2 = pts[3 * far + 2];
        float bestv = -1.0f; int bestn = n0;
#pragma unroll
        for (int k = 0; k < 8; k++) {
            const float d0 = px[k] - c0, d1 = py[k] - c1, d2 = pz[k] - c2;
            // reference semantics: separately-rounded squares, forward 3-sum
            const float dd = (mul_nr(d0, d0) + mul_nr(d1, d1)) + mul_nr(d2, d2);
            const float dm = fminf(dist[k], dd);
            dist[k] = dm;
            if (dm > bestv) { bestv = dm; bestn = n0 + k; }   // strict > keeps first
        }
        // wave max via DPP (dists >= 0, bound_ctrl-zero is identity-safe)
        float m = bestv;
        m = fmaxf(m, dpp_movf<0x111>(m));   // row_shr:1
        m = fmaxf(m, dpp_movf<0x112>(m));   // row_shr:2
        m = fmaxf(m, dpp_movf<0x114>(m));   // row_shr:4
        m = fmaxf(m, dpp_movf<0x118>(m));   // row_shr:8
        m = fmaxf(m, dpp_movf<0x142>(m));   // row_bcast:15
        m = fmaxf(m, dpp_movf<0x143>(m));   // row_bcast:31  -> lane63 = wave max
        const float wmax = __int_as_float(
            __builtin_amdgcn_readlane(__float_as_int(m), 63));
        // first lane holding the max == smallest index (contiguous ownership)
        const unsigned long long mk = __ballot(bestv == wmax);
        const int src = __ffsll((long long)mk) - 1;
        const int wn = __builtin_amdgcn_readlane(bestn, src);
        if (lane == 0)
            slots[i & 1][w] =
                ((unsigned long long)__float_as_uint(wmax) << 32) | (unsigned)(~wn);
        __syncthreads();                           // the only barrier per iter
        const unsigned long long* sl = slots[i & 1];
        const unsigned long long s0 = sl[0], s1 = sl[1], s2 = sl[2], s3 = sl[3];
        const unsigned long long s4 = sl[4], s5 = sl[5], s6 = sl[6], s7 = sl[7];
        const unsigned long long a0 = s0 > s1 ? s0 : s1;
        const unsigned long long a1 = s2 > s3 ? s2 : s3;
        const unsigned long long a2 = s4 > s5 ? s4 : s5;
        const unsigned long long a3 = s6 > s7 ? s6 : s7;
        const unsigned long long b0 = a0 > a1 ? a0 : a1;
        const unsigned long long b1 = a2 > a3 ? a2 : a3;
        const unsigned long long bb = b0 > b1 ? b0 : b1;
        far = (int)(~(unsigned)bb);
    }
}

// ---------------------------------------------------------------- gather new_xyz
__global__ __launch_bounds__(256) void k_newxyz(const float* __restrict__ xyz,
                                                const int* __restrict__ fps_idx,
                                                float* __restrict__ newxyz) {
    int i = blockIdx.x * 256 + threadIdx.x;
    if (i >= B_ * M_) return;
    int b = i >> 10;
    int f = fps_idx[i];
    const float* p = xyz + ((size_t)b * N_ + f) * 3;
    newxyz[3 * i] = p[0]; newxyz[3 * i + 1] = p[1]; newxyz[3 * i + 2] = p[2];
}

// ---------------------------------------------------------------- ball query (bitwise-frozen)
__global__ __launch_bounds__(256) void k_ball(const float* __restrict__ xyz,
                                              const float* __restrict__ sqn,
                                              const int* __restrict__ fps_idx,
                                              const float* __restrict__ newxyz,
                                              int* __restrict__ ball) {
    const int w = threadIdx.x >> 6, lane = threadIdx.x & 63;
    const int q = blockIdx.x * 4 + w;
    const int b = q >> 10;
    __shared__ int buf[4][32];
    const float* xb = xyz + (size_t)b * N_ * 3;
    const float* sb = sqn + (size_t)b * N_;
    const float q0 = newxyz[3 * q], q1 = newxyz[3 * q + 1], q2 = newxyz[3 * q + 2];
    const float sq = sb[fps_idx[q]];

    int cnt = 0;
    for (int base = 0; base < N_ && cnt < 32; base += 64) {
        const int n = base + lane;
        const float p0 = xb[3 * n], p1 = xb[3 * n + 1], p2 = xb[3 * n + 2];
        float dot = fmaf(q2, p2, fmaf(q1, p1, q0 * p0));   // ascending FMA (proven)
        float tt = -2.0f * dot;
        tt = tt + sq;
        tt = tt + sb[n];
        const bool pred = !(tt > RR_);
        const unsigned long long mask = __ballot(pred);
        const int pos = cnt + __popcll(mask & ((1ull << lane) - 1ull));
        if (pred && pos < 32) buf[w][pos] = n;
        cnt += (int)__popcll(mask);
    }
    __syncthreads();
    if (lane < 32) {
        int e = buf[w][(lane < cnt) ? lane : 0];
        ball[(size_t)q * 32 + lane] = e;
    }
}

// ---------------------------------------------------------------- weight transpose
__global__ __launch_bounds__(256) void k_wtrans(const float* __restrict__ W0,
                                                const float* __restrict__ W1,
                                                const float* __restrict__ W2,
                                                float* __restrict__ W0T,
                                                float* __restrict__ W1T,
                                                float* __restrict__ W2T) {
    int t = blockIdx.x * 256 + threadIdx.x;
    if (t < 64 * 67) { int o = t / 67, c = t % 67; W0T[c * 64 + o] = W0[t]; }
    if (t < 64 * 64) { int o = t / 64, c = t % 64; W1T[c * 64 + o] = W1[t]; }
    if (t < 128 * 64) { int o = t / 64, c = t % 64; W2T[c * 128 + o] = W2[t]; }
}

// ---------------------------------------------------------------- MLP stages
template <int STAGE>
__global__ __launch_bounds__(TPB_) void k_mlp(
    const float* __restrict__ points, const float* __restrict__ xyz,
    const float* __restrict__ newxyz, const int* __restrict__ ball,
    const float* __restrict__ W0T, const float* __restrict__ W1T,
    const float* __restrict__ W2T, const float* __restrict__ bnp,
    float* __restrict__ partials, float* __restrict__ out_np) {
    const int t = threadIdx.x;
    const int lane = t & 63, w = t >> 6;
    const int r = blockIdx.x * TPB_ + t;
    const int b = r >> 15;
    const int q = r >> 5;
    const int g = ball[r];
    const float* prow = points + ((size_t)(b * N_) + g) * D_;
    const float xg0 = xyz[((size_t)b * N_ + g) * 3 + 0] - newxyz[(size_t)q * 3 + 0];
    const float xg1 = xyz[((size_t)b * N_ + g) * 3 + 1] - newxyz[(size_t)q * 3 + 1];
    const float xg2 = xyz[((size_t)b * N_ + g) * 3 + 2] - newxyz[(size_t)q * 3 + 2];

    // ---- GEMM0 -> h0 (static indices only)
    float h0[64];
#pragma unroll
    for (int o = 0; o < 64; o++) h0[o] = 0.f;
    for (int c = 0; c < 64; c += 4) {
        const float4 xv = *reinterpret_cast<const float4*>(prow + c);
        const float xs[4] = {xv.x, xv.y, xv.z, xv.w};
#pragma unroll
        for (int j = 0; j < 4; j++) {
            const float xc = xs[j];
            const float* wr = W0T + (c + j) * 64;
#pragma unroll
            for (int o = 0; o < 64; o++) h0[o] = fmaf(xc, wr[o], h0[o]);
        }
    }
    {
        const float* wa = W0T + 64 * 64;
        const float* wb = W0T + 65 * 64;
        const float* wc = W0T + 66 * 64;
#pragma unroll
        for (int o = 0; o < 64; o++) h0[o] = fmaf(xg0, wa[o], h0[o]);
#pragma unroll
        for (int o = 0; o < 64; o++) h0[o] = fmaf(xg1, wb[o], h0[o]);
#pragma unroll
        for (int o = 0; o < 64; o++) h0[o] = fmaf(xg2, wc[o], h0[o]);
    }

    if constexpr (STAGE == 0) {
        __shared__ float ssum[2][64], ssq[2][64];
        float tmp[64];
#pragma unroll
        for (int i = 0; i < 64; i++) tmp[i] = h0[i] * h0[i];
        const float s = fold_sum_wave(h0, lane);
        const float sq = fold_sum_wave(tmp, lane);
        ssum[w][lane] = s; ssq[w][lane] = sq;
        __syncthreads();
        if (t < 64) {
            partials[(size_t)blockIdx.x * 256 + t] = ssum[0][t] + ssum[1][t];
            partials[(size_t)blockIdx.x * 256 + 128 + t] = ssq[0][t] + ssq[1][t];
        }
        return;
    } else {
        __shared__ float tile[TPB_ * 65];

        // bn0 + relu, stash row in LDS for runtime-c consumption
#pragma unroll
        for (int o = 0; o < 64; o++) {
            const float v = fmaxf(0.f, fmaf(h0[o], bnp[o], bnp[128 + o]));
            tile[t * 65 + o] = v;
        }

        // ---- GEMM1 -> h1
        float h1[64];
#pragma unroll
        for (int o = 0; o < 64; o++) h1[o] = 0.f;
        for (int c = 0; c < 64; c++) {
            const float xc = tile[t * 65 + c];
            const float* wr = W1T + c * 64;
#pragma unroll
            for (int o = 0; o < 64; o++) h1[o] = fmaf(xc, wr[o], h1[o]);
        }

        if constexpr (STAGE == 1) {
            __shared__ float ssum[2][64], ssq[2][64];
            float tmp[64];
#pragma unroll
            for (int i = 0; i < 64; i++) tmp[i] = h1[i] * h1[i];
            const float s = fold_sum_wave(h1, lane);
            const float sq = fold_sum_wave(tmp, lane);
            ssum[w][lane] = s; ssq[w][lane] = sq;
            __syncthreads();
            if (t < 64) {
                partials[(size_t)blockIdx.x * 256 + t] = ssum[0][t] + ssum[1][t];
                partials[(size_t)blockIdx.x * 256 + 128 + t] = ssq[0][t] + ssq[1][t];
            }
            return;
        } else {
            // bn1 + relu, stash row (own-row overwrite: no barrier needed)
#pragma unroll
            for (int o = 0; o < 64; o++) {
                const float v = fmaxf(0.f, fmaf(h1[o], bnp[256 + o], bnp[256 + 128 + o]));
                tile[t * 65 + o] = v;
            }

            // ---- GEMM2 -> h2[128]
            float h2[128];
#pragma unroll
            for (int o = 0; o < 128; o++) h2[o] = 0.f;
            for (int c = 0; c < 64; c++) {
                const float hc = tile[t * 65 + c];
                const float* wr = W2T + c * 128;
#pragma unroll
                for (int o = 0; o < 128; o++) h2[o] = fmaf(hc, wr[o], h2[o]);
            }

            if constexpr (STAGE == 2) {
                __shared__ float s2[2][128], q2[2][128];
                float tmp[64];
#pragma unroll
                for (int i = 0; i < 64; i++) tmp[i] = h2[i] * h2[i];
                const float sA = fold_sum_wave(h2, lane);       // mutates h2[0..63]
                const float qA = fold_sum_wave(tmp, lane);
                s2[w][lane] = sA; q2[w][lane] = qA;
#pragma unroll
                for (int i = 0; i < 64; i++) tmp[i] = h2[64 + i] * h2[64 + i];
                const float sB = fold_sum_wave(h2 + 64, lane);
                const float qB = fold_sum_wave(tmp, lane);
                s2[w][64 + lane] = sB; q2[w][64 + lane] = qB;
                __syncthreads();
                if (t < 128) {
                    partials[(size_t)blockIdx.x * 256 + t] = s2[0][t] + s2[1][t];
                    partials[(size_t)blockIdx.x * 256 + 128 + t] = q2[0][t] + q2[1][t];
                }
                return;
            } else {
                // ---- STAGE 3: bn2 + relu + max over the 32-sample group
                const float* bn2 = bnp + 512;
#pragma unroll
                for (int o = 0; o < 128; o++)
                    h2[o] = fmaxf(0.f, fmaf(h2[o], bn2[o], bn2[128 + o]));

                const int qq = blockIdx.x * 4 + w * 2 + (lane >> 5);
                float r0, r1;
                fold_max_half(h2, lane, r0, r1);
                out_np[(size_t)qq * 128 + (lane & 31)] = r0;
                out_np[(size_t)qq * 128 + 32 + (lane & 31)] = r1;
                fold_max_half(h2 + 64, lane, r0, r1);
                out_np[(size_t)qq * 128 + 64 + (lane & 31)] = r0;
                out_np[(size_t)qq * 128 + 96 + (lane & 31)] = r1;
                return;
            }
        }
    }
}

// ---------------------------------------------------------------- BN finalize
template <int C>
__global__ __launch_bounds__(128) void k_bnfin(const float* __restrict__ partials,
                                               const float* __restrict__ gw,
                                               const float* __restrict__ bw,
                                               float* __restrict__ bnpL) {
    const int t = threadIdx.x;
    if (t >= C) return;
    double Ssum = 0.0, Q = 0.0;
    for (int blk = 0; blk < NBLK_; blk++) {
        Ssum += (double)partials[(size_t)blk * 256 + t];
        Q += (double)partials[(size_t)blk * 256 + 128 + t];
    }
    const double mean = Ssum / (double)NROWS_;
    const double var = Q / (double)NROWS_ - mean * mean;
    const float sc = (float)((double)gw[t] / sqrt(var + 1e-5));
    const float sh = (float)((double)bw[t] - mean * (double)sc);
    bnpL[t] = sc;
    bnpL[128 + t] = sh;
}

// ---------------------------------------------------------------- launch
extern "C" void kernel_launch(void* const* d_in, const int* in_sizes, int n_in,
                              void* d_out, int out_size, void* d_ws, size_t ws_size,
                              hipStream_t stream) {
    const float* xyz = (const float*)d_in[0];
    const float* points = (const float*)d_in[1];
    const float* W0 = (const float*)d_in[2];
    const float* g0 = (const float*)d_in[3];
    const float* b0 = (const float*)d_in[4];
    const float* W1 = (const float*)d_in[5];
    const float* g1 = (const float*)d_in[6];
    const float* b1 = (const float*)d_in[7];
    const float* W2 = (const float*)d_in[8];
    const float* g2 = (const float*)d_in[9];
    const float* b2 = (const float*)d_in[10];

    float* out = (float*)d_out;
    float* newxyz = out;
    float* out_np = out + B_ * M_ * 3;

    char* ws = (char*)d_ws;
    float* sqn = (float*)(ws + OFF_SQN);
    int* fps_idx = (int*)(ws + OFF_FPS);
    int* ball = (int*)(ws + OFF_BALL);
    float* W0T = (float*)(ws + OFF_W0T);
    float* W1T = (float*)(ws + OFF_W1T);
    float* W2T = (float*)(ws + OFF_W2T);
    float* partials = (float*)(ws + OFF_PART);
    float* bnp = (float*)(ws + OFF_BNP);

    k_sqnorm<<<(B_ * N_ + 255) / 256, 256, 0, stream>>>(xyz, sqn);
    k_fps<<<B_, 512, 0, stream>>>(xyz, fps_idx);
    k_newxyz<<<(B_ * M_ + 255) / 256, 256, 0, stream>>>(xyz, fps_idx, newxyz);
    k_ball<<<B_ * M_ / 4, 256, 0, stream>>>(xyz, sqn, fps_idx, newxyz, ball);
    k_wtrans<<<32, 256, 0, stream>>>(W0, W1, W2, W0T, W1T, W2T);

    k_mlp<0><<<NBLK_, TPB_, 0, stream>>>(points, xyz, newxyz, ball, W0T, W1T, W2T, bnp, partials, out_np);
    k_bnfin<64><<<1, 128, 0, stream>>>(partials, g0, b0, bnp);
    k_mlp<1><<<NBLK_, TPB_, 0, stream>>>(points, xyz, newxyz, ball, W0T, W1T, W2T, bnp, partials, out_np);
    k_bnfin<64><<<1, 128, 0, stream>>>(partials, g1, b1, bnp + 256);
    k_mlp<2><<<NBLK_, TPB_, 0, stream>>>(points, xyz, newxyz, ball, W0T, W1T, W2T, bnp, partials, out_np);
    k_bnfin<128><<<1, 128, 0, stream>>>(partials, g2, b2, bnp + 512);
    k_mlp<3><<<NBLK_, TPB_, 0, stream>>>(points, xyz, newxyz, ball, W0T, W1T, W2T, bnp, partials, out_np);
}

// Round 6
// 1930.179 us; speedup vs baseline: 1.9534x; 1.0001x over previous
//
#include <hip/hip_runtime.h>
#include <cstdint>
#include <cstddef>

namespace {
constexpr int B_ = 16;
constexpr int N_ = 4096;
constexpr int D_ = 64;
constexpr int M_ = 1024;
constexpr int S_ = 32;
constexpr int NROWS_ = B_ * M_ * S_;   // 524288
constexpr int TPB_ = 128;
constexpr int NBLK_ = NROWS_ / TPB_;   // 4096
constexpr float RR_ = 0.04f;

// ws offsets (bytes)
constexpr size_t OFF_SQN  = 0;                                   // 262144
constexpr size_t OFF_FPS  = 262144;                              // 65536
constexpr size_t OFF_BALL = 327680;                              // 2097152
constexpr size_t OFF_W0T  = 2424832;                             // 17152
constexpr size_t OFF_W1T  = OFF_W0T + 67 * 64 * 4;               // 16384
constexpr size_t OFF_W2T  = OFF_W1T + 64 * 64 * 4;               // 32768
constexpr size_t OFF_PART = OFF_W2T + 64 * 128 * 4;              // 4096*256*4
constexpr size_t OFF_BNP  = OFF_PART + (size_t)NBLK_ * 256 * 4;  // 3072
// activation caches (used only if ws_size permits; f32 round-trip is exact)
constexpr size_t OFF_H0   = (OFF_BNP + 3072 + 255) & ~(size_t)255;
constexpr size_t H_SZ     = (size_t)NROWS_ * 64 * 4;             // 134,217,728
constexpr size_t OFF_H1   = OFF_H0 + H_SZ;
constexpr size_t NEED1    = OFF_H1 + H_SZ;                       // ~275 MB
constexpr size_t OFF_H2   = OFF_H1 + H_SZ;
constexpr size_t H2_SZ    = (size_t)NROWS_ * 128 * 4;            // 268,435,456
constexpr size_t NEED2    = OFF_H2 + H2_SZ;                      // ~544 MB
}

// non-contractible multiply (separately-rounded product), scheduler-friendly
__device__ __forceinline__ float mul_nr(float a, float b) {
    float p = a * b;
    asm("" : "+v"(p));
    return p;
}
// volatile variant kept for the PROVEN-bitwise decision kernels (zero-risk)
__device__ __forceinline__ float mul_nf(float a, float b) {
    float p = a * b;
    asm volatile("" : "+v"(p));
    return p;
}

// DPP lane move: result = src[selected lane] per dpp ctrl (VALU-rate, no LDS)
template <int CTRL>
__device__ __forceinline__ float dpp_movf(float x) {
    return __int_as_float(
        __builtin_amdgcn_update_dpp(0, __float_as_int(x), CTRL, 0xF, 0xF, true));
}
__device__ __forceinline__ float xor_exch(float x, int k) {
    if (k == 0) return dpp_movf<0xB1>(x);   // quad_perm [1,0,3,2]
    if (k == 1) return dpp_movf<0x4E>(x);   // quad_perm [2,3,0,1]
    return __shfl_xor(x, 1 << k);
}

// ---------------------------------------------------------------- fold reduce
// Per-wave transpose-reduce: lane L holds v[0..63]; after fold, value at lane
// L = op over the wave's 64 rows of channel L. Mutates cur.
__device__ __forceinline__ float fold_sum_wave(float* cur, int lane) {
#pragma unroll
    for (int k = 0; k < 6; k++) {
        const bool hi = (lane >> k) & 1;
#pragma unroll
        for (int m = 0; m < (32 >> k); m++) {
            const float a = cur[2 * m], b = cur[2 * m + 1];
            const float keep = hi ? b : a;
            const float give = hi ? a : b;
            const float got = xor_exch(give, k);
            cur[m] = keep + got;
        }
    }
    return cur[0];
}

__device__ __forceinline__ void fold_max_half(float* cur, int lane, float& r0, float& r1) {
#pragma unroll
    for (int k = 0; k < 5; k++) {
        const bool hi = (lane >> k) & 1;
#pragma unroll
        for (int m = 0; m < (32 >> k); m++) {
            const float a = cur[2 * m], b = cur[2 * m + 1];
            const float keep = hi ? b : a;
            const float give = hi ? a : b;
            const float got = xor_exch(give, k);
            cur[m] = fmaxf(keep, got);
        }
    }
    r0 = cur[0]; r1 = cur[1];
}

// ---------------------------------------------------------------- sqnorm
__global__ __launch_bounds__(256) void k_sqnorm(const float* __restrict__ xyz,
                                                float* __restrict__ sqn) {
    int i = blockIdx.x * 256 + threadIdx.x;
    if (i >= B_ * N_) return;
    float x = xyz[3 * i], y = xyz[3 * i + 1], z = xyz[3 * i + 2];
    sqn[i] = (mul_nf(x, x) + mul_nf(y, y)) + mul_nf(z, z);
}

// ---------------------------------------------------------------- FPS (proven)
__global__ __launch_bounds__(512) void k_fps(const float* __restrict__ xyz,
                                             int* __restrict__ fps_idx) {
    const int b = blockIdx.x, t = threadIdx.x;
    const int lane = t & 63, w = t >> 6;
    const float* xb = xyz + (size_t)b * N_ * 3;
    __shared__ float pts[N_ * 3];                 // 48 KB
    __shared__ unsigned long long slots[2][8];
    for (int i = t; i < N_ * 3; i += 512) pts[i] = xb[i];
    __syncthreads();

    const int n0 = t * 8;
    float px[8], py[8], pz[8], dist[8];
#pragma unroll
    for (int k = 0; k < 8; k++) {
        px[k] = pts[3 * (n0 + k)];
        py[k] = pts[3 * (n0 + k) + 1];
        pz[k] = pts[3 * (n0 + k) + 2];
        dist[k] = 1e10f;
    }

    int far = 0;
    for (int i = 0; i < M_; i++) {
        if (t == 0) fps_idx[b * M_ + i] = far;    // emit BEFORE update
        const float c0 = pts[3 * far], c1 = pts[3 * far + 1], c2 = pts[3 * far + 2];
        float bestv = -1.0f; int bestn = n0;
#pragma unroll
        for (int k = 0; k < 8; k++) {
            const float d0 = px[k] - c0, d1 = py[k] - c1, d2 = pz[k] - c2;
            const float dd = (mul_nr(d0, d0) + mul_nr(d1, d1)) + mul_nr(d2, d2);
            const float dm = fminf(dist[k], dd);
            dist[k] = dm;
            if (dm > bestv) { bestv = dm; bestn = n0 + k; }   // strict > keeps first
        }
        float m = bestv;
        m = fmaxf(m, dpp_movf<0x111>(m));
        m = fmaxf(m, dpp_movf<0x112>(m));
        m = fmaxf(m, dpp_movf<0x114>(m));
        m = fmaxf(m, dpp_movf<0x118>(m));
        m = fmaxf(m, dpp_movf<0x142>(m));
        m = fmaxf(m, dpp_movf<0x143>(m));
        const float wmax = __int_as_float(
            __builtin_amdgcn_readlane(__float_as_int(m), 63));
        const unsigned long long mk = __ballot(bestv == wmax);
        const int src = __ffsll((long long)mk) - 1;
        const int wn = __builtin_amdgcn_readlane(bestn, src);
        if (lane == 0)
            slots[i & 1][w] =
                ((unsigned long long)__float_as_uint(wmax) << 32) | (unsigned)(~wn);
        __syncthreads();
        const unsigned long long* sl = slots[i & 1];
        const unsigned long long s0 = sl[0], s1 = sl[1], s2 = sl[2], s3 = sl[3];
        const unsigned long long s4 = sl[4], s5 = sl[5], s6 = sl[6], s7 = sl[7];
        const unsigned long long a0 = s0 > s1 ? s0 : s1;
        const unsigned long long a1 = s2 > s3 ? s2 : s3;
        const unsigned long long a2 = s4 > s5 ? s4 : s5;
        const unsigned long long a3 = s6 > s7 ? s6 : s7;
        const unsigned long long b0 = a0 > a1 ? a0 : a1;
        const unsigned long long b1 = a2 > a3 ? a2 : a3;
        const unsigned long long bb = b0 > b1 ? b0 : b1;
        far = (int)(~(unsigned)bb);
    }
}

// ---------------------------------------------------------------- gather new_xyz
__global__ __launch_bounds__(256) void k_newxyz(const float* __restrict__ xyz,
                                                const int* __restrict__ fps_idx,
                                                float* __restrict__ newxyz) {
    int i = blockIdx.x * 256 + threadIdx.x;
    if (i >= B_ * M_) return;
    int b = i >> 10;
    int f = fps_idx[i];
    const float* p = xyz + ((size_t)b * N_ + f) * 3;
    newxyz[3 * i] = p[0]; newxyz[3 * i + 1] = p[1]; newxyz[3 * i + 2] = p[2];
}

// ---------------------------------------------------------------- ball query (bitwise-frozen)
__global__ __launch_bounds__(256) void k_ball(const float* __restrict__ xyz,
                                              const float* __restrict__ sqn,
                                              const int* __restrict__ fps_idx,
                                              const float* __restrict__ newxyz,
                                              int* __restrict__ ball) {
    const int w = threadIdx.x >> 6, lane = threadIdx.x & 63;
    const int q = blockIdx.x * 4 + w;
    const int b = q >> 10;
    __shared__ int buf[4][32];
    const float* xb = xyz + (size_t)b * N_ * 3;
    const float* sb = sqn + (size_t)b * N_;
    const float q0 = newxyz[3 * q], q1 = newxyz[3 * q + 1], q2 = newxyz[3 * q + 2];
    const float sq = sb[fps_idx[q]];

    int cnt = 0;
    for (int base = 0; base < N_ && cnt < 32; base += 64) {
        const int n = base + lane;
        const float p0 = xb[3 * n], p1 = xb[3 * n + 1], p2 = xb[3 * n + 2];
        float dot = fmaf(q2, p2, fmaf(q1, p1, q0 * p0));   // ascending FMA (proven)
        float tt = -2.0f * dot;
        tt = tt + sq;
        tt = tt + sb[n];
        const bool pred = !(tt > RR_);
        const unsigned long long mask = __ballot(pred);
        const int pos = cnt + __popcll(mask & ((1ull << lane) - 1ull));
        if (pred && pos < 32) buf[w][pos] = n;
        cnt += (int)__popcll(mask);
    }
    __syncthreads();
    if (lane < 32) {
        int e = buf[w][(lane < cnt) ? lane : 0];
        ball[(size_t)q * 32 + lane] = e;
    }
}

// ---------------------------------------------------------------- weight transpose
__global__ __launch_bounds__(256) void k_wtrans(const float* __restrict__ W0,
                                                const float* __restrict__ W1,
                                                const float* __restrict__ W2,
                                                float* __restrict__ W0T,
                                                float* __restrict__ W1T,
                                                float* __restrict__ W2T) {
    int t = blockIdx.x * 256 + threadIdx.x;
    if (t < 64 * 67) { int o = t / 67, c = t % 67; W0T[c * 64 + o] = W0[t]; }
    if (t < 64 * 64) { int o = t / 64, c = t % 64; W1T[c * 64 + o] = W1[t]; }
    if (t < 128 * 64) { int o = t / 64, c = t % 64; W2T[c * 128 + o] = W2[t]; }
}

// ================================================================ shared GEMM0
__device__ __forceinline__ void gemm0_row(
    const float* __restrict__ points, const float* __restrict__ xyz,
    const float* __restrict__ newxyz, const int* __restrict__ ball,
    const float* __restrict__ W0T, int r, float* h0) {
    const int b = r >> 15;
    const int q = r >> 5;
    const int g = ball[r];
    const float* prow = points + ((size_t)(b * N_) + g) * D_;
    const float xg0 = xyz[((size_t)b * N_ + g) * 3 + 0] - newxyz[(size_t)q * 3 + 0];
    const float xg1 = xyz[((size_t)b * N_ + g) * 3 + 1] - newxyz[(size_t)q * 3 + 1];
    const float xg2 = xyz[((size_t)b * N_ + g) * 3 + 2] - newxyz[(size_t)q * 3 + 2];

#pragma unroll
    for (int o = 0; o < 64; o++) h0[o] = 0.f;
    for (int c = 0; c < 64; c += 4) {
        const float4 xv = *reinterpret_cast<const float4*>(prow + c);
        const float xs[4] = {xv.x, xv.y, xv.z, xv.w};
#pragma unroll
        for (int j = 0; j < 4; j++) {
            const float xc = xs[j];
            const float* wr = W0T + (c + j) * 64;
#pragma unroll
            for (int o = 0; o < 64; o++) h0[o] = fmaf(xc, wr[o], h0[o]);
        }
    }
    const float* wa = W0T + 64 * 64;
    const float* wb = W0T + 65 * 64;
    const float* wc = W0T + 66 * 64;
#pragma unroll
    for (int o = 0; o < 64; o++) h0[o] = fmaf(xg0, wa[o], h0[o]);
#pragma unroll
    for (int o = 0; o < 64; o++) h0[o] = fmaf(xg1, wb[o], h0[o]);
#pragma unroll
    for (int o = 0; o < 64; o++) h0[o] = fmaf(xg2, wc[o], h0[o]);
}

// ================================================================ CACHED PATH
// stage 0: GEMM0 -> store h0 + stats0
__global__ __launch_bounds__(TPB_) void k_c0(
    const float* __restrict__ points, const float* __restrict__ xyz,
    const float* __restrict__ newxyz, const int* __restrict__ ball,
    const float* __restrict__ W0T, float* __restrict__ partials,
    float* __restrict__ h0buf) {
    const int t = threadIdx.x, lane = t & 63, w = t >> 6;
    const int r = blockIdx.x * TPB_ + t;
    float h0[64];
    gemm0_row(points, xyz, newxyz, ball, W0T, r, h0);

    float4* dst = (float4*)(h0buf + (size_t)r * 64);
#pragma unroll
    for (int j = 0; j < 16; j++)
        dst[j] = make_float4(h0[4 * j], h0[4 * j + 1], h0[4 * j + 2], h0[4 * j + 3]);

    __shared__ float ssum[2][64], ssq[2][64];
    float tmp[64];
#pragma unroll
    for (int i = 0; i < 64; i++) tmp[i] = h0[i] * h0[i];
    const float s = fold_sum_wave(h0, lane);
    const float sq = fold_sum_wave(tmp, lane);
    ssum[w][lane] = s; ssq[w][lane] = sq;
    __syncthreads();
    if (t < 64) {
        partials[(size_t)blockIdx.x * 256 + t] = ssum[0][t] + ssum[1][t];
        partials[(size_t)blockIdx.x * 256 + 128 + t] = ssq[0][t] + ssq[1][t];
    }
}

// stage 1: load h0 -> bn0+relu -> GEMM1 -> store h1 + stats1
__global__ __launch_bounds__(TPB_) void k_c1(
    const float* __restrict__ h0buf, const float* __restrict__ W1T,
    const float* __restrict__ bnp, float* __restrict__ partials,
    float* __restrict__ h1buf) {
    const int t = threadIdx.x, lane = t & 63, w = t >> 6;
    const int r = blockIdx.x * TPB_ + t;
    __shared__ float tile[TPB_ * 65];

    const float4* src = (const float4*)(h0buf + (size_t)r * 64);
#pragma unroll
    for (int j = 0; j < 16; j++) {
        const float4 v = src[j];
        tile[t * 65 + 4 * j + 0] = fmaxf(0.f, fmaf(v.x, bnp[4 * j + 0], bnp[128 + 4 * j + 0]));
        tile[t * 65 + 4 * j + 1] = fmaxf(0.f, fmaf(v.y, bnp[4 * j + 1], bnp[128 + 4 * j + 1]));
        tile[t * 65 + 4 * j + 2] = fmaxf(0.f, fmaf(v.z, bnp[4 * j + 2], bnp[128 + 4 * j + 2]));
        tile[t * 65 + 4 * j + 3] = fmaxf(0.f, fmaf(v.w, bnp[4 * j + 3], bnp[128 + 4 * j + 3]));
    }

    float h1[64];
#pragma unroll
    for (int o = 0; o < 64; o++) h1[o] = 0.f;
    for (int c = 0; c < 64; c++) {
        const float xc = tile[t * 65 + c];
        const float* wr = W1T + c * 64;
#pragma unroll
        for (int o = 0; o < 64; o++) h1[o] = fmaf(xc, wr[o], h1[o]);
    }

    float4* dst = (float4*)(h1buf + (size_t)r * 64);
#pragma unroll
    for (int j = 0; j < 16; j++)
        dst[j] = make_float4(h1[4 * j], h1[4 * j + 1], h1[4 * j + 2], h1[4 * j + 3]);

    __shared__ float ssum[2][64], ssq[2][64];
    float tmp[64];
#pragma unroll
    for (int i = 0; i < 64; i++) tmp[i] = h1[i] * h1[i];
    const float s = fold_sum_wave(h1, lane);
    const float sq = fold_sum_wave(tmp, lane);
    ssum[w][lane] = s; ssq[w][lane] = sq;
    __syncthreads();
    if (t < 64) {
        partials[(size_t)blockIdx.x * 256 + t] = ssum[0][t] + ssum[1][t];
        partials[(size_t)blockIdx.x * 256 + 128 + t] = ssq[0][t] + ssq[1][t];
    }
}

// stage 2: load h1 -> bn1+relu -> GEMM2 -> (optional h2 store) + stats2
template <bool STORE_H2>
__global__ __launch_bounds__(TPB_) void k_c2(
    const float* __restrict__ h1buf, const float* __restrict__ W2T,
    const float* __restrict__ bnp, float* __restrict__ partials,
    float* __restrict__ h2buf) {
    const int t = threadIdx.x, lane = t & 63, w = t >> 6;
    const int r = blockIdx.x * TPB_ + t;
    __shared__ float tile[TPB_ * 65];

    const float4* src = (const float4*)(h1buf + (size_t)r * 64);
    const float* bn1 = bnp + 256;
#pragma unroll
    for (int j = 0; j < 16; j++) {
        const float4 v = src[j];
        tile[t * 65 + 4 * j + 0] = fmaxf(0.f, fmaf(v.x, bn1[4 * j + 0], bn1[128 + 4 * j + 0]));
        tile[t * 65 + 4 * j + 1] = fmaxf(0.f, fmaf(v.y, bn1[4 * j + 1], bn1[128 + 4 * j + 1]));
        tile[t * 65 + 4 * j + 2] = fmaxf(0.f, fmaf(v.z, bn1[4 * j + 2], bn1[128 + 4 * j + 2]));
        tile[t * 65 + 4 * j + 3] = fmaxf(0.f, fmaf(v.w, bn1[4 * j + 3], bn1[128 + 4 * j + 3]));
    }

    float h2[128];
#pragma unroll
    for (int o = 0; o < 128; o++) h2[o] = 0.f;
    for (int c = 0; c < 64; c++) {
        const float hc = tile[t * 65 + c];
        const float* wr = W2T + c * 128;
#pragma unroll
        for (int o = 0; o < 128; o++) h2[o] = fmaf(hc, wr[o], h2[o]);
    }

    if constexpr (STORE_H2) {
        float4* dst = (float4*)(h2buf + (size_t)r * 128);
#pragma unroll
        for (int j = 0; j < 32; j++)
            dst[j] = make_float4(h2[4 * j], h2[4 * j + 1], h2[4 * j + 2], h2[4 * j + 3]);
    }

    __shared__ float s2[2][128], q2[2][128];
    float tmp[64];
#pragma unroll
    for (int i = 0; i < 64; i++) tmp[i] = h2[i] * h2[i];
    const float sA = fold_sum_wave(h2, lane);
    const float qA = fold_sum_wave(tmp, lane);
    s2[w][lane] = sA; q2[w][lane] = qA;
#pragma unroll
    for (int i = 0; i < 64; i++) tmp[i] = h2[64 + i] * h2[64 + i];
    const float sB = fold_sum_wave(h2 + 64, lane);
    const float qB = fold_sum_wave(tmp, lane);
    s2[w][64 + lane] = sB; q2[w][64 + lane] = qB;
    __syncthreads();
    if (t < 128) {
        partials[(size_t)blockIdx.x * 256 + t] = s2[0][t] + s2[1][t];
        partials[(size_t)blockIdx.x * 256 + 128 + t] = q2[0][t] + q2[1][t];
    }
}

// stage 3 (tier1): load h1 -> bn1+relu -> GEMM2 -> bn2+relu -> max -> out
__global__ __launch_bounds__(TPB_) void k_c3(
    const float* __restrict__ h1buf, const float* __restrict__ W2T,
    const float* __restrict__ bnp, float* __restrict__ out_np) {
    const int t = threadIdx.x, lane = t & 63, w = t >> 6;
    const int r = blockIdx.x * TPB_ + t;
    __shared__ float tile[TPB_ * 65];

    const float4* src = (const float4*)(h1buf + (size_t)r * 64);
    const float* bn1 = bnp + 256;
#pragma unroll
    for (int j = 0; j < 16; j++) {
        const float4 v = src[j];
        tile[t * 65 + 4 * j + 0] = fmaxf(0.f, fmaf(v.x, bn1[4 * j + 0], bn1[128 + 4 * j + 0]));
        tile[t * 65 + 4 * j + 1] = fmaxf(0.f, fmaf(v.y, bn1[4 * j + 1], bn1[128 + 4 * j + 1]));
        tile[t * 65 + 4 * j + 2] = fmaxf(0.f, fmaf(v.z, bn1[4 * j + 2], bn1[128 + 4 * j + 2]));
        tile[t * 65 + 4 * j + 3] = fmaxf(0.f, fmaf(v.w, bn1[4 * j + 3], bn1[128 + 4 * j + 3]));
    }

    float h2[128];
#pragma unroll
    for (int o = 0; o < 128; o++) h2[o] = 0.f;
    for (int c = 0; c < 64; c++) {
        const float hc = tile[t * 65 + c];
        const float* wr = W2T + c * 128;
#pragma unroll
        for (int o = 0; o < 128; o++) h2[o] = fmaf(hc, wr[o], h2[o]);
    }

    const float* bn2 = bnp + 512;
#pragma unroll
    for (int o = 0; o < 128; o++)
        h2[o] = fmaxf(0.f, fmaf(h2[o], bn2[o], bn2[128 + o]));

    const int qq = blockIdx.x * 4 + w * 2 + (lane >> 5);
    float r0, r1;
    fold_max_half(h2, lane, r0, r1);
    out_np[(size_t)qq * 128 + (lane & 31)] = r0;
    out_np[(size_t)qq * 128 + 32 + (lane & 31)] = r1;
    fold_max_half(h2 + 64, lane, r0, r1);
    out_np[(size_t)qq * 128 + 64 + (lane & 31)] = r0;
    out_np[(size_t)qq * 128 + 96 + (lane & 31)] = r1;
}

// stage 3 (tier2): load h2 -> bn2+relu -> max -> out (memory-bound)
__global__ __launch_bounds__(TPB_) void k_c3s(
    const float* __restrict__ h2buf, const float* __restrict__ bnp,
    float* __restrict__ out_np) {
    const int t = threadIdx.x, lane = t & 63, w = t >> 6;
    const int r = blockIdx.x * TPB_ + t;
    const float* bn2 = bnp + 512;

    float h2[128];
    const float4* src = (const float4*)(h2buf + (size_t)r * 128);
#pragma unroll
    for (int j = 0; j < 32; j++) {
        const float4 v = src[j];
        h2[4 * j + 0] = fmaxf(0.f, fmaf(v.x, bn2[4 * j + 0], bn2[128 + 4 * j + 0]));
        h2[4 * j + 1] = fmaxf(0.f, fmaf(v.y, bn2[4 * j + 1], bn2[128 + 4 * j + 1]));
        h2[4 * j + 2] = fmaxf(0.f, fmaf(v.z, bn2[4 * j + 2], bn2[128 + 4 * j + 2]));
        h2[4 * j + 3] = fmaxf(0.f, fmaf(v.w, bn2[4 * j + 3], bn2[128 + 4 * j + 3]));
    }

    const int qq = blockIdx.x * 4 + w * 2 + (lane >> 5);
    float r0, r1;
    fold_max_half(h2, lane, r0, r1);
    out_np[(size_t)qq * 128 + (lane & 31)] = r0;
    out_np[(size_t)qq * 128 + 32 + (lane & 31)] = r1;
    fold_max_half(h2 + 64, lane, r0, r1);
    out_np[(size_t)qq * 128 + 64 + (lane & 31)] = r0;
    out_np[(size_t)qq * 128 + 96 + (lane & 31)] = r1;
}

// ================================================================ FALLBACK PATH
template <int STAGE>
__global__ __launch_bounds__(TPB_) void k_mlp(
    const float* __restrict__ points, const float* __restrict__ xyz,
    const float* __restrict__ newxyz, const int* __restrict__ ball,
    const float* __restrict__ W0T, const float* __restrict__ W1T,
    const float* __restrict__ W2T, const float* __restrict__ bnp,
    float* __restrict__ partials, float* __restrict__ out_np) {
    const int t = threadIdx.x;
    const int lane = t & 63, w = t >> 6;
    const int r = blockIdx.x * TPB_ + t;

    float h0[64];
    gemm0_row(points, xyz, newxyz, ball, W0T, r, h0);

    if constexpr (STAGE == 0) {
        __shared__ float ssum[2][64], ssq[2][64];
        float tmp[64];
#pragma unroll
        for (int i = 0; i < 64; i++) tmp[i] = h0[i] * h0[i];
        const float s = fold_sum_wave(h0, lane);
        const float sq = fold_sum_wave(tmp, lane);
        ssum[w][lane] = s; ssq[w][lane] = sq;
        __syncthreads();
        if (t < 64) {
            partials[(size_t)blockIdx.x * 256 + t] = ssum[0][t] + ssum[1][t];
            partials[(size_t)blockIdx.x * 256 + 128 + t] = ssq[0][t] + ssq[1][t];
        }
        return;
    } else {
        __shared__ float tile[TPB_ * 65];
#pragma unroll
        for (int o = 0; o < 64; o++) {
            const float v = fmaxf(0.f, fmaf(h0[o], bnp[o], bnp[128 + o]));
            tile[t * 65 + o] = v;
        }

        float h1[64];
#pragma unroll
        for (int o = 0; o < 64; o++) h1[o] = 0.f;
        for (int c = 0; c < 64; c++) {
            const float xc = tile[t * 65 + c];
            const float* wr = W1T + c * 64;
#pragma unroll
            for (int o = 0; o < 64; o++) h1[o] = fmaf(xc, wr[o], h1[o]);
        }

        if constexpr (STAGE == 1) {
            __shared__ float ssum[2][64], ssq[2][64];
            float tmp[64];
#pragma unroll
            for (int i = 0; i < 64; i++) tmp[i] = h1[i] * h1[i];
            const float s = fold_sum_wave(h1, lane);
            const float sq = fold_sum_wave(tmp, lane);
            ssum[w][lane] = s; ssq[w][lane] = sq;
            __syncthreads();
            if (t < 64) {
                partials[(size_t)blockIdx.x * 256 + t] = ssum[0][t] + ssum[1][t];
                partials[(size_t)blockIdx.x * 256 + 128 + t] = ssq[0][t] + ssq[1][t];
            }
            return;
        } else {
#pragma unroll
            for (int o = 0; o < 64; o++) {
                const float v = fmaxf(0.f, fmaf(h1[o], bnp[256 + o], bnp[256 + 128 + o]));
                tile[t * 65 + o] = v;
            }

            float h2[128];
#pragma unroll
            for (int o = 0; o < 128; o++) h2[o] = 0.f;
            for (int c = 0; c < 64; c++) {
                const float hc = tile[t * 65 + c];
                const float* wr = W2T + c * 128;
#pragma unroll
                for (int o = 0; o < 128; o++) h2[o] = fmaf(hc, wr[o], h2[o]);
            }

            if constexpr (STAGE == 2) {
                __shared__ float s2[2][128], q2[2][128];
                float tmp[64];
#pragma unroll
                for (int i = 0; i < 64; i++) tmp[i] = h2[i] * h2[i];
                const float sA = fold_sum_wave(h2, lane);
                const float qA = fold_sum_wave(tmp, lane);
                s2[w][lane] = sA; q2[w][lane] = qA;
#pragma unroll
                for (int i = 0; i < 64; i++) tmp[i] = h2[64 + i] * h2[64 + i];
                const float sB = fold_sum_wave(h2 + 64, lane);
                const float qB = fold_sum_wave(tmp, lane);
                s2[w][64 + lane] = sB; q2[w][64 + lane] = qB;
                __syncthreads();
                if (t < 128) {
                    partials[(size_t)blockIdx.x * 256 + t] = s2[0][t] + s2[1][t];
                    partials[(size_t)blockIdx.x * 256 + 128 + t] = q2[0][t] + q2[1][t];
                }
                return;
            } else {
                const float* bn2 = bnp + 512;
#pragma unroll
                for (int o = 0; o < 128; o++)
                    h2[o] = fmaxf(0.f, fmaf(h2[o], bn2[o], bn2[128 + o]));

                const int qq = blockIdx.x * 4 + w * 2 + (lane >> 5);
                float r0, r1;
                fold_max_half(h2, lane, r0, r1);
                out_np[(size_t)qq * 128 + (lane & 31)] = r0;
                out_np[(size_t)qq * 128 + 32 + (lane & 31)] = r1;
                fold_max_half(h2 + 64, lane, r0, r1);
                out_np[(size_t)qq * 128 + 64 + (lane & 31)] = r0;
                out_np[(size_t)qq * 128 + 96 + (lane & 31)] = r1;
                return;
            }
        }
    }
}

// ---------------------------------------------------------------- BN finalize
template <int C>
__global__ __launch_bounds__(128) void k_bnfin(const float* __restrict__ partials,
                                               const float* __restrict__ gw,
                                               const float* __restrict__ bw,
                                               float* __restrict__ bnpL) {
    const int t = threadIdx.x;
    if (t >= C) return;
    double Ssum = 0.0, Q = 0.0;
    for (int blk = 0; blk < NBLK_; blk++) {
        Ssum += (double)partials[(size_t)blk * 256 + t];
        Q += (double)partials[(size_t)blk * 256 + 128 + t];
    }
    const double mean = Ssum / (double)NROWS_;
    const double var = Q / (double)NROWS_ - mean * mean;
    const float sc = (float)((double)gw[t] / sqrt(var + 1e-5));
    const float sh = (float)((double)bw[t] - mean * (double)sc);
    bnpL[t] = sc;
    bnpL[128 + t] = sh;
}

// ---------------------------------------------------------------- launch
extern "C" void kernel_launch(void* const* d_in, const int* in_sizes, int n_in,
                              void* d_out, int out_size, void* d_ws, size_t ws_size,
                              hipStream_t stream) {
    const float* xyz = (const float*)d_in[0];
    const float* points = (const float*)d_in[1];
    const float* W0 = (const float*)d_in[2];
    const float* g0 = (const float*)d_in[3];
    const float* b0 = (const float*)d_in[4];
    const float* W1 = (const float*)d_in[5];
    const float* g1 = (const float*)d_in[6];
    const float* b1 = (const float*)d_in[7];
    const float* W2 = (const float*)d_in[8];
    const float* g2 = (const float*)d_in[9];
    const float* b2 = (const float*)d_in[10];

    float* out = (float*)d_out;
    float* newxyz = out;
    float* out_np = out + B_ * M_ * 3;

    char* ws = (char*)d_ws;
    float* sqn = (float*)(ws + OFF_SQN);
    int* fps_idx = (int*)(ws + OFF_FPS);
    int* ball = (int*)(ws + OFF_BALL);
    float* W0T = (float*)(ws + OFF_W0T);
    float* W1T = (float*)(ws + OFF_W1T);
    float* W2T = (float*)(ws + OFF_W2T);
    float* partials = (float*)(ws + OFF_PART);
    float* bnp = (float*)(ws + OFF_BNP);
    float* h0buf = (float*)(ws + OFF_H0);
    float* h1buf = (float*)(ws + OFF_H1);
    float* h2buf = (float*)(ws + OFF_H2);

    k_sqnorm<<<(B_ * N_ + 255) / 256, 256, 0, stream>>>(xyz, sqn);
    k_fps<<<B_, 512, 0, stream>>>(xyz, fps_idx);
    k_newxyz<<<(B_ * M_ + 255) / 256, 256, 0, stream>>>(xyz, fps_idx, newxyz);
    k_ball<<<B_ * M_ / 4, 256, 0, stream>>>(xyz, sqn, fps_idx, newxyz, ball);
    k_wtrans<<<32, 256, 0, stream>>>(W0, W1, W2, W0T, W1T, W2T);

    if (ws_size >= NEED1) {
        // cached-activation path (bit-identical arithmetic; f32 round-trip exact)
        k_c0<<<NBLK_, TPB_, 0, stream>>>(points, xyz, newxyz, ball, W0T, partials, h0buf);
        k_bnfin<64><<<1, 128, 0, stream>>>(partials, g0, b0, bnp);
        k_c1<<<NBLK_, TPB_, 0, stream>>>(h0buf, W1T, bnp, partials, h1buf);
        k_bnfin<64><<<1, 128, 0, stream>>>(partials, g1, b1, bnp + 256);
        if (ws_size >= NEED2) {
            k_c2<true><<<NBLK_, TPB_, 0, stream>>>(h1buf, W2T, bnp, partials, h2buf);
            k_bnfin<128><<<1, 128, 0, stream>>>(partials, g2, b2, bnp + 512);
            k_c3s<<<NBLK_, TPB_, 0, stream>>>(h2buf, bnp, out_np);
        } else {
            k_c2<false><<<NBLK_, TPB_, 0, stream>>>(h1buf, W2T, bnp, partials, h2buf);
            k_bnfin<128><<<1, 128, 0, stream>>>(partials, g2, b2, bnp + 512);
            k_c3<<<NBLK_, TPB_, 0, stream>>>(h1buf, W2T, bnp, out_np);
        }
    } else {
        k_mlp<0><<<NBLK_, TPB_, 0, stream>>>(points, xyz, newxyz, ball, W0T, W1T, W2T, bnp, partials, out_np);
        k_bnfin<64><<<1, 128, 0, stream>>>(partials, g0, b0, bnp);
        k_mlp<1><<<NBLK_, TPB_, 0, stream>>>(points, xyz, newxyz, ball, W0T, W1T, W2T, bnp, partials, out_np);
        k_bnfin<64><<<1, 128, 0, stream>>>(partials, g1, b1, bnp + 256);
        k_mlp<2><<<NBLK_, TPB_, 0, stream>>>(points, xyz, newxyz, ball, W0T, W1T, W2T, bnp, partials, out_np);
        k_bnfin<128><<<1, 128, 0, stream>>>(partials, g2, b2, bnp + 512);
        k_mlp<3><<<NBLK_, TPB_, 0, stream>>>(points, xyz, newxyz, ball, W0T, W1T, W2T, bnp, partials, out_np);
    }
}

// Round 7
// 1597.439 us; speedup vs baseline: 2.3603x; 1.2083x over previous
//
#include <hip/hip_runtime.h>
#include <hip/hip_bf16.h>
#include <cstdint>
#include <cstddef>

namespace {
constexpr int B_ = 16;
constexpr int N_ = 4096;
constexpr int D_ = 64;
constexpr int M_ = 1024;
constexpr int S_ = 32;
constexpr int NROWS_ = B_ * M_ * S_;     // 524288
constexpr int TPB_ = 256;                // 4 waves
constexpr int NBLKM_ = NROWS_ / TPB_;    // 2048
constexpr float RR_ = 0.04f;

// ws offsets (bytes)
constexpr size_t OFF_SQN  = 0;                                    // 262144
constexpr size_t OFF_FPS  = 262144;                               // 65536
constexpr size_t OFF_BALL = 327680;                               // 2097152
constexpr size_t OFF_W0T  = 2424832;                              // 17152
constexpr size_t OFF_W1T  = OFF_W0T + 67 * 64 * 4;                // 16384
constexpr size_t OFF_W2T  = OFF_W1T + 64 * 64 * 4;                // 32768
constexpr size_t OFF_PART = OFF_W2T + 64 * 128 * 4;               // 2048*256*4
constexpr size_t OFF_BNP  = OFF_PART + (size_t)NBLKM_ * 256 * 4;  // 3072
// h1 activation cache (tier-selected at launch from ws_size; deterministic)
constexpr size_t OFF_H1   = (OFF_BNP + 3072 + 255) & ~(size_t)255;
constexpr size_t H1F_SZ   = (size_t)NROWS_ * 64 * 4;              // 134,217,728
constexpr size_t H1H_SZ   = (size_t)NROWS_ * 64 * 2;              // 67,108,864
constexpr size_t NEED_F32 = OFF_H1 + H1F_SZ;                      // ~132.4 MB
constexpr size_t NEED_BF16 = OFF_H1 + H1H_SZ;                     // ~68.4 MB
}

// non-contractible multiply (separately-rounded product), scheduler-friendly
__device__ __forceinline__ float mul_nr(float a, float b) {
    float p = a * b;
    asm("" : "+v"(p));
    return p;
}
// volatile variant kept for the PROVEN-bitwise decision kernels (zero-risk)
__device__ __forceinline__ float mul_nf(float a, float b) {
    float p = a * b;
    asm volatile("" : "+v"(p));
    return p;
}

// DPP lane move (VALU-rate cross-lane)
template <int CTRL>
__device__ __forceinline__ float dpp_movf(float x) {
    return __int_as_float(
        __builtin_amdgcn_update_dpp(0, __float_as_int(x), CTRL, 0xF, 0xF, true));
}
__device__ __forceinline__ float xor_exch(float x, int k) {
    if (k == 0) return dpp_movf<0xB1>(x);   // quad_perm [1,0,3,2]
    if (k == 1) return dpp_movf<0x4E>(x);   // quad_perm [2,3,0,1]
    return __shfl_xor(x, 1 << k);
}

// ---------------------------------------------------------------- fold reduce
__device__ __forceinline__ float fold_sum_wave(float* cur, int lane) {
#pragma unroll
    for (int k = 0; k < 6; k++) {
        const bool hi = (lane >> k) & 1;
#pragma unroll
        for (int m = 0; m < (32 >> k); m++) {
            const float a = cur[2 * m], b = cur[2 * m + 1];
            const float keep = hi ? b : a;
            const float give = hi ? a : b;
            const float got = xor_exch(give, k);
            cur[m] = keep + got;
        }
    }
    return cur[0];
}

__device__ __forceinline__ void fold_max_half(float* cur, int lane, float& r0, float& r1) {
#pragma unroll
    for (int k = 0; k < 5; k++) {
        const bool hi = (lane >> k) & 1;
#pragma unroll
        for (int m = 0; m < (32 >> k); m++) {
            const float a = cur[2 * m], b = cur[2 * m + 1];
            const float keep = hi ? b : a;
            const float give = hi ? a : b;
            const float got = xor_exch(give, k);
            cur[m] = fmaxf(keep, got);
        }
    }
    r0 = cur[0]; r1 = cur[1];
}

// bf16 pack/unpack (RNE)
__device__ __forceinline__ unsigned short f2bf(float f) {
    __hip_bfloat16 h = __float2bfloat16(f);
    return *reinterpret_cast<unsigned short*>(&h);
}
__device__ __forceinline__ float bf2f(unsigned short u) {
    __hip_bfloat16 h = *reinterpret_cast<__hip_bfloat16*>(&u);
    return __bfloat162float(h);
}

// ---------------------------------------------------------------- sqnorm
__global__ __launch_bounds__(256) void k_sqnorm(const float* __restrict__ xyz,
                                                float* __restrict__ sqn) {
    int i = blockIdx.x * 256 + threadIdx.x;
    if (i >= B_ * N_) return;
    float x = xyz[3 * i], y = xyz[3 * i + 1], z = xyz[3 * i + 2];
    sqn[i] = (mul_nf(x, x) + mul_nf(y, y)) + mul_nf(z, z);
}

// ---------------------------------------------------------------- FPS (proven)
__global__ __launch_bounds__(512) void k_fps(const float* __restrict__ xyz,
                                             int* __restrict__ fps_idx) {
    const int b = blockIdx.x, t = threadIdx.x;
    const int lane = t & 63, w = t >> 6;
    const float* xb = xyz + (size_t)b * N_ * 3;
    __shared__ float pts[N_ * 3];
    __shared__ unsigned long long slots[2][8];
    for (int i = t; i < N_ * 3; i += 512) pts[i] = xb[i];
    __syncthreads();

    const int n0 = t * 8;
    float px[8], py[8], pz[8], dist[8];
#pragma unroll
    for (int k = 0; k < 8; k++) {
        px[k] = pts[3 * (n0 + k)];
        py[k] = pts[3 * (n0 + k) + 1];
        pz[k] = pts[3 * (n0 + k) + 2];
        dist[k] = 1e10f;
    }

    int far = 0;
    for (int i = 0; i < M_; i++) {
        if (t == 0) fps_idx[b * M_ + i] = far;
        const float c0 = pts[3 * far], c1 = pts[3 * far + 1], c2 = pts[3 * far + 2];
        float bestv = -1.0f; int bestn = n0;
#pragma unroll
        for (int k = 0; k < 8; k++) {
            const float d0 = px[k] - c0, d1 = py[k] - c1, d2 = pz[k] - c2;
            const float dd = (mul_nr(d0, d0) + mul_nr(d1, d1)) + mul_nr(d2, d2);
            const float dm = fminf(dist[k], dd);
            dist[k] = dm;
            if (dm > bestv) { bestv = dm; bestn = n0 + k; }
        }
        float m = bestv;
        m = fmaxf(m, dpp_movf<0x111>(m));
        m = fmaxf(m, dpp_movf<0x112>(m));
        m = fmaxf(m, dpp_movf<0x114>(m));
        m = fmaxf(m, dpp_movf<0x118>(m));
        m = fmaxf(m, dpp_movf<0x142>(m));
        m = fmaxf(m, dpp_movf<0x143>(m));
        const float wmax = __int_as_float(
            __builtin_amdgcn_readlane(__float_as_int(m), 63));
        const unsigned long long mk = __ballot(bestv == wmax);
        const int src = __ffsll((long long)mk) - 1;
        const int wn = __builtin_amdgcn_readlane(bestn, src);
        if (lane == 0)
            slots[i & 1][w] =
                ((unsigned long long)__float_as_uint(wmax) << 32) | (unsigned)(~wn);
        __syncthreads();
        const unsigned long long* sl = slots[i & 1];
        const unsigned long long s0 = sl[0], s1 = sl[1], s2 = sl[2], s3 = sl[3];
        const unsigned long long s4 = sl[4], s5 = sl[5], s6 = sl[6], s7 = sl[7];
        const unsigned long long a0 = s0 > s1 ? s0 : s1;
        const unsigned long long a1 = s2 > s3 ? s2 : s3;
        const unsigned long long a2 = s4 > s5 ? s4 : s5;
        const unsigned long long a3 = s6 > s7 ? s6 : s7;
        const unsigned long long b0 = a0 > a1 ? a0 : a1;
        const unsigned long long b1 = a2 > a3 ? a2 : a3;
        const unsigned long long bb = b0 > b1 ? b0 : b1;
        far = (int)(~(unsigned)bb);
    }
}

// ---------------------------------------------------------------- gather new_xyz
__global__ __launch_bounds__(256) void k_newxyz(const float* __restrict__ xyz,
                                                const int* __restrict__ fps_idx,
                                                float* __restrict__ newxyz) {
    int i = blockIdx.x * 256 + threadIdx.x;
    if (i >= B_ * M_) return;
    int b = i >> 10;
    int f = fps_idx[i];
    const float* p = xyz + ((size_t)b * N_ + f) * 3;
    newxyz[3 * i] = p[0]; newxyz[3 * i + 1] = p[1]; newxyz[3 * i + 2] = p[2];
}

// ---------------------------------------------------------------- ball query (bitwise-frozen)
__global__ __launch_bounds__(256) void k_ball(const float* __restrict__ xyz,
                                              const float* __restrict__ sqn,
                                              const int* __restrict__ fps_idx,
                                              const float* __restrict__ newxyz,
                                              int* __restrict__ ball) {
    const int w = threadIdx.x >> 6, lane = threadIdx.x & 63;
    const int q = blockIdx.x * 4 + w;
    const int b = q >> 10;
    __shared__ int buf[4][32];
    const float* xb = xyz + (size_t)b * N_ * 3;
    const float* sb = sqn + (size_t)b * N_;
    const float q0 = newxyz[3 * q], q1 = newxyz[3 * q + 1], q2 = newxyz[3 * q + 2];
    const float sq = sb[fps_idx[q]];

    int cnt = 0;
    for (int base = 0; base < N_ && cnt < 32; base += 64) {
        const int n = base + lane;
        const float p0 = xb[3 * n], p1 = xb[3 * n + 1], p2 = xb[3 * n + 2];
        float dot = fmaf(q2, p2, fmaf(q1, p1, q0 * p0));
        float tt = -2.0f * dot;
        tt = tt + sq;
        tt = tt + sb[n];
        const bool pred = !(tt > RR_);
        const unsigned long long mask = __ballot(pred);
        const int pos = cnt + __popcll(mask & ((1ull << lane) - 1ull));
        if (pred && pos < 32) buf[w][pos] = n;
        cnt += (int)__popcll(mask);
    }
    __syncthreads();
    if (lane < 32) {
        int e = buf[w][(lane < cnt) ? lane : 0];
        ball[(size_t)q * 32 + lane] = e;
    }
}

// ---------------------------------------------------------------- weight transpose
__global__ __launch_bounds__(256) void k_wtrans(const float* __restrict__ W0,
                                                const float* __restrict__ W1,
                                                const float* __restrict__ W2,
                                                float* __restrict__ W0T,
                                                float* __restrict__ W1T,
                                                float* __restrict__ W2T) {
    int t = blockIdx.x * 256 + threadIdx.x;
    if (t < 64 * 67) { int o = t / 67, c = t % 67; W0T[c * 64 + o] = W0[t]; }
    if (t < 64 * 64) { int o = t / 64, c = t % 64; W1T[c * 64 + o] = W1[t]; }
    if (t < 128 * 64) { int o = t / 64, c = t % 64; W2T[c * 128 + o] = W2[t]; }
}

// ================================================================ GEMM pieces
// weights live in LDS (uniform ds_read = broadcast, conflict-free); activations
// live in statically-indexed registers (c-loops fully unrolled).
__device__ __forceinline__ void stage_w(float* dst, const float* __restrict__ src,
                                        int n, int t) {
    for (int i = t; i < n; i += TPB_) dst[i] = src[i];
}

__device__ __forceinline__ void g0_row(
    const float* __restrict__ points, const float* __restrict__ xyz,
    const float* __restrict__ newxyz, const int* __restrict__ ball,
    const float* w0, int r, float* h0) {
    const int b = r >> 15;
    const int q = r >> 5;
    const int g = ball[r];
    const float* prow = points + ((size_t)(b * N_) + g) * D_;
    const float xg0 = xyz[((size_t)b * N_ + g) * 3 + 0] - newxyz[(size_t)q * 3 + 0];
    const float xg1 = xyz[((size_t)b * N_ + g) * 3 + 1] - newxyz[(size_t)q * 3 + 1];
    const float xg2 = xyz[((size_t)b * N_ + g) * 3 + 2] - newxyz[(size_t)q * 3 + 2];

#pragma unroll
    for (int o = 0; o < 64; o++) h0[o] = 0.f;
#pragma unroll
    for (int c = 0; c < 64; c += 4) {
        const float4 xv = *reinterpret_cast<const float4*>(prow + c);
        const float xs[4] = {xv.x, xv.y, xv.z, xv.w};
#pragma unroll
        for (int j = 0; j < 4; j++) {
            const float xc = xs[j];
            const float* wr = w0 + (c + j) * 64;
#pragma unroll
            for (int o = 0; o < 64; o++) h0[o] = fmaf(xc, wr[o], h0[o]);
        }
    }
#pragma unroll
    for (int o = 0; o < 64; o++) h0[o] = fmaf(xg0, w0[64 * 64 + o], h0[o]);
#pragma unroll
    for (int o = 0; o < 64; o++) h0[o] = fmaf(xg1, w0[65 * 64 + o], h0[o]);
#pragma unroll
    for (int o = 0; o < 64; o++) h0[o] = fmaf(xg2, w0[66 * 64 + o], h0[o]);
}

__device__ __forceinline__ void g1_row(const float* x, const float* w1, float* h1) {
#pragma unroll
    for (int o = 0; o < 64; o++) h1[o] = 0.f;
#pragma unroll
    for (int c = 0; c < 64; c++) {
        const float xc = x[c];
        const float* wr = w1 + c * 64;
#pragma unroll
        for (int o = 0; o < 64; o++) h1[o] = fmaf(xc, wr[o], h1[o]);
    }
}

__device__ __forceinline__ void g2_row(const float* x, const float* w2, float* h2) {
#pragma unroll
    for (int o = 0; o < 128; o++) h2[o] = 0.f;
#pragma unroll
    for (int c = 0; c < 64; c++) {
        const float xc = x[c];
        const float* wr = w2 + c * 128;
#pragma unroll
        for (int o = 0; o < 128; o++) h2[o] = fmaf(xc, wr[o], h2[o]);
    }
}

template <int NCH>
__device__ __forceinline__ void bn_relu(float* x, const float* __restrict__ bnp, int base) {
#pragma unroll
    for (int o = 0; o < NCH; o++)
        x[o] = fmaxf(0.f, fmaf(x[o], bnp[base + o], bnp[base + 128 + o]));
}

// stats: per-wave fold + 4-wave LDS combine
__device__ __forceinline__ void stats64_fold(float* h, int lane, int w, int t,
                                             float (*ssum)[64], float (*ssq)[64],
                                             float* dst) {
    float tmp[64];
#pragma unroll
    for (int i = 0; i < 64; i++) tmp[i] = h[i] * h[i];
    const float s = fold_sum_wave(h, lane);
    const float q = fold_sum_wave(tmp, lane);
    ssum[w][lane] = s; ssq[w][lane] = q;
    __syncthreads();
    if (t < 64) {
        dst[t] = ssum[0][t] + ssum[1][t] + ssum[2][t] + ssum[3][t];
        dst[128 + t] = ssq[0][t] + ssq[1][t] + ssq[2][t] + ssq[3][t];
    }
}

__device__ __forceinline__ void stats128_fold(float* h2, int lane, int w, int t,
                                              float (*ssum)[128], float (*ssq)[128],
                                              float* dst) {
    float tmp[64];
#pragma unroll
    for (int i = 0; i < 64; i++) tmp[i] = h2[i] * h2[i];
    const float sA = fold_sum_wave(h2, lane);
    const float qA = fold_sum_wave(tmp, lane);
    ssum[w][lane] = sA; ssq[w][lane] = qA;
#pragma unroll
    for (int i = 0; i < 64; i++) tmp[i] = h2[64 + i] * h2[64 + i];
    const float sB = fold_sum_wave(h2 + 64, lane);
    const float qB = fold_sum_wave(tmp, lane);
    ssum[w][64 + lane] = sB; ssq[w][64 + lane] = qB;
    __syncthreads();
    if (t < 128) {
        dst[t] = ssum[0][t] + ssum[1][t] + ssum[2][t] + ssum[3][t];
        dst[128 + t] = ssq[0][t] + ssq[1][t] + ssq[2][t] + ssq[3][t];
    }
}

__device__ __forceinline__ void max_out(float* h2, int lane, int w, int blk,
                                        float* __restrict__ out_np) {
    const int qq = blk * 8 + w * 2 + (lane >> 5);
    float r0, r1;
    fold_max_half(h2, lane, r0, r1);
    out_np[(size_t)qq * 128 + (lane & 31)] = r0;
    out_np[(size_t)qq * 128 + 32 + (lane & 31)] = r1;
    fold_max_half(h2 + 64, lane, r0, r1);
    out_np[(size_t)qq * 128 + 64 + (lane & 31)] = r0;
    out_np[(size_t)qq * 128 + 96 + (lane & 31)] = r1;
}

// h1 cache store/load (f32 exact; bf16 RNE)
__device__ __forceinline__ void h1_store_f32(const float* h1, float* buf, int r) {
    float4* dst = (float4*)(buf + (size_t)r * 64);
#pragma unroll
    for (int j = 0; j < 16; j++)
        dst[j] = make_float4(h1[4 * j], h1[4 * j + 1], h1[4 * j + 2], h1[4 * j + 3]);
}
__device__ __forceinline__ void h1_load_f32(float* x, const float* buf, int r) {
    const float4* src = (const float4*)(buf + (size_t)r * 64);
#pragma unroll
    for (int j = 0; j < 16; j++) {
        const float4 v = src[j];
        x[4 * j] = v.x; x[4 * j + 1] = v.y; x[4 * j + 2] = v.z; x[4 * j + 3] = v.w;
    }
}
__device__ __forceinline__ void h1_store_bf(const float* h1, unsigned short* buf, int r) {
    ushort4* dst = (ushort4*)(buf + (size_t)r * 64);
#pragma unroll
    for (int j = 0; j < 16; j++) {
        ushort4 v;
        v.x = f2bf(h1[4 * j]); v.y = f2bf(h1[4 * j + 1]);
        v.z = f2bf(h1[4 * j + 2]); v.w = f2bf(h1[4 * j + 3]);
        dst[j] = v;
    }
}
__device__ __forceinline__ void h1_load_bf(float* x, const unsigned short* buf, int r) {
    const ushort4* src = (const ushort4*)(buf + (size_t)r * 64);
#pragma unroll
    for (int j = 0; j < 16; j++) {
        const ushort4 v = src[j];
        x[4 * j] = bf2f(v.x); x[4 * j + 1] = bf2f(v.y);
        x[4 * j + 2] = bf2f(v.z); x[4 * j + 3] = bf2f(v.w);
    }
}

// ================================================================ MLP kernels
// S0: G0 -> stats0
__global__ __launch_bounds__(TPB_) void k_s0(
    const float* __restrict__ points, const float* __restrict__ xyz,
    const float* __restrict__ newxyz, const int* __restrict__ ball,
    const float* __restrict__ W0T, float* __restrict__ partials) {
    __shared__ float w0[67 * 64];
    __shared__ float ssum[4][64], ssq[4][64];
    const int t = threadIdx.x, lane = t & 63, w = t >> 6;
    stage_w(w0, W0T, 67 * 64, t);
    __syncthreads();
    const int r = blockIdx.x * TPB_ + t;
    float h0[64];
    g0_row(points, xyz, newxyz, ball, w0, r, h0);
    stats64_fold(h0, lane, w, t, ssum, ssq, partials + (size_t)blockIdx.x * 256);
}

// S1: G0,bn0,G1 -> stats1 (+optional h1 store; 0=none 1=f32 2=bf16)
template <int HST>
__global__ __launch_bounds__(TPB_) void k_s1(
    const float* __restrict__ points, const float* __restrict__ xyz,
    const float* __restrict__ newxyz, const int* __restrict__ ball,
    const float* __restrict__ W0T, const float* __restrict__ W1T,
    const float* __restrict__ bnp, float* __restrict__ partials,
    float* __restrict__ h1f, unsigned short* __restrict__ h1h) {
    __shared__ float w0[67 * 64];
    __shared__ float w1[64 * 64];
    __shared__ float ssum[4][64], ssq[4][64];
    const int t = threadIdx.x, lane = t & 63, w = t >> 6;
    stage_w(w0, W0T, 67 * 64, t);
    stage_w(w1, W1T, 64 * 64, t);
    __syncthreads();
    const int r = blockIdx.x * TPB_ + t;
    float h0[64];
    g0_row(points, xyz, newxyz, ball, w0, r, h0);
    bn_relu<64>(h0, bnp, 0);
    float h1[64];
    g1_row(h0, w1, h1);
    if constexpr (HST == 1) h1_store_f32(h1, h1f, r);
    if constexpr (HST == 2) h1_store_bf(h1, h1h, r);
    stats64_fold(h1, lane, w, t, ssum, ssq, partials + (size_t)blockIdx.x * 256);
}

// S2 (cached h1): load,bn1,G2 -> stats2  (HLD 1=f32 2=bf16)
template <int HLD>
__global__ __launch_bounds__(TPB_) void k_s2c(
    const float* __restrict__ h1f, const unsigned short* __restrict__ h1h,
    const float* __restrict__ W2T, const float* __restrict__ bnp,
    float* __restrict__ partials) {
    __shared__ float w2[64 * 128];
    __shared__ float ssum[4][128], ssq[4][128];
    const int t = threadIdx.x, lane = t & 63, w = t >> 6;
    stage_w(w2, W2T, 64 * 128, t);
    __syncthreads();
    const int r = blockIdx.x * TPB_ + t;
    float x[64];
    if constexpr (HLD == 1) h1_load_f32(x, h1f, r); else h1_load_bf(x, h1h, r);
    bn_relu<64>(x, bnp, 256);
    float h2[128];
    g2_row(x, w2, h2);
    stats128_fold(h2, lane, w, t, ssum, ssq, partials + (size_t)blockIdx.x * 256);
}

// S3 (cached h1): load,bn1,G2,bn2,max -> out
template <int HLD>
__global__ __launch_bounds__(TPB_) void k_s3c(
    const float* __restrict__ h1f, const unsigned short* __restrict__ h1h,
    const float* __restrict__ W2T, const float* __restrict__ bnp,
    float* __restrict__ out_np) {
    __shared__ float w2[64 * 128];
    const int t = threadIdx.x, lane = t & 63, w = t >> 6;
    stage_w(w2, W2T, 64 * 128, t);
    __syncthreads();
    const int r = blockIdx.x * TPB_ + t;
    float x[64];
    if constexpr (HLD == 1) h1_load_f32(x, h1f, r); else h1_load_bf(x, h1h, r);
    bn_relu<64>(x, bnp, 256);
    float h2[128];
    g2_row(x, w2, h2);
    bn_relu<128>(h2, bnp, 512);
    max_out(h2, lane, w, blockIdx.x, out_np);
}

// S2 recompute: G0,bn0,G1,bn1,G2 -> stats2
__global__ __launch_bounds__(TPB_) void k_s2r(
    const float* __restrict__ points, const float* __restrict__ xyz,
    const float* __restrict__ newxyz, const int* __restrict__ ball,
    const float* __restrict__ W0T, const float* __restrict__ W1T,
    const float* __restrict__ W2T, const float* __restrict__ bnp,
    float* __restrict__ partials) {
    __shared__ float w0[67 * 64];
    __shared__ float w1[64 * 64];
    __shared__ float w2[64 * 128];
    __shared__ float ssum[4][128], ssq[4][128];
    const int t = threadIdx.x, lane = t & 63, w = t >> 6;
    stage_w(w0, W0T, 67 * 64, t);
    stage_w(w1, W1T, 64 * 64, t);
    stage_w(w2, W2T, 64 * 128, t);
    __syncthreads();
    const int r = blockIdx.x * TPB_ + t;
    float h0[64];
    g0_row(points, xyz, newxyz, ball, w0, r, h0);
    bn_relu<64>(h0, bnp, 0);
    float h1[64];
    g1_row(h0, w1, h1);
    bn_relu<64>(h1, bnp, 256);
    float h2[128];
    g2_row(h1, w2, h2);
    stats128_fold(h2, lane, w, t, ssum, ssq, partials + (size_t)blockIdx.x * 256);
}

// S3 recompute: ... -> out
__global__ __launch_bounds__(TPB_) void k_s3r(
    const float* __restrict__ points, const float* __restrict__ xyz,
    const float* __restrict__ newxyz, const int* __restrict__ ball,
    const float* __restrict__ W0T, const float* __restrict__ W1T,
    const float* __restrict__ W2T, const float* __restrict__ bnp,
    float* __restrict__ out_np) {
    __shared__ float w0[67 * 64];
    __shared__ float w1[64 * 64];
    __shared__ float w2[64 * 128];
    const int t = threadIdx.x, lane = t & 63, w = t >> 6;
    stage_w(w0, W0T, 67 * 64, t);
    stage_w(w1, W1T, 64 * 64, t);
    stage_w(w2, W2T, 64 * 128, t);
    __syncthreads();
    const int r = blockIdx.x * TPB_ + t;
    float h0[64];
    g0_row(points, xyz, newxyz, ball, w0, r, h0);
    bn_relu<64>(h0, bnp, 0);
    float h1[64];
    g1_row(h0, w1, h1);
    bn_relu<64>(h1, bnp, 256);
    float h2[128];
    g2_row(h1, w2, h2);
    bn_relu<128>(h2, bnp, 512);
    max_out(h2, lane, w, blockIdx.x, out_np);
}

// ---------------------------------------------------------------- BN finalize
template <int C>
__global__ __launch_bounds__(128) void k_bnfin(const float* __restrict__ partials,
                                               const float* __restrict__ gw,
                                               const float* __restrict__ bw,
                                               float* __restrict__ bnpL) {
    const int t = threadIdx.x;
    if (t >= C) return;
    double Ssum = 0.0, Q = 0.0;
    for (int blk = 0; blk < NBLKM_; blk++) {
        Ssum += (double)partials[(size_t)blk * 256 + t];
        Q += (double)partials[(size_t)blk * 256 + 128 + t];
    }
    const double mean = Ssum / (double)NROWS_;
    const double var = Q / (double)NROWS_ - mean * mean;
    const float sc = (float)((double)gw[t] / sqrt(var + 1e-5));
    const float sh = (float)((double)bw[t] - mean * (double)sc);
    bnpL[t] = sc;
    bnpL[128 + t] = sh;
}

// ---------------------------------------------------------------- launch
extern "C" void kernel_launch(void* const* d_in, const int* in_sizes, int n_in,
                              void* d_out, int out_size, void* d_ws, size_t ws_size,
                              hipStream_t stream) {
    const float* xyz = (const float*)d_in[0];
    const float* points = (const float*)d_in[1];
    const float* W0 = (const float*)d_in[2];
    const float* g0 = (const float*)d_in[3];
    const float* b0 = (const float*)d_in[4];
    const float* W1 = (const float*)d_in[5];
    const float* g1 = (const float*)d_in[6];
    const float* b1 = (const float*)d_in[7];
    const float* W2 = (const float*)d_in[8];
    const float* g2 = (const float*)d_in[9];
    const float* b2 = (const float*)d_in[10];

    float* out = (float*)d_out;
    float* newxyz = out;
    float* out_np = out + B_ * M_ * 3;

    char* ws = (char*)d_ws;
    float* sqn = (float*)(ws + OFF_SQN);
    int* fps_idx = (int*)(ws + OFF_FPS);
    int* ball = (int*)(ws + OFF_BALL);
    float* W0T = (float*)(ws + OFF_W0T);
    float* W1T = (float*)(ws + OFF_W1T);
    float* W2T = (float*)(ws + OFF_W2T);
    float* partials = (float*)(ws + OFF_PART);
    float* bnp = (float*)(ws + OFF_BNP);
    float* h1f = (float*)(ws + OFF_H1);
    unsigned short* h1h = (unsigned short*)(ws + OFF_H1);

    k_sqnorm<<<(B_ * N_ + 255) / 256, 256, 0, stream>>>(xyz, sqn);
    k_fps<<<B_, 512, 0, stream>>>(xyz, fps_idx);
    k_newxyz<<<(B_ * M_ + 255) / 256, 256, 0, stream>>>(xyz, fps_idx, newxyz);
    k_ball<<<B_ * M_ / 4, 256, 0, stream>>>(xyz, sqn, fps_idx, newxyz, ball);
    k_wtrans<<<32, 256, 0, stream>>>(W0, W1, W2, W0T, W1T, W2T);

    k_s0<<<NBLKM_, TPB_, 0, stream>>>(points, xyz, newxyz, ball, W0T, partials);
    k_bnfin<64><<<1, 128, 0, stream>>>(partials, g0, b0, bnp);

    if (ws_size >= NEED_F32) {
        k_s1<1><<<NBLKM_, TPB_, 0, stream>>>(points, xyz, newxyz, ball, W0T, W1T, bnp, partials, h1f, h1h);
        k_bnfin<64><<<1, 128, 0, stream>>>(partials, g1, b1, bnp + 256);
        k_s2c<1><<<NBLKM_, TPB_, 0, stream>>>(h1f, h1h, W2T, bnp, partials);
        k_bnfin<128><<<1, 128, 0, stream>>>(partials, g2, b2, bnp + 512);
        k_s3c<1><<<NBLKM_, TPB_, 0, stream>>>(h1f, h1h, W2T, bnp, out_np);
    } else if (ws_size >= NEED_BF16) {
        k_s1<2><<<NBLKM_, TPB_, 0, stream>>>(points, xyz, newxyz, ball, W0T, W1T, bnp, partials, h1f, h1h);
        k_bnfin<64><<<1, 128, 0, stream>>>(partials, g1, b1, bnp + 256);
        k_s2c<2><<<NBLKM_, TPB_, 0, stream>>>(h1f, h1h, W2T, bnp, partials);
        k_bnfin<128><<<1, 128, 0, stream>>>(partials, g2, b2, bnp + 512);
        k_s3c<2><<<NBLKM_, TPB_, 0, stream>>>(h1f, h1h, W2T, bnp, out_np);
    } else {
        k_s1<0><<<NBLKM_, TPB_, 0, stream>>>(points, xyz, newxyz, ball, W0T, W1T, bnp, partials, h1f, h1h);
        k_bnfin<64><<<1, 128, 0, stream>>>(partials, g1, b1, bnp + 256);
        k_s2r<<<NBLKM_, TPB_, 0, stream>>>(points, xyz, newxyz, ball, W0T, W1T, W2T, bnp, partials);
        k_bnfin<128><<<1, 128, 0, stream>>>(partials, g2, b2, bnp + 512);
        k_s3r<<<NBLKM_, TPB_, 0, stream>>>(points, xyz, newxyz, ball, W0T, W1T, W2T, bnp, out_np);
    }
}

// Round 8
// 1460.162 us; speedup vs baseline: 2.5822x; 1.0940x over previous
//
#include <hip/hip_runtime.h>
#include <hip/hip_bf16.h>
#include <cstdint>
#include <cstddef>

namespace {
constexpr int B_ = 16;
constexpr int N_ = 4096;
constexpr int D_ = 64;
constexpr int M_ = 1024;
constexpr int S_ = 32;
constexpr int NROWS_ = B_ * M_ * S_;     // 524288
constexpr int TPB_ = 256;                // 4 waves
constexpr int NBLKM_ = NROWS_ / TPB_;    // 2048 (fallback, R=1)
constexpr int NBLK2_ = NROWS_ / (2 * TPB_); // 1024 (R=2)
constexpr float RR_ = 0.04f;

// ws offsets (bytes)
constexpr size_t OFF_SQN  = 0;                                    // 262144
constexpr size_t OFF_FPS  = 262144;                               // 65536
constexpr size_t OFF_BALL = 327680;                               // 2097152
constexpr size_t OFF_W0T  = 2424832;                              // 17152
constexpr size_t OFF_W1T  = OFF_W0T + 67 * 64 * 4;                // 16384
constexpr size_t OFF_W2T  = OFF_W1T + 64 * 64 * 4;                // 32768
constexpr size_t OFF_PART = OFF_W2T + 64 * 128 * 4;               // 2048*256*4
constexpr size_t OFF_BNP  = OFF_PART + (size_t)NBLKM_ * 256 * 4;  // 3072
// E/D dedup buffers + h1 cache
constexpr size_t OFF_E    = (OFF_BNP + 3072 + 255) & ~(size_t)255;
constexpr size_t E_SZ     = (size_t)B_ * N_ * 64 * 4;             // 16,777,216
constexpr size_t OFF_D    = OFF_E + E_SZ;
constexpr size_t D_SZ     = (size_t)B_ * M_ * 64 * 4;             // 4,194,304
constexpr size_t OFF_H1   = OFF_D + D_SZ;
constexpr size_t H1F_SZ   = (size_t)NROWS_ * 64 * 4;              // 134,217,728
constexpr size_t H1H_SZ   = (size_t)NROWS_ * 64 * 2;              // 67,108,864
constexpr size_t NEED_A   = OFF_H1 + H1F_SZ;                      // ~152.4 MiB
constexpr size_t NEED_B   = OFF_H1 + H1H_SZ;                      // ~88.4 MiB
}

// non-contractible multiply (separately-rounded product), scheduler-friendly
__device__ __forceinline__ float mul_nr(float a, float b) {
    float p = a * b;
    asm("" : "+v"(p));
    return p;
}
// volatile variant kept for the PROVEN-bitwise decision kernels (zero-risk)
__device__ __forceinline__ float mul_nf(float a, float b) {
    float p = a * b;
    asm volatile("" : "+v"(p));
    return p;
}

// DPP lane move (VALU-rate cross-lane)
template <int CTRL>
__device__ __forceinline__ float dpp_movf(float x) {
    return __int_as_float(
        __builtin_amdgcn_update_dpp(0, __float_as_int(x), CTRL, 0xF, 0xF, true));
}
__device__ __forceinline__ float xor_exch(float x, int k) {
    if (k == 0) return dpp_movf<0xB1>(x);   // quad_perm [1,0,3,2]
    if (k == 1) return dpp_movf<0x4E>(x);   // quad_perm [2,3,0,1]
    return __shfl_xor(x, 1 << k);
}

// ---------------------------------------------------------------- fold reduce
// 64-wide: lane L ends with op over all 64 lanes of channel L (mutates cur[64])
__device__ __forceinline__ float fold_sum_wave(float* cur, int lane) {
#pragma unroll
    for (int k = 0; k < 6; k++) {
        const bool hi = (lane >> k) & 1;
#pragma unroll
        for (int m = 0; m < (32 >> k); m++) {
            const float a = cur[2 * m], b = cur[2 * m + 1];
            const float keep = hi ? b : a;
            const float give = hi ? a : b;
            const float got = xor_exch(give, k);
            cur[m] = keep + got;
        }
    }
    return cur[0];
}
// 32-wide: lane L ends with op over L's 32-lane half of channel (L&31)
__device__ __forceinline__ float fold_sum32(float* cur, int lane) {
#pragma unroll
    for (int k = 0; k < 5; k++) {
        const bool hi = (lane >> k) & 1;
#pragma unroll
        for (int m = 0; m < (16 >> k); m++) {
            const float a = cur[2 * m], b = cur[2 * m + 1];
            const float keep = hi ? b : a;
            const float give = hi ? a : b;
            const float got = xor_exch(give, k);
            cur[m] = keep + got;
        }
    }
    return cur[0];
}
__device__ __forceinline__ float fold_max32(float* cur, int lane) {
#pragma unroll
    for (int k = 0; k < 5; k++) {
        const bool hi = (lane >> k) & 1;
#pragma unroll
        for (int m = 0; m < (16 >> k); m++) {
            const float a = cur[2 * m], b = cur[2 * m + 1];
            const float keep = hi ? b : a;
            const float give = hi ? a : b;
            const float got = xor_exch(give, k);
            cur[m] = fmaxf(keep, got);
        }
    }
    return cur[0];
}
__device__ __forceinline__ void fold_max_half(float* cur, int lane, float& r0, float& r1) {
#pragma unroll
    for (int k = 0; k < 5; k++) {
        const bool hi = (lane >> k) & 1;
#pragma unroll
        for (int m = 0; m < (32 >> k); m++) {
            const float a = cur[2 * m], b = cur[2 * m + 1];
            const float keep = hi ? b : a;
            const float give = hi ? a : b;
            const float got = xor_exch(give, k);
            cur[m] = fmaxf(keep, got);
        }
    }
    r0 = cur[0]; r1 = cur[1];
}

// bf16 pack/unpack (RNE)
__device__ __forceinline__ unsigned short f2bf(float f) {
    __hip_bfloat16 h = __float2bfloat16(f);
    return *reinterpret_cast<unsigned short*>(&h);
}
__device__ __forceinline__ float bf2f(unsigned short u) {
    __hip_bfloat16 h = *reinterpret_cast<__hip_bfloat16*>(&u);
    return __bfloat162float(h);
}

// ---------------------------------------------------------------- sqnorm
__global__ __launch_bounds__(256) void k_sqnorm(const float* __restrict__ xyz,
                                                float* __restrict__ sqn) {
    int i = blockIdx.x * 256 + threadIdx.x;
    if (i >= B_ * N_) return;
    float x = xyz[3 * i], y = xyz[3 * i + 1], z = xyz[3 * i + 2];
    sqn[i] = (mul_nf(x, x) + mul_nf(y, y)) + mul_nf(z, z);
}

// ---------------------------------------------------------------- FPS (proven)
__global__ __launch_bounds__(512) void k_fps(const float* __restrict__ xyz,
                                             int* __restrict__ fps_idx) {
    const int b = blockIdx.x, t = threadIdx.x;
    const int lane = t & 63, w = t >> 6;
    const float* xb = xyz + (size_t)b * N_ * 3;
    __shared__ float pts[N_ * 3];
    __shared__ unsigned long long slots[2][8];
    for (int i = t; i < N_ * 3; i += 512) pts[i] = xb[i];
    __syncthreads();

    const int n0 = t * 8;
    float px[8], py[8], pz[8], dist[8];
#pragma unroll
    for (int k = 0; k < 8; k++) {
        px[k] = pts[3 * (n0 + k)];
        py[k] = pts[3 * (n0 + k) + 1];
        pz[k] = pts[3 * (n0 + k) + 2];
        dist[k] = 1e10f;
    }

    int far = 0;
    for (int i = 0; i < M_; i++) {
        if (t == 0) fps_idx[b * M_ + i] = far;
        const float c0 = pts[3 * far], c1 = pts[3 * far + 1], c2 = pts[3 * far + 2];
        float bestv = -1.0f; int bestn = n0;
#pragma unroll
        for (int k = 0; k < 8; k++) {
            const float d0 = px[k] - c0, d1 = py[k] - c1, d2 = pz[k] - c2;
            const float dd = (mul_nr(d0, d0) + mul_nr(d1, d1)) + mul_nr(d2, d2);
            const float dm = fminf(dist[k], dd);
            dist[k] = dm;
            if (dm > bestv) { bestv = dm; bestn = n0 + k; }
        }
        float m = bestv;
        m = fmaxf(m, dpp_movf<0x111>(m));
        m = fmaxf(m, dpp_movf<0x112>(m));
        m = fmaxf(m, dpp_movf<0x114>(m));
        m = fmaxf(m, dpp_movf<0x118>(m));
        m = fmaxf(m, dpp_movf<0x142>(m));
        m = fmaxf(m, dpp_movf<0x143>(m));
        const float wmax = __int_as_float(
            __builtin_amdgcn_readlane(__float_as_int(m), 63));
        const unsigned long long mk = __ballot(bestv == wmax);
        const int src = __ffsll((long long)mk) - 1;
        const int wn = __builtin_amdgcn_readlane(bestn, src);
        if (lane == 0)
            slots[i & 1][w] =
                ((unsigned long long)__float_as_uint(wmax) << 32) | (unsigned)(~wn);
        __syncthreads();
        const unsigned long long* sl = slots[i & 1];
        const unsigned long long s0 = sl[0], s1 = sl[1], s2 = sl[2], s3 = sl[3];
        const unsigned long long s4 = sl[4], s5 = sl[5], s6 = sl[6], s7 = sl[7];
        const unsigned long long a0 = s0 > s1 ? s0 : s1;
        const unsigned long long a1 = s2 > s3 ? s2 : s3;
        const unsigned long long a2 = s4 > s5 ? s4 : s5;
        const unsigned long long a3 = s6 > s7 ? s6 : s7;
        const unsigned long long b0 = a0 > a1 ? a0 : a1;
        const unsigned long long b1 = a2 > a3 ? a2 : a3;
        const unsigned long long bb = b0 > b1 ? b0 : b1;
        far = (int)(~(unsigned)bb);
    }
}

// ---------------------------------------------------------------- gather new_xyz
__global__ __launch_bounds__(256) void k_newxyz(const float* __restrict__ xyz,
                                                const int* __restrict__ fps_idx,
                                                float* __restrict__ newxyz) {
    int i = blockIdx.x * 256 + threadIdx.x;
    if (i >= B_ * M_) return;
    int b = i >> 10;
    int f = fps_idx[i];
    const float* p = xyz + ((size_t)b * N_ + f) * 3;
    newxyz[3 * i] = p[0]; newxyz[3 * i + 1] = p[1]; newxyz[3 * i + 2] = p[2];
}

// ---------------------------------------------------------------- ball query (bitwise-frozen)
__global__ __launch_bounds__(256) void k_ball(const float* __restrict__ xyz,
                                              const float* __restrict__ sqn,
                                              const int* __restrict__ fps_idx,
                                              const float* __restrict__ newxyz,
                                              int* __restrict__ ball) {
    const int w = threadIdx.x >> 6, lane = threadIdx.x & 63;
    const int q = blockIdx.x * 4 + w;
    const int b = q >> 10;
    __shared__ int buf[4][32];
    const float* xb = xyz + (size_t)b * N_ * 3;
    const float* sb = sqn + (size_t)b * N_;
    const float q0 = newxyz[3 * q], q1 = newxyz[3 * q + 1], q2 = newxyz[3 * q + 2];
    const float sq = sb[fps_idx[q]];

    int cnt = 0;
    for (int base = 0; base < N_ && cnt < 32; base += 64) {
        const int n = base + lane;
        const float p0 = xb[3 * n], p1 = xb[3 * n + 1], p2 = xb[3 * n + 2];
        float dot = fmaf(q2, p2, fmaf(q1, p1, q0 * p0));
        float tt = -2.0f * dot;
        tt = tt + sq;
        tt = tt + sb[n];
        const bool pred = !(tt > RR_);
        const unsigned long long mask = __ballot(pred);
        const int pos = cnt + __popcll(mask & ((1ull << lane) - 1ull));
        if (pred && pos < 32) buf[w][pos] = n;
        cnt += (int)__popcll(mask);
    }
    __syncthreads();
    if (lane < 32) {
        int e = buf[w][(lane < cnt) ? lane : 0];
        ball[(size_t)q * 32 + lane] = e;
    }
}

// ---------------------------------------------------------------- weight transpose
__global__ __launch_bounds__(256) void k_wtrans(const float* __restrict__ W0,
                                                const float* __restrict__ W1,
                                                const float* __restrict__ W2,
                                                float* __restrict__ W0T,
                                                float* __restrict__ W1T,
                                                float* __restrict__ W2T) {
    int t = blockIdx.x * 256 + threadIdx.x;
    if (t < 64 * 67) { int o = t / 67, c = t % 67; W0T[c * 64 + o] = W0[t]; }
    if (t < 64 * 64) { int o = t / 64, c = t % 64; W1T[c * 64 + o] = W1[t]; }
    if (t < 128 * 64) { int o = t / 64, c = t % 64; W2T[c * 128 + o] = W2[t]; }
}

// ================================================================ helpers
__device__ __forceinline__ void stage_w(float* dst, const float* __restrict__ src,
                                        int n, int t) {
    for (int i = t; i < n; i += TPB_) dst[i] = src[i];
}

template <int NCH>
__device__ __forceinline__ void bn_relu(float* x, const float* __restrict__ bnp, int base) {
#pragma unroll
    for (int o = 0; o < NCH; o++)
        x[o] = fmaxf(0.f, fmaf(x[o], bnp[base + o], bnp[base + 128 + o]));
}

// h0 row = E[b,g] - D[q]  (GEMM0 dedup)
__device__ __forceinline__ void load_h0(float* x, const float* __restrict__ E,
                                        const float* __restrict__ Dq,
                                        const int* __restrict__ ball, int r) {
    const int b = r >> 15, q = r >> 5;
    const int g = ball[r];
    const float4* e = (const float4*)(E + ((size_t)(b * N_) + g) * 64);
    const float4* d = (const float4*)(Dq + (size_t)q * 64);
#pragma unroll
    for (int j = 0; j < 16; j++) {
        const float4 ev = e[j]; const float4 dv = d[j];
        x[4 * j + 0] = ev.x - dv.x; x[4 * j + 1] = ev.y - dv.y;
        x[4 * j + 2] = ev.z - dv.z; x[4 * j + 3] = ev.w - dv.w;
    }
}

__device__ __forceinline__ void h1_load_f32(float* x, const float* buf, int r) {
    const float4* src = (const float4*)(buf + (size_t)r * 64);
#pragma unroll
    for (int j = 0; j < 16; j++) {
        const float4 v = src[j];
        x[4 * j] = v.x; x[4 * j + 1] = v.y; x[4 * j + 2] = v.z; x[4 * j + 3] = v.w;
    }
}
__device__ __forceinline__ void h1_load_bf(float* x, const unsigned short* buf, int r) {
    const ushort4* src = (const ushort4*)(buf + (size_t)r * 64);
#pragma unroll
    for (int j = 0; j < 16; j++) {
        const ushort4 v = src[j];
        x[4 * j] = bf2f(v.x); x[4 * j + 1] = bf2f(v.y);
        x[4 * j + 2] = bf2f(v.z); x[4 * j + 3] = bf2f(v.w);
    }
}

// ================================================================ E / D pre-pass
// E[n][o] = points[n]·W0p + xyz[n]·W0x  (65536 unique rows; same FMA chain as g0)
__global__ __launch_bounds__(TPB_) void k_e(
    const float* __restrict__ points, const float* __restrict__ xyz,
    const float* __restrict__ W0T, float* __restrict__ E) {
    __shared__ float w0[67 * 64];
    const int t = threadIdx.x;
    stage_w(w0, W0T, 67 * 64, t);
    __syncthreads();
    const int n = blockIdx.x * TPB_ + t;      // 0..65535
    const float* prow = points + (size_t)n * 64;
    float h[64];
#pragma unroll
    for (int o = 0; o < 64; o++) h[o] = 0.f;
#pragma unroll
    for (int c = 0; c < 64; c += 4) {
        const float4 xv = *reinterpret_cast<const float4*>(prow + c);
        const float xs[4] = {xv.x, xv.y, xv.z, xv.w};
#pragma unroll
        for (int j = 0; j < 4; j++) {
            const float xc = xs[j];
            const float* wr = w0 + (c + j) * 64;
#pragma unroll
            for (int o = 0; o < 64; o++) h[o] = fmaf(xc, wr[o], h[o]);
        }
    }
    const float x0 = xyz[(size_t)n * 3], x1 = xyz[(size_t)n * 3 + 1], x2 = xyz[(size_t)n * 3 + 2];
#pragma unroll
    for (int o = 0; o < 64; o++) h[o] = fmaf(x0, w0[64 * 64 + o], h[o]);
#pragma unroll
    for (int o = 0; o < 64; o++) h[o] = fmaf(x1, w0[65 * 64 + o], h[o]);
#pragma unroll
    for (int o = 0; o < 64; o++) h[o] = fmaf(x2, w0[66 * 64 + o], h[o]);
    float4* dst = (float4*)(E + (size_t)n * 64);
#pragma unroll
    for (int j = 0; j < 16; j++)
        dst[j] = make_float4(h[4 * j], h[4 * j + 1], h[4 * j + 2], h[4 * j + 3]);
}

// D[q][o] = newxyz[q]·W0x
__global__ __launch_bounds__(256) void k_d(
    const float* __restrict__ newxyz, const float* __restrict__ W0T,
    float* __restrict__ Dq) {
    const int q = blockIdx.x * 256 + threadIdx.x;   // 0..16383
    const float n0 = newxyz[3 * q], n1 = newxyz[3 * q + 1], n2 = newxyz[3 * q + 2];
    const float* wa = W0T + 64 * 64;
    const float* wb = W0T + 65 * 64;
    const float* wc = W0T + 66 * 64;
    float* dst = Dq + (size_t)q * 64;
#pragma unroll
    for (int o = 0; o < 64; o++)
        dst[o] = fmaf(n2, wc[o], fmaf(n1, wb[o], n0 * wa[o]));
}

// ================================================================ MLP stages (R=2)
// S0: gather h0 (E-D) x2 rows -> stats0
__global__ __launch_bounds__(TPB_, 2) void k_s0(
    const float* __restrict__ E, const float* __restrict__ Dq,
    const int* __restrict__ ball, float* __restrict__ partials) {
    const int t = threadIdx.x, lane = t & 63, w = t >> 6;
    const int r0 = blockIdx.x * 512 + t, r1 = r0 + 256;
    __shared__ float ssum[4][64], ssq[4][64];
    float x0[64], x1[64];
    load_h0(x0, E, Dq, ball, r0);
    load_h0(x1, E, Dq, ball, r1);
#pragma unroll
    for (int i = 0; i < 64; i++) {
        const float sv_ = x0[i] + x1[i];
        x1[i] = x0[i] * x0[i] + x1[i] * x1[i];
        x0[i] = sv_;
    }
    const float sv = fold_sum_wave(x0, lane);
    const float qv = fold_sum_wave(x1, lane);
    ssum[w][lane] = sv; ssq[w][lane] = qv;
    __syncthreads();
    if (t < 64) {
        float* dst = partials + (size_t)blockIdx.x * 256;
        dst[t] = ssum[0][t] + ssum[1][t] + ssum[2][t] + ssum[3][t];
        dst[128 + t] = ssq[0][t] + ssq[1][t] + ssq[2][t] + ssq[3][t];
    }
}

// S1: h0 gather, bn0, G1 (R=2, o-tiled) -> h1 store + stats1.  HST 1=f32 2=bf16
template <int HST>
__global__ __launch_bounds__(TPB_, 2) void k_s1(
    const float* __restrict__ E, const float* __restrict__ Dq,
    const int* __restrict__ ball, const float* __restrict__ W1T,
    const float* __restrict__ bnp, float* __restrict__ partials,
    float* __restrict__ h1f, unsigned short* __restrict__ h1h) {
    __shared__ float w1[64 * 64];
    __shared__ float ssum[4][64], ssq[4][64];
    const int t = threadIdx.x, lane = t & 63, w = t >> 6;
    stage_w(w1, W1T, 64 * 64, t);
    const int r0 = blockIdx.x * 512 + t, r1 = r0 + 256;
    float x0[64], x1[64];
    load_h0(x0, E, Dq, ball, r0);
    bn_relu<64>(x0, bnp, 0);
    load_h0(x1, E, Dq, ball, r1);
    bn_relu<64>(x1, bnp, 0);
    __syncthreads();

#pragma unroll
    for (int tile = 0; tile < 2; tile++) {
        float a0[32], a1[32];
#pragma unroll
        for (int o = 0; o < 32; o++) { a0[o] = 0.f; a1[o] = 0.f; }
#pragma unroll
        for (int c = 0; c < 64; c++) {
            const float* wr = w1 + c * 64 + tile * 32;
            const float xc0 = x0[c], xc1 = x1[c];
#pragma unroll
            for (int o = 0; o < 32; o++) {
                a0[o] = fmaf(xc0, wr[o], a0[o]);
                a1[o] = fmaf(xc1, wr[o], a1[o]);
            }
        }
        if constexpr (HST == 1) {
            float4* d0 = (float4*)(h1f + (size_t)r0 * 64 + tile * 32);
            float4* d1 = (float4*)(h1f + (size_t)r1 * 64 + tile * 32);
#pragma unroll
            for (int j = 0; j < 8; j++) {
                d0[j] = make_float4(a0[4 * j], a0[4 * j + 1], a0[4 * j + 2], a0[4 * j + 3]);
                d1[j] = make_float4(a1[4 * j], a1[4 * j + 1], a1[4 * j + 2], a1[4 * j + 3]);
            }
        } else {
            ushort4* d0 = (ushort4*)(h1h + (size_t)r0 * 64 + tile * 32);
            ushort4* d1 = (ushort4*)(h1h + (size_t)r1 * 64 + tile * 32);
#pragma unroll
            for (int j = 0; j < 8; j++) {
                ushort4 v0, v1;
                v0.x = f2bf(a0[4 * j]); v0.y = f2bf(a0[4 * j + 1]);
                v0.z = f2bf(a0[4 * j + 2]); v0.w = f2bf(a0[4 * j + 3]);
                v1.x = f2bf(a1[4 * j]); v1.y = f2bf(a1[4 * j + 1]);
                v1.z = f2bf(a1[4 * j + 2]); v1.w = f2bf(a1[4 * j + 3]);
                d0[j] = v0; d1[j] = v1;
            }
        }
        // stats (raw h1): s->a0, sq->a1
#pragma unroll
        for (int o = 0; o < 32; o++) {
            const float sv_ = a0[o] + a1[o];
            a1[o] = a0[o] * a0[o] + a1[o] * a1[o];
            a0[o] = sv_;
        }
        float sv = fold_sum32(a0, lane); sv += __shfl_xor(sv, 32);
        float qv = fold_sum32(a1, lane); qv += __shfl_xor(qv, 32);
        if (lane < 32) { ssum[w][tile * 32 + lane] = sv; ssq[w][tile * 32 + lane] = qv; }
    }
    __syncthreads();
    if (t < 64) {
        float* dst = partials + (size_t)blockIdx.x * 256;
        dst[t] = ssum[0][t] + ssum[1][t] + ssum[2][t] + ssum[3][t];
        dst[128 + t] = ssq[0][t] + ssq[1][t] + ssq[2][t] + ssq[3][t];
    }
}

// S2: h1 load, bn1, G2 (R=2, o-tiled) -> stats2.  HLD 1=f32 2=bf16
template <int HLD>
__global__ __launch_bounds__(TPB_, 2) void k_s2(
    const float* __restrict__ h1f, const unsigned short* __restrict__ h1h,
    const float* __restrict__ W2T, const float* __restrict__ bnp,
    float* __restrict__ partials) {
    __shared__ float w2[64 * 128];
    __shared__ float ssum[4][128], ssq[4][128];
    const int t = threadIdx.x, lane = t & 63, w = t >> 6;
    stage_w(w2, W2T, 64 * 128, t);
    const int r0 = blockIdx.x * 512 + t, r1 = r0 + 256;
    float x0[64], x1[64];
    if constexpr (HLD == 1) { h1_load_f32(x0, h1f, r0); h1_load_f32(x1, h1f, r1); }
    else { h1_load_bf(x0, h1h, r0); h1_load_bf(x1, h1h, r1); }
    bn_relu<64>(x0, bnp, 256);
    bn_relu<64>(x1, bnp, 256);
    __syncthreads();

#pragma unroll
    for (int tile = 0; tile < 4; tile++) {
        float a0[32], a1[32];
#pragma unroll
        for (int o = 0; o < 32; o++) { a0[o] = 0.f; a1[o] = 0.f; }
#pragma unroll
        for (int c = 0; c < 64; c++) {
            const float* wr = w2 + c * 128 + tile * 32;
            const float xc0 = x0[c], xc1 = x1[c];
#pragma unroll
            for (int o = 0; o < 32; o++) {
                a0[o] = fmaf(xc0, wr[o], a0[o]);
                a1[o] = fmaf(xc1, wr[o], a1[o]);
            }
        }
#pragma unroll
        for (int o = 0; o < 32; o++) {
            const float sv_ = a0[o] + a1[o];
            a1[o] = a0[o] * a0[o] + a1[o] * a1[o];
            a0[o] = sv_;
        }
        float sv = fold_sum32(a0, lane); sv += __shfl_xor(sv, 32);
        float qv = fold_sum32(a1, lane); qv += __shfl_xor(qv, 32);
        if (lane < 32) { ssum[w][tile * 32 + lane] = sv; ssq[w][tile * 32 + lane] = qv; }
    }
    __syncthreads();
    if (t < 128) {
        float* dst = partials + (size_t)blockIdx.x * 256;
        dst[t] = ssum[0][t] + ssum[1][t] + ssum[2][t] + ssum[3][t];
        dst[128 + t] = ssq[0][t] + ssq[1][t] + ssq[2][t] + ssq[3][t];
    }
}

// S3: h1 load, bn1, G2, bn2+relu, group-max -> out
template <int HLD>
__global__ __launch_bounds__(TPB_, 2) void k_s3(
    const float* __restrict__ h1f, const unsigned short* __restrict__ h1h,
    const float* __restrict__ W2T, const float* __restrict__ bnp,
    float* __restrict__ out_np) {
    __shared__ float w2[64 * 128];
    const int t = threadIdx.x, lane = t & 63, w = t >> 6;
    stage_w(w2, W2T, 64 * 128, t);
    const int r0 = blockIdx.x * 512 + t, r1 = r0 + 256;
    float x0[64], x1[64];
    if constexpr (HLD == 1) { h1_load_f32(x0, h1f, r0); h1_load_f32(x1, h1f, r1); }
    else { h1_load_bf(x0, h1h, r0); h1_load_bf(x1, h1h, r1); }
    bn_relu<64>(x0, bnp, 256);
    bn_relu<64>(x1, bnp, 256);
    __syncthreads();

    const int q0 = blockIdx.x * 16 + w * 2 + (lane >> 5);
#pragma unroll
    for (int tile = 0; tile < 4; tile++) {
        float a0[32], a1[32];
#pragma unroll
        for (int o = 0; o < 32; o++) { a0[o] = 0.f; a1[o] = 0.f; }
#pragma unroll
        for (int c = 0; c < 64; c++) {
            const float* wr = w2 + c * 128 + tile * 32;
            const float xc0 = x0[c], xc1 = x1[c];
#pragma unroll
            for (int o = 0; o < 32; o++) {
                a0[o] = fmaf(xc0, wr[o], a0[o]);
                a1[o] = fmaf(xc1, wr[o], a1[o]);
            }
        }
#pragma unroll
        for (int o = 0; o < 32; o++) {
            const float sc = bnp[512 + tile * 32 + o];
            const float sh = bnp[512 + 128 + tile * 32 + o];
            a0[o] = fmaxf(0.f, fmaf(a0[o], sc, sh));
            a1[o] = fmaxf(0.f, fmaf(a1[o], sc, sh));
        }
        const float m0 = fold_max32(a0, lane);
        const float m1 = fold_max32(a1, lane);
        out_np[(size_t)q0 * 128 + tile * 32 + (lane & 31)] = m0;
        out_np[(size_t)(q0 + 8) * 128 + tile * 32 + (lane & 31)] = m1;
    }
}

// ================================================================ fallback (R=1 recompute; known-good)
__device__ __forceinline__ void g0_row(
    const float* __restrict__ points, const float* __restrict__ xyz,
    const float* __restrict__ newxyz, const int* __restrict__ ball,
    const float* w0, int r, float* h0) {
    const int b = r >> 15;
    const int q = r >> 5;
    const int g = ball[r];
    const float* prow = points + ((size_t)(b * N_) + g) * D_;
    const float xg0 = xyz[((size_t)b * N_ + g) * 3 + 0] - newxyz[(size_t)q * 3 + 0];
    const float xg1 = xyz[((size_t)b * N_ + g) * 3 + 1] - newxyz[(size_t)q * 3 + 1];
    const float xg2 = xyz[((size_t)b * N_ + g) * 3 + 2] - newxyz[(size_t)q * 3 + 2];
#pragma unroll
    for (int o = 0; o < 64; o++) h0[o] = 0.f;
#pragma unroll
    for (int c = 0; c < 64; c += 4) {
        const float4 xv = *reinterpret_cast<const float4*>(prow + c);
        const float xs[4] = {xv.x, xv.y, xv.z, xv.w};
#pragma unroll
        for (int j = 0; j < 4; j++) {
            const float xc = xs[j];
            const float* wr = w0 + (c + j) * 64;
#pragma unroll
            for (int o = 0; o < 64; o++) h0[o] = fmaf(xc, wr[o], h0[o]);
        }
    }
#pragma unroll
    for (int o = 0; o < 64; o++) h0[o] = fmaf(xg0, w0[64 * 64 + o], h0[o]);
#pragma unroll
    for (int o = 0; o < 64; o++) h0[o] = fmaf(xg1, w0[65 * 64 + o], h0[o]);
#pragma unroll
    for (int o = 0; o < 64; o++) h0[o] = fmaf(xg2, w0[66 * 64 + o], h0[o]);
}

__device__ __forceinline__ void g1_row(const float* x, const float* w1, float* h1) {
#pragma unroll
    for (int o = 0; o < 64; o++) h1[o] = 0.f;
#pragma unroll
    for (int c = 0; c < 64; c++) {
        const float xc = x[c];
        const float* wr = w1 + c * 64;
#pragma unroll
        for (int o = 0; o < 64; o++) h1[o] = fmaf(xc, wr[o], h1[o]);
    }
}
__device__ __forceinline__ void g2_row(const float* x, const float* w2, float* h2) {
#pragma unroll
    for (int o = 0; o < 128; o++) h2[o] = 0.f;
#pragma unroll
    for (int c = 0; c < 64; c++) {
        const float xc = x[c];
        const float* wr = w2 + c * 128;
#pragma unroll
        for (int o = 0; o < 128; o++) h2[o] = fmaf(xc, wr[o], h2[o]);
    }
}

__device__ __forceinline__ void stats64_fold(float* h, int lane, int w, int t,
                                             float (*ssum)[64], float (*ssq)[64],
                                             float* dst) {
    float tmp[64];
#pragma unroll
    for (int i = 0; i < 64; i++) tmp[i] = h[i] * h[i];
    const float s = fold_sum_wave(h, lane);
    const float q = fold_sum_wave(tmp, lane);
    ssum[w][lane] = s; ssq[w][lane] = q;
    __syncthreads();
    if (t < 64) {
        dst[t] = ssum[0][t] + ssum[1][t] + ssum[2][t] + ssum[3][t];
        dst[128 + t] = ssq[0][t] + ssq[1][t] + ssq[2][t] + ssq[3][t];
    }
}
__device__ __forceinline__ void stats128_fold(float* h2, int lane, int w, int t,
                                              float (*ssum)[128], float (*ssq)[128],
                                              float* dst) {
    float tmp[64];
#pragma unroll
    for (int i = 0; i < 64; i++) tmp[i] = h2[i] * h2[i];
    const float sA = fold_sum_wave(h2, lane);
    const float qA = fold_sum_wave(tmp, lane);
    ssum[w][lane] = sA; ssq[w][lane] = qA;
#pragma unroll
    for (int i = 0; i < 64; i++) tmp[i] = h2[64 + i] * h2[64 + i];
    const float sB = fold_sum_wave(h2 + 64, lane);
    const float qB = fold_sum_wave(tmp, lane);
    ssum[w][64 + lane] = sB; ssq[w][64 + lane] = qB;
    __syncthreads();
    if (t < 128) {
        dst[t] = ssum[0][t] + ssum[1][t] + ssum[2][t] + ssum[3][t];
        dst[128 + t] = ssq[0][t] + ssq[1][t] + ssq[2][t] + ssq[3][t];
    }
}
__device__ __forceinline__ void max_out_r1(float* h2, int lane, int w, int blk,
                                           float* __restrict__ out_np) {
    const int qq = blk * 8 + w * 2 + (lane >> 5);
    float r0, r1;
    fold_max_half(h2, lane, r0, r1);
    out_np[(size_t)qq * 128 + (lane & 31)] = r0;
    out_np[(size_t)qq * 128 + 32 + (lane & 31)] = r1;
    fold_max_half(h2 + 64, lane, r0, r1);
    out_np[(size_t)qq * 128 + 64 + (lane & 31)] = r0;
    out_np[(size_t)qq * 128 + 96 + (lane & 31)] = r1;
}

__global__ __launch_bounds__(TPB_) void k_s0r(
    const float* __restrict__ points, const float* __restrict__ xyz,
    const float* __restrict__ newxyz, const int* __restrict__ ball,
    const float* __restrict__ W0T, float* __restrict__ partials) {
    __shared__ float w0[67 * 64];
    __shared__ float ssum[4][64], ssq[4][64];
    const int t = threadIdx.x, lane = t & 63, w = t >> 6;
    stage_w(w0, W0T, 67 * 64, t);
    __syncthreads();
    const int r = blockIdx.x * TPB_ + t;
    float h0[64];
    g0_row(points, xyz, newxyz, ball, w0, r, h0);
    stats64_fold(h0, lane, w, t, ssum, ssq, partials + (size_t)blockIdx.x * 256);
}
__global__ __launch_bounds__(TPB_) void k_s1r(
    const float* __restrict__ points, const float* __restrict__ xyz,
    const float* __restrict__ newxyz, const int* __restrict__ ball,
    const float* __restrict__ W0T, const float* __restrict__ W1T,
    const float* __restrict__ bnp, float* __restrict__ partials) {
    __shared__ float w0[67 * 64];
    __shared__ float w1[64 * 64];
    __shared__ float ssum[4][64], ssq[4][64];
    const int t = threadIdx.x, lane = t & 63, w = t >> 6;
    stage_w(w0, W0T, 67 * 64, t);
    stage_w(w1, W1T, 64 * 64, t);
    __syncthreads();
    const int r = blockIdx.x * TPB_ + t;
    float h0[64];
    g0_row(points, xyz, newxyz, ball, w0, r, h0);
    bn_relu<64>(h0, bnp, 0);
    float h1[64];
    g1_row(h0, w1, h1);
    stats64_fold(h1, lane, w, t, ssum, ssq, partials + (size_t)blockIdx.x * 256);
}
__global__ __launch_bounds__(TPB_) void k_s2r(
    const float* __restrict__ points, const float* __restrict__ xyz,
    const float* __restrict__ newxyz, const int* __restrict__ ball,
    const float* __restrict__ W0T, const float* __restrict__ W1T,
    const float* __restrict__ W2T, const float* __restrict__ bnp,
    float* __restrict__ partials) {
    __shared__ float w0[67 * 64];
    __shared__ float w1[64 * 64];
    __shared__ float w2[64 * 128];
    __shared__ float ssum[4][128], ssq[4][128];
    const int t = threadIdx.x, lane = t & 63, w = t >> 6;
    stage_w(w0, W0T, 67 * 64, t);
    stage_w(w1, W1T, 64 * 64, t);
    stage_w(w2, W2T, 64 * 128, t);
    __syncthreads();
    const int r = blockIdx.x * TPB_ + t;
    float h0[64];
    g0_row(points, xyz, newxyz, ball, w0, r, h0);
    bn_relu<64>(h0, bnp, 0);
    float h1[64];
    g1_row(h0, w1, h1);
    bn_relu<64>(h1, bnp, 256);
    float h2[128];
    g2_row(h1, w2, h2);
    stats128_fold(h2, lane, w, t, ssum, ssq, partials + (size_t)blockIdx.x * 256);
}
__global__ __launch_bounds__(TPB_) void k_s3r(
    const float* __restrict__ points, const float* __restrict__ xyz,
    const float* __restrict__ newxyz, const int* __restrict__ ball,
    const float* __restrict__ W0T, const float* __restrict__ W1T,
    const float* __restrict__ W2T, const float* __restrict__ bnp,
    float* __restrict__ out_np) {
    __shared__ float w0[67 * 64];
    __shared__ float w1[64 * 64];
    __shared__ float w2[64 * 128];
    const int t = threadIdx.x, lane = t & 63, w = t >> 6;
    stage_w(w0, W0T, 67 * 64, t);
    stage_w(w1, W1T, 64 * 64, t);
    stage_w(w2, W2T, 64 * 128, t);
    __syncthreads();
    const int r = blockIdx.x * TPB_ + t;
    float h0[64];
    g0_row(points, xyz, newxyz, ball, w0, r, h0);
    bn_relu<64>(h0, bnp, 0);
    float h1[64];
    g1_row(h0, w1, h1);
    bn_relu<64>(h1, bnp, 256);
    float h2[128];
    g2_row(h1, w2, h2);
    bn_relu<128>(h2, bnp, 512);
    max_out_r1(h2, lane, w, blockIdx.x, out_np);
}

// ---------------------------------------------------------------- BN finalize
template <int C, int NB>
__global__ __launch_bounds__(128) void k_bnfin(const float* __restrict__ partials,
                                               const float* __restrict__ gw,
                                               const float* __restrict__ bw,
                                               float* __restrict__ bnpL) {
    const int t = threadIdx.x;
    if (t >= C) return;
    double Ssum = 0.0, Q = 0.0;
    for (int blk = 0; blk < NB; blk++) {
        Ssum += (double)partials[(size_t)blk * 256 + t];
        Q += (double)partials[(size_t)blk * 256 + 128 + t];
    }
    const double mean = Ssum / (double)NROWS_;
    const double var = Q / (double)NROWS_ - mean * mean;
    const float sc = (float)((double)gw[t] / sqrt(var + 1e-5));
    const float sh = (float)((double)bw[t] - mean * (double)sc);
    bnpL[t] = sc;
    bnpL[128 + t] = sh;
}

// ---------------------------------------------------------------- launch
extern "C" void kernel_launch(void* const* d_in, const int* in_sizes, int n_in,
                              void* d_out, int out_size, void* d_ws, size_t ws_size,
                              hipStream_t stream) {
    const float* xyz = (const float*)d_in[0];
    const float* points = (const float*)d_in[1];
    const float* W0 = (const float*)d_in[2];
    const float* g0 = (const float*)d_in[3];
    const float* b0 = (const float*)d_in[4];
    const float* W1 = (const float*)d_in[5];
    const float* g1 = (const float*)d_in[6];
    const float* b1 = (const float*)d_in[7];
    const float* W2 = (const float*)d_in[8];
    const float* g2 = (const float*)d_in[9];
    const float* b2 = (const float*)d_in[10];

    float* out = (float*)d_out;
    float* newxyz = out;
    float* out_np = out + B_ * M_ * 3;

    char* ws = (char*)d_ws;
    float* sqn = (float*)(ws + OFF_SQN);
    int* fps_idx = (int*)(ws + OFF_FPS);
    int* ball = (int*)(ws + OFF_BALL);
    float* W0T = (float*)(ws + OFF_W0T);
    float* W1T = (float*)(ws + OFF_W1T);
    float* W2T = (float*)(ws + OFF_W2T);
    float* partials = (float*)(ws + OFF_PART);
    float* bnp = (float*)(ws + OFF_BNP);
    float* Ebuf = (float*)(ws + OFF_E);
    float* Dbuf = (float*)(ws + OFF_D);
    float* h1f = (float*)(ws + OFF_H1);
    unsigned short* h1h = (unsigned short*)(ws + OFF_H1);

    k_sqnorm<<<(B_ * N_ + 255) / 256, 256, 0, stream>>>(xyz, sqn);
    k_fps<<<B_, 512, 0, stream>>>(xyz, fps_idx);
    k_newxyz<<<(B_ * M_ + 255) / 256, 256, 0, stream>>>(xyz, fps_idx, newxyz);
    k_ball<<<B_ * M_ / 4, 256, 0, stream>>>(xyz, sqn, fps_idx, newxyz, ball);
    k_wtrans<<<32, 256, 0, stream>>>(W0, W1, W2, W0T, W1T, W2T);

    if (ws_size >= NEED_B) {
        k_e<<<B_ * N_ / TPB_, TPB_, 0, stream>>>(points, xyz, W0T, Ebuf);
        k_d<<<B_ * M_ / 256, 256, 0, stream>>>(newxyz, W0T, Dbuf);
        k_s0<<<NBLK2_, TPB_, 0, stream>>>(Ebuf, Dbuf, ball, partials);
        k_bnfin<64, NBLK2_><<<1, 128, 0, stream>>>(partials, g0, b0, bnp);
        if (ws_size >= NEED_A) {
            k_s1<1><<<NBLK2_, TPB_, 0, stream>>>(Ebuf, Dbuf, ball, W1T, bnp, partials, h1f, h1h);
            k_bnfin<64, NBLK2_><<<1, 128, 0, stream>>>(partials, g1, b1, bnp + 256);
            k_s2<1><<<NBLK2_, TPB_, 0, stream>>>(h1f, h1h, W2T, bnp, partials);
            k_bnfin<128, NBLK2_><<<1, 128, 0, stream>>>(partials, g2, b2, bnp + 512);
            k_s3<1><<<NBLK2_, TPB_, 0, stream>>>(h1f, h1h, W2T, bnp, out_np);
        } else {
            k_s1<2><<<NBLK2_, TPB_, 0, stream>>>(Ebuf, Dbuf, ball, W1T, bnp, partials, h1f, h1h);
            k_bnfin<64, NBLK2_><<<1, 128, 0, stream>>>(partials, g1, b1, bnp + 256);
            k_s2<2><<<NBLK2_, TPB_, 0, stream>>>(h1f, h1h, W2T, bnp, partials);
            k_bnfin<128, NBLK2_><<<1, 128, 0, stream>>>(partials, g2, b2, bnp + 512);
            k_s3<2><<<NBLK2_, TPB_, 0, stream>>>(h1f, h1h, W2T, bnp, out_np);
        }
    } else {
        // recompute fallback (R=1, known-good)
        k_s0r<<<NBLKM_, TPB_, 0, stream>>>(points, xyz, newxyz, ball, W0T, partials);
        k_bnfin<64, NBLKM_><<<1, 128, 0, stream>>>(partials, g0, b0, bnp);
        k_s1r<<<NBLKM_, TPB_, 0, stream>>>(points, xyz, newxyz, ball, W0T, W1T, bnp, partials);
        k_bnfin<64, NBLKM_><<<1, 128, 0, stream>>>(partials, g1, b1, bnp + 256);
        k_s2r<<<NBLKM_, TPB_, 0, stream>>>(points, xyz, newxyz, ball, W0T, W1T, W2T, bnp, partials);
        k_bnfin<128, NBLKM_><<<1, 128, 0, stream>>>(partials, g2, b2, bnp + 512);
        k_s3r<<<NBLKM_, TPB_, 0, stream>>>(points, xyz, newxyz, ball, W0T, W1T, W2T, bnp, out_np);
    }
}

// Round 9
// 1253.591 us; speedup vs baseline: 3.0077x; 1.1648x over previous
//
#include <hip/hip_runtime.h>
#include <hip/hip_bf16.h>
#include <cstdint>
#include <cstddef>

namespace {
constexpr int B_ = 16;
constexpr int N_ = 4096;
constexpr int D_ = 64;
constexpr int M_ = 1024;
constexpr int S_ = 32;
constexpr int NROWS_ = B_ * M_ * S_;     // 524288
constexpr int TPB_ = 256;                // 4 waves
constexpr int NBLKM_ = NROWS_ / TPB_;    // 2048 (fallback, R=1)
constexpr int NBLK2_ = NROWS_ / (2 * TPB_); // 1024 (R=2)
constexpr float RR_ = 0.04f;

// ws offsets (bytes)
constexpr size_t OFF_SQN  = 0;                                    // 262144
constexpr size_t OFF_FPS  = 262144;                               // 65536
constexpr size_t OFF_BALL = 327680;                               // 2097152
constexpr size_t OFF_W0T  = 2424832;                              // 17152
constexpr size_t OFF_W1T  = OFF_W0T + 67 * 64 * 4;                // 16384
constexpr size_t OFF_W2T  = OFF_W1T + 64 * 64 * 4;                // 32768
constexpr size_t OFF_PART = OFF_W2T + 64 * 128 * 4;               // 2048*256*4
constexpr size_t OFF_BNP  = OFF_PART + (size_t)NBLKM_ * 256 * 4;  // 3072
// E/D dedup buffers + h1 cache.  E is dead after k_s1; its space is reused
// by k_s2 for the per-(q,ch) raw-h2 max/min (exactly E_SZ bytes).
constexpr size_t OFF_E    = (OFF_BNP + 3072 + 255) & ~(size_t)255;
constexpr size_t E_SZ     = (size_t)B_ * N_ * 64 * 4;             // 16,777,216
constexpr size_t OFF_D    = OFF_E + E_SZ;
constexpr size_t D_SZ     = (size_t)B_ * M_ * 64 * 4;             // 4,194,304
constexpr size_t OFF_H1   = OFF_D + D_SZ;
constexpr size_t H1F_SZ   = (size_t)NROWS_ * 64 * 4;              // 134,217,728
constexpr size_t H1H_SZ   = (size_t)NROWS_ * 64 * 2;              // 67,108,864
constexpr size_t NEED_A   = OFF_H1 + H1F_SZ;                      // ~152.4 MiB
constexpr size_t NEED_B   = OFF_H1 + H1H_SZ;                      // ~88.4 MiB
}

// non-contractible multiply (separately-rounded product), scheduler-friendly
__device__ __forceinline__ float mul_nr(float a, float b) {
    float p = a * b;
    asm("" : "+v"(p));
    return p;
}
// volatile variant kept for the PROVEN-bitwise decision kernels (zero-risk)
__device__ __forceinline__ float mul_nf(float a, float b) {
    float p = a * b;
    asm volatile("" : "+v"(p));
    return p;
}

// DPP lane move (VALU-rate cross-lane)
template <int CTRL>
__device__ __forceinline__ float dpp_movf(float x) {
    return __int_as_float(
        __builtin_amdgcn_update_dpp(0, __float_as_int(x), CTRL, 0xF, 0xF, true));
}
__device__ __forceinline__ float xor_exch(float x, int k) {
    if (k == 0) return dpp_movf<0xB1>(x);   // quad_perm [1,0,3,2]
    if (k == 1) return dpp_movf<0x4E>(x);   // quad_perm [2,3,0,1]
    return __shfl_xor(x, 1 << k);
}

// ---------------------------------------------------------------- fold reduce
// 64-wide: lane L ends with op over all 64 lanes of channel L (mutates cur[64])
__device__ __forceinline__ float fold_sum_wave(float* cur, int lane) {
#pragma unroll
    for (int k = 0; k < 6; k++) {
        const bool hi = (lane >> k) & 1;
#pragma unroll
        for (int m = 0; m < (32 >> k); m++) {
            const float a = cur[2 * m], b = cur[2 * m + 1];
            const float keep = hi ? b : a;
            const float give = hi ? a : b;
            const float got = xor_exch(give, k);
            cur[m] = keep + got;
        }
    }
    return cur[0];
}
// 32-wide: lane L ends with op over L's 32-lane half of channel (L&31)
__device__ __forceinline__ float fold_sum32(float* cur, int lane) {
#pragma unroll
    for (int k = 0; k < 5; k++) {
        const bool hi = (lane >> k) & 1;
#pragma unroll
        for (int m = 0; m < (16 >> k); m++) {
            const float a = cur[2 * m], b = cur[2 * m + 1];
            const float keep = hi ? b : a;
            const float give = hi ? a : b;
            const float got = xor_exch(give, k);
            cur[m] = keep + got;
        }
    }
    return cur[0];
}
__device__ __forceinline__ float fold_max32(float* cur, int lane) {
#pragma unroll
    for (int k = 0; k < 5; k++) {
        const bool hi = (lane >> k) & 1;
#pragma unroll
        for (int m = 0; m < (16 >> k); m++) {
            const float a = cur[2 * m], b = cur[2 * m + 1];
            const float keep = hi ? b : a;
            const float give = hi ? a : b;
            const float got = xor_exch(give, k);
            cur[m] = fmaxf(keep, got);
        }
    }
    return cur[0];
}
__device__ __forceinline__ float fold_min32(float* cur, int lane) {
#pragma unroll
    for (int k = 0; k < 5; k++) {
        const bool hi = (lane >> k) & 1;
#pragma unroll
        for (int m = 0; m < (16 >> k); m++) {
            const float a = cur[2 * m], b = cur[2 * m + 1];
            const float keep = hi ? b : a;
            const float give = hi ? a : b;
            const float got = xor_exch(give, k);
            cur[m] = fminf(keep, got);
        }
    }
    return cur[0];
}
__device__ __forceinline__ void fold_max_half(float* cur, int lane, float& r0, float& r1) {
#pragma unroll
    for (int k = 0; k < 5; k++) {
        const bool hi = (lane >> k) & 1;
#pragma unroll
        for (int m = 0; m < (32 >> k); m++) {
            const float a = cur[2 * m], b = cur[2 * m + 1];
            const float keep = hi ? b : a;
            const float give = hi ? a : b;
            const float got = xor_exch(give, k);
            cur[m] = fmaxf(keep, got);
        }
    }
    r0 = cur[0]; r1 = cur[1];
}

// bf16 pack/unpack (RNE)
__device__ __forceinline__ unsigned short f2bf(float f) {
    __hip_bfloat16 h = __float2bfloat16(f);
    return *reinterpret_cast<unsigned short*>(&h);
}
__device__ __forceinline__ float bf2f(unsigned short u) {
    __hip_bfloat16 h = *reinterpret_cast<__hip_bfloat16*>(&u);
    return __bfloat162float(h);
}

// ---------------------------------------------------------------- sqnorm
__global__ __launch_bounds__(256) void k_sqnorm(const float* __restrict__ xyz,
                                                float* __restrict__ sqn) {
    int i = blockIdx.x * 256 + threadIdx.x;
    if (i >= B_ * N_) return;
    float x = xyz[3 * i], y = xyz[3 * i + 1], z = xyz[3 * i + 2];
    sqn[i] = (mul_nf(x, x) + mul_nf(y, y)) + mul_nf(z, z);
}

// ---------------------------------------------------------------- FPS (proven)
__global__ __launch_bounds__(512) void k_fps(const float* __restrict__ xyz,
                                             int* __restrict__ fps_idx) {
    const int b = blockIdx.x, t = threadIdx.x;
    const int lane = t & 63, w = t >> 6;
    const float* xb = xyz + (size_t)b * N_ * 3;
    __shared__ float pts[N_ * 3];
    __shared__ unsigned long long slots[2][8];
    for (int i = t; i < N_ * 3; i += 512) pts[i] = xb[i];
    __syncthreads();

    const int n0 = t * 8;
    float px[8], py[8], pz[8], dist[8];
#pragma unroll
    for (int k = 0; k < 8; k++) {
        px[k] = pts[3 * (n0 + k)];
        py[k] = pts[3 * (n0 + k) + 1];
        pz[k] = pts[3 * (n0 + k) + 2];
        dist[k] = 1e10f;
    }

    int far = 0;
    for (int i = 0; i < M_; i++) {
        if (t == 0) fps_idx[b * M_ + i] = far;
        const float c0 = pts[3 * far], c1 = pts[3 * far + 1], c2 = pts[3 * far + 2];
        float bestv = -1.0f; int bestn = n0;
#pragma unroll
        for (int k = 0; k < 8; k++) {
            const float d0 = px[k] - c0, d1 = py[k] - c1, d2 = pz[k] - c2;
            const float dd = (mul_nr(d0, d0) + mul_nr(d1, d1)) + mul_nr(d2, d2);
            const float dm = fminf(dist[k], dd);
            dist[k] = dm;
            if (dm > bestv) { bestv = dm; bestn = n0 + k; }
        }
        float m = bestv;
        m = fmaxf(m, dpp_movf<0x111>(m));
        m = fmaxf(m, dpp_movf<0x112>(m));
        m = fmaxf(m, dpp_movf<0x114>(m));
        m = fmaxf(m, dpp_movf<0x118>(m));
        m = fmaxf(m, dpp_movf<0x142>(m));
        m = fmaxf(m, dpp_movf<0x143>(m));
        const float wmax = __int_as_float(
            __builtin_amdgcn_readlane(__float_as_int(m), 63));
        const unsigned long long mk = __ballot(bestv == wmax);
        const int src = __ffsll((long long)mk) - 1;
        const int wn = __builtin_amdgcn_readlane(bestn, src);
        if (lane == 0)
            slots[i & 1][w] =
                ((unsigned long long)__float_as_uint(wmax) << 32) | (unsigned)(~wn);
        __syncthreads();
        const unsigned long long* sl = slots[i & 1];
        const unsigned long long s0 = sl[0], s1 = sl[1], s2 = sl[2], s3 = sl[3];
        const unsigned long long s4 = sl[4], s5 = sl[5], s6 = sl[6], s7 = sl[7];
        const unsigned long long a0 = s0 > s1 ? s0 : s1;
        const unsigned long long a1 = s2 > s3 ? s2 : s3;
        const unsigned long long a2 = s4 > s5 ? s4 : s5;
        const unsigned long long a3 = s6 > s7 ? s6 : s7;
        const unsigned long long b0 = a0 > a1 ? a0 : a1;
        const unsigned long long b1 = a2 > a3 ? a2 : a3;
        const unsigned long long bb = b0 > b1 ? b0 : b1;
        far = (int)(~(unsigned)bb);
    }
}

// ---------------------------------------------------------------- gather new_xyz
__global__ __launch_bounds__(256) void k_newxyz(const float* __restrict__ xyz,
                                                const int* __restrict__ fps_idx,
                                                float* __restrict__ newxyz) {
    int i = blockIdx.x * 256 + threadIdx.x;
    if (i >= B_ * M_) return;
    int b = i >> 10;
    int f = fps_idx[i];
    const float* p = xyz + ((size_t)b * N_ + f) * 3;
    newxyz[3 * i] = p[0]; newxyz[3 * i + 1] = p[1]; newxyz[3 * i + 2] = p[2];
}

// ---------------------------------------------------------------- ball query (bitwise-frozen)
__global__ __launch_bounds__(256) void k_ball(const float* __restrict__ xyz,
                                              const float* __restrict__ sqn,
                                              const int* __restrict__ fps_idx,
                                              const float* __restrict__ newxyz,
                                              int* __restrict__ ball) {
    const int w = threadIdx.x >> 6, lane = threadIdx.x & 63;
    const int q = blockIdx.x * 4 + w;
    const int b = q >> 10;
    __shared__ int buf[4][32];
    const float* xb = xyz + (size_t)b * N_ * 3;
    const float* sb = sqn + (size_t)b * N_;
    const float q0 = newxyz[3 * q], q1 = newxyz[3 * q + 1], q2 = newxyz[3 * q + 2];
    const float sq = sb[fps_idx[q]];

    int cnt = 0;
    for (int base = 0; base < N_ && cnt < 32; base += 64) {
        const int n = base + lane;
        const float p0 = xb[3 * n], p1 = xb[3 * n + 1], p2 = xb[3 * n + 2];
        float dot = fmaf(q2, p2, fmaf(q1, p1, q0 * p0));
        float tt = -2.0f * dot;
        tt = tt + sq;
        tt = tt + sb[n];
        const bool pred = !(tt > RR_);
        const unsigned long long mask = __ballot(pred);
        const int pos = cnt + __popcll(mask & ((1ull << lane) - 1ull));
        if (pred && pos < 32) buf[w][pos] = n;
        cnt += (int)__popcll(mask);
    }
    __syncthreads();
    if (lane < 32) {
        int e = buf[w][(lane < cnt) ? lane : 0];
        ball[(size_t)q * 32 + lane] = e;
    }
}

// ---------------------------------------------------------------- weight transpose
__global__ __launch_bounds__(256) void k_wtrans(const float* __restrict__ W0,
                                                const float* __restrict__ W1,
                                                const float* __restrict__ W2,
                                                float* __restrict__ W0T,
                                                float* __restrict__ W1T,
                                                float* __restrict__ W2T) {
    int t = blockIdx.x * 256 + threadIdx.x;
    if (t < 64 * 67) { int o = t / 67, c = t % 67; W0T[c * 64 + o] = W0[t]; }
    if (t < 64 * 64) { int o = t / 64, c = t % 64; W1T[c * 64 + o] = W1[t]; }
    if (t < 128 * 64) { int o = t / 64, c = t % 64; W2T[c * 128 + o] = W2[t]; }
}

// ================================================================ helpers
__device__ __forceinline__ void stage_w(float* dst, const float* __restrict__ src,
                                        int n, int t) {
    for (int i = t; i < n; i += TPB_) dst[i] = src[i];
}

template <int NCH>
__device__ __forceinline__ void bn_relu(float* x, const float* __restrict__ bnp, int base) {
#pragma unroll
    for (int o = 0; o < NCH; o++)
        x[o] = fmaxf(0.f, fmaf(x[o], bnp[base + o], bnp[base + 128 + o]));
}

// h0 row = E[b,g] - D[q]  (GEMM0 dedup)
__device__ __forceinline__ void load_h0(float* x, const float* __restrict__ E,
                                        const float* __restrict__ Dq,
                                        const int* __restrict__ ball, int r) {
    const int b = r >> 15, q = r >> 5;
    const int g = ball[r];
    const float4* e = (const float4*)(E + ((size_t)(b * N_) + g) * 64);
    const float4* d = (const float4*)(Dq + (size_t)q * 64);
#pragma unroll
    for (int j = 0; j < 16; j++) {
        const float4 ev = e[j]; const float4 dv = d[j];
        x[4 * j + 0] = ev.x - dv.x; x[4 * j + 1] = ev.y - dv.y;
        x[4 * j + 2] = ev.z - dv.z; x[4 * j + 3] = ev.w - dv.w;
    }
}

__device__ __forceinline__ void h1_load_f32(float* x, const float* buf, int r) {
    const float4* src = (const float4*)(buf + (size_t)r * 64);
#pragma unroll
    for (int j = 0; j < 16; j++) {
        const float4 v = src[j];
        x[4 * j] = v.x; x[4 * j + 1] = v.y; x[4 * j + 2] = v.z; x[4 * j + 3] = v.w;
    }
}
__device__ __forceinline__ void h1_load_bf(float* x, const unsigned short* buf, int r) {
    const ushort4* src = (const ushort4*)(buf + (size_t)r * 64);
#pragma unroll
    for (int j = 0; j < 16; j++) {
        const ushort4 v = src[j];
        x[4 * j] = bf2f(v.x); x[4 * j + 1] = bf2f(v.y);
        x[4 * j + 2] = bf2f(v.z); x[4 * j + 3] = bf2f(v.w);
    }
}

// ================================================================ E / D pre-pass
__global__ __launch_bounds__(TPB_) void k_e(
    const float* __restrict__ points, const float* __restrict__ xyz,
    const float* __restrict__ W0T, float* __restrict__ E) {
    __shared__ float w0[67 * 64];
    const int t = threadIdx.x;
    stage_w(w0, W0T, 67 * 64, t);
    __syncthreads();
    const int n = blockIdx.x * TPB_ + t;      // 0..65535
    const float* prow = points + (size_t)n * 64;
    float h[64];
#pragma unroll
    for (int o = 0; o < 64; o++) h[o] = 0.f;
#pragma unroll
    for (int c = 0; c < 64; c += 4) {
        const float4 xv = *reinterpret_cast<const float4*>(prow + c);
        const float xs[4] = {xv.x, xv.y, xv.z, xv.w};
#pragma unroll
        for (int j = 0; j < 4; j++) {
            const float xc = xs[j];
            const float* wr = w0 + (c + j) * 64;
#pragma unroll
            for (int o = 0; o < 64; o++) h[o] = fmaf(xc, wr[o], h[o]);
        }
    }
    const float x0 = xyz[(size_t)n * 3], x1 = xyz[(size_t)n * 3 + 1], x2 = xyz[(size_t)n * 3 + 2];
#pragma unroll
    for (int o = 0; o < 64; o++) h[o] = fmaf(x0, w0[64 * 64 + o], h[o]);
#pragma unroll
    for (int o = 0; o < 64; o++) h[o] = fmaf(x1, w0[65 * 64 + o], h[o]);
#pragma unroll
    for (int o = 0; o < 64; o++) h[o] = fmaf(x2, w0[66 * 64 + o], h[o]);
    float4* dst = (float4*)(E + (size_t)n * 64);
#pragma unroll
    for (int j = 0; j < 16; j++)
        dst[j] = make_float4(h[4 * j], h[4 * j + 1], h[4 * j + 2], h[4 * j + 3]);
}

__global__ __launch_bounds__(256) void k_d(
    const float* __restrict__ newxyz, const float* __restrict__ W0T,
    float* __restrict__ Dq) {
    const int q = blockIdx.x * 256 + threadIdx.x;   // 0..16383
    const float n0 = newxyz[3 * q], n1 = newxyz[3 * q + 1], n2 = newxyz[3 * q + 2];
    const float* wa = W0T + 64 * 64;
    const float* wb = W0T + 65 * 64;
    const float* wc = W0T + 66 * 64;
    float* dst = Dq + (size_t)q * 64;
#pragma unroll
    for (int o = 0; o < 64; o++)
        dst[o] = fmaf(n2, wc[o], fmaf(n1, wb[o], n0 * wa[o]));
}

// ================================================================ MLP stages (R=2)
// S0: gather h0 (E-D) x2 rows -> stats0
__global__ __launch_bounds__(TPB_, 2) void k_s0(
    const float* __restrict__ E, const float* __restrict__ Dq,
    const int* __restrict__ ball, float* __restrict__ partials) {
    const int t = threadIdx.x, lane = t & 63, w = t >> 6;
    const int r0 = blockIdx.x * 512 + t, r1 = r0 + 256;
    __shared__ float ssum[4][64], ssq[4][64];
    float x0[64], x1[64];
    load_h0(x0, E, Dq, ball, r0);
    load_h0(x1, E, Dq, ball, r1);
#pragma unroll
    for (int i = 0; i < 64; i++) {
        const float sv_ = x0[i] + x1[i];
        x1[i] = x0[i] * x0[i] + x1[i] * x1[i];
        x0[i] = sv_;
    }
    const float sv = fold_sum_wave(x0, lane);
    const float qv = fold_sum_wave(x1, lane);
    ssum[w][lane] = sv; ssq[w][lane] = qv;
    __syncthreads();
    if (t < 64) {
        float* dst = partials + (size_t)blockIdx.x * 256;
        dst[t] = ssum[0][t] + ssum[1][t] + ssum[2][t] + ssum[3][t];
        dst[128 + t] = ssq[0][t] + ssq[1][t] + ssq[2][t] + ssq[3][t];
    }
}

// S1: h0 gather, bn0, G1 (R=2, o-tiled) -> h1 store + stats1.  HST 1=f32 2=bf16
template <int HST>
__global__ __launch_bounds__(TPB_, 2) void k_s1(
    const float* __restrict__ E, const float* __restrict__ Dq,
    const int* __restrict__ ball, const float* __restrict__ W1T,
    const float* __restrict__ bnp, float* __restrict__ partials,
    float* __restrict__ h1f, unsigned short* __restrict__ h1h) {
    __shared__ float w1[64 * 64];
    __shared__ float ssum[4][64], ssq[4][64];
    const int t = threadIdx.x, lane = t & 63, w = t >> 6;
    stage_w(w1, W1T, 64 * 64, t);
    const int r0 = blockIdx.x * 512 + t, r1 = r0 + 256;
    float x0[64], x1[64];
    load_h0(x0, E, Dq, ball, r0);
    bn_relu<64>(x0, bnp, 0);
    load_h0(x1, E, Dq, ball, r1);
    bn_relu<64>(x1, bnp, 0);
    __syncthreads();

#pragma unroll
    for (int tile = 0; tile < 2; tile++) {
        float a0[32], a1[32];
#pragma unroll
        for (int o = 0; o < 32; o++) { a0[o] = 0.f; a1[o] = 0.f; }
#pragma unroll
        for (int c = 0; c < 64; c++) {
            const float* wr = w1 + c * 64 + tile * 32;
            const float xc0 = x0[c], xc1 = x1[c];
#pragma unroll
            for (int o = 0; o < 32; o++) {
                a0[o] = fmaf(xc0, wr[o], a0[o]);
                a1[o] = fmaf(xc1, wr[o], a1[o]);
            }
        }
        if constexpr (HST == 1) {
            float4* d0 = (float4*)(h1f + (size_t)r0 * 64 + tile * 32);
            float4* d1 = (float4*)(h1f + (size_t)r1 * 64 + tile * 32);
#pragma unroll
            for (int j = 0; j < 8; j++) {
                d0[j] = make_float4(a0[4 * j], a0[4 * j + 1], a0[4 * j + 2], a0[4 * j + 3]);
                d1[j] = make_float4(a1[4 * j], a1[4 * j + 1], a1[4 * j + 2], a1[4 * j + 3]);
            }
        } else {
            ushort4* d0 = (ushort4*)(h1h + (size_t)r0 * 64 + tile * 32);
            ushort4* d1 = (ushort4*)(h1h + (size_t)r1 * 64 + tile * 32);
#pragma unroll
            for (int j = 0; j < 8; j++) {
                ushort4 v0, v1;
                v0.x = f2bf(a0[4 * j]); v0.y = f2bf(a0[4 * j + 1]);
                v0.z = f2bf(a0[4 * j + 2]); v0.w = f2bf(a0[4 * j + 3]);
                v1.x = f2bf(a1[4 * j]); v1.y = f2bf(a1[4 * j + 1]);
                v1.z = f2bf(a1[4 * j + 2]); v1.w = f2bf(a1[4 * j + 3]);
                d0[j] = v0; d1[j] = v1;
            }
        }
        // stats (raw h1): s->a0, sq->a1
#pragma unroll
        for (int o = 0; o < 32; o++) {
            const float sv_ = a0[o] + a1[o];
            a1[o] = a0[o] * a0[o] + a1[o] * a1[o];
            a0[o] = sv_;
        }
        float sv = fold_sum32(a0, lane); sv += __shfl_xor(sv, 32);
        float qv = fold_sum32(a1, lane); qv += __shfl_xor(qv, 32);
        if (lane < 32) { ssum[w][tile * 32 + lane] = sv; ssq[w][tile * 32 + lane] = qv; }
    }
    __syncthreads();
    if (t < 64) {
        float* dst = partials + (size_t)blockIdx.x * 256;
        dst[t] = ssum[0][t] + ssum[1][t] + ssum[2][t] + ssum[3][t];
        dst[128 + t] = ssq[0][t] + ssq[1][t] + ssq[2][t] + ssq[3][t];
    }
}

// S2: h1 load, bn1, G2 (R=2, o-tiled) -> stats2 + per-(q,ch) raw-h2 max/min.
// The max/min let S3 skip the GEMM2 recompute entirely:
//   max_s relu(fma(h2,sc,sh)) == relu(fma(max_s h2, sc, sh)) for sc>=0 (bitwise;
//   fma is exact-then-round, rounding is monotone), and min_s h2 for sc<0.
template <int HLD>
__global__ __launch_bounds__(TPB_, 2) void k_s2(
    const float* __restrict__ h1f, const unsigned short* __restrict__ h1h,
    const float* __restrict__ W2T, const float* __restrict__ bnp,
    float* __restrict__ partials, float* __restrict__ maxb,
    float* __restrict__ minb) {
    __shared__ float w2[64 * 128];
    __shared__ float ssum[4][128], ssq[4][128];
    const int t = threadIdx.x, lane = t & 63, w = t >> 6;
    stage_w(w2, W2T, 64 * 128, t);
    const int r0 = blockIdx.x * 512 + t, r1 = r0 + 256;
    float x0[64], x1[64];
    if constexpr (HLD == 1) { h1_load_f32(x0, h1f, r0); h1_load_f32(x1, h1f, r1); }
    else { h1_load_bf(x0, h1h, r0); h1_load_bf(x1, h1h, r1); }
    bn_relu<64>(x0, bnp, 256);
    bn_relu<64>(x1, bnp, 256);
    __syncthreads();

    const int q0 = blockIdx.x * 16 + w * 2 + (lane >> 5);
#pragma unroll
    for (int tile = 0; tile < 4; tile++) {
        float a0[32], a1[32];
#pragma unroll
        for (int o = 0; o < 32; o++) { a0[o] = 0.f; a1[o] = 0.f; }
#pragma unroll
        for (int c = 0; c < 64; c++) {
            const float* wr = w2 + c * 128 + tile * 32;
            const float xc0 = x0[c], xc1 = x1[c];
#pragma unroll
            for (int o = 0; o < 32; o++) {
                a0[o] = fmaf(xc0, wr[o], a0[o]);
                a1[o] = fmaf(xc1, wr[o], a1[o]);
            }
        }
        // per-q raw-h2 max & min (folds mutate copies)
        {
            float c0[32];
#pragma unroll
            for (int o = 0; o < 32; o++) c0[o] = a0[o];
            const float mx = fold_max32(c0, lane);
#pragma unroll
            for (int o = 0; o < 32; o++) c0[o] = a0[o];
            const float mn = fold_min32(c0, lane);
            maxb[(size_t)q0 * 128 + tile * 32 + (lane & 31)] = mx;
            minb[(size_t)q0 * 128 + tile * 32 + (lane & 31)] = mn;
#pragma unroll
            for (int o = 0; o < 32; o++) c0[o] = a1[o];
            const float mx1 = fold_max32(c0, lane);
#pragma unroll
            for (int o = 0; o < 32; o++) c0[o] = a1[o];
            const float mn1 = fold_min32(c0, lane);
            maxb[(size_t)(q0 + 8) * 128 + tile * 32 + (lane & 31)] = mx1;
            minb[(size_t)(q0 + 8) * 128 + tile * 32 + (lane & 31)] = mn1;
        }
        // stats
#pragma unroll
        for (int o = 0; o < 32; o++) {
            const float sv_ = a0[o] + a1[o];
            a1[o] = a0[o] * a0[o] + a1[o] * a1[o];
            a0[o] = sv_;
        }
        float sv = fold_sum32(a0, lane); sv += __shfl_xor(sv, 32);
        float qv = fold_sum32(a1, lane); qv += __shfl_xor(qv, 32);
        if (lane < 32) { ssum[w][tile * 32 + lane] = sv; ssq[w][tile * 32 + lane] = qv; }
    }
    __syncthreads();
    if (t < 128) {
        float* dst = partials + (size_t)blockIdx.x * 256;
        dst[t] = ssum[0][t] + ssum[1][t] + ssum[2][t] + ssum[3][t];
        dst[128 + t] = ssq[0][t] + ssq[1][t] + ssq[2][t] + ssq[3][t];
    }
}

// S3: elementwise epilogue from cached max/min (no GEMM recompute)
__global__ __launch_bounds__(256) void k_s3m(
    const float* __restrict__ maxb, const float* __restrict__ minb,
    const float* __restrict__ bnp, float* __restrict__ out_np) {
    const int i = blockIdx.x * 256 + threadIdx.x;   // 0 .. B*M*128-1
    const int ch = i & 127;
    const float sc = bnp[512 + ch], sh = bnp[512 + 128 + ch];
    const float h = (sc >= 0.f) ? maxb[i] : minb[i];
    out_np[i] = fmaxf(0.f, fmaf(h, sc, sh));
}

// ================================================================ fallback (R=1 recompute; known-good)
__device__ __forceinline__ void g0_row(
    const float* __restrict__ points, const float* __restrict__ xyz,
    const float* __restrict__ newxyz, const int* __restrict__ ball,
    const float* w0, int r, float* h0) {
    const int b = r >> 15;
    const int q = r >> 5;
    const int g = ball[r];
    const float* prow = points + ((size_t)(b * N_) + g) * D_;
    const float xg0 = xyz[((size_t)b * N_ + g) * 3 + 0] - newxyz[(size_t)q * 3 + 0];
    const float xg1 = xyz[((size_t)b * N_ + g) * 3 + 1] - newxyz[(size_t)q * 3 + 1];
    const float xg2 = xyz[((size_t)b * N_ + g) * 3 + 2] - newxyz[(size_t)q * 3 + 2];
#pragma unroll
    for (int o = 0; o < 64; o++) h0[o] = 0.f;
#pragma unroll
    for (int c = 0; c < 64; c += 4) {
        const float4 xv = *reinterpret_cast<const float4*>(prow + c);
        const float xs[4] = {xv.x, xv.y, xv.z, xv.w};
#pragma unroll
        for (int j = 0; j < 4; j++) {
            const float xc = xs[j];
            const float* wr = w0 + (c + j) * 64;
#pragma unroll
            for (int o = 0; o < 64; o++) h0[o] = fmaf(xc, wr[o], h0[o]);
        }
    }
#pragma unroll
    for (int o = 0; o < 64; o++) h0[o] = fmaf(xg0, w0[64 * 64 + o], h0[o]);
#pragma unroll
    for (int o = 0; o < 64; o++) h0[o] = fmaf(xg1, w0[65 * 64 + o], h0[o]);
#pragma unroll
    for (int o = 0; o < 64; o++) h0[o] = fmaf(xg2, w0[66 * 64 + o], h0[o]);
}

__device__ __forceinline__ void g1_row(const float* x, const float* w1, float* h1) {
#pragma unroll
    for (int o = 0; o < 64; o++) h1[o] = 0.f;
#pragma unroll
    for (int c = 0; c < 64; c++) {
        const float xc = x[c];
        const float* wr = w1 + c * 64;
#pragma unroll
        for (int o = 0; o < 64; o++) h1[o] = fmaf(xc, wr[o], h1[o]);
    }
}
__device__ __forceinline__ void g2_row(const float* x, const float* w2, float* h2) {
#pragma unroll
    for (int o = 0; o < 128; o++) h2[o] = 0.f;
#pragma unroll
    for (int c = 0; c < 64; c++) {
        const float xc = x[c];
        const float* wr = w2 + c * 128;
#pragma unroll
        for (int o = 0; o < 128; o++) h2[o] = fmaf(xc, wr[o], h2[o]);
    }
}

__device__ __forceinline__ void stats64_fold(float* h, int lane, int w, int t,
                                             float (*ssum)[64], float (*ssq)[64],
                                             float* dst) {
    float tmp[64];
#pragma unroll
    for (int i = 0; i < 64; i++) tmp[i] = h[i] * h[i];
    const float s = fold_sum_wave(h, lane);
    const float q = fold_sum_wave(tmp, lane);
    ssum[w][lane] = s; ssq[w][lane] = q;
    __syncthreads();
    if (t < 64) {
        dst[t] = ssum[0][t] + ssum[1][t] + ssum[2][t] + ssum[3][t];
        dst[128 + t] = ssq[0][t] + ssq[1][t] + ssq[2][t] + ssq[3][t];
    }
}
__device__ __forceinline__ void stats128_fold(float* h2, int lane, int w, int t,
                                              float (*ssum)[128], float (*ssq)[128],
                                              float* dst) {
    float tmp[64];
#pragma unroll
    for (int i = 0; i < 64; i++) tmp[i] = h2[i] * h2[i];
    const float sA = fold_sum_wave(h2, lane);
    const float qA = fold_sum_wave(tmp, lane);
    ssum[w][lane] = sA; ssq[w][lane] = qA;
#pragma unroll
    for (int i = 0; i < 64; i++) tmp[i] = h2[64 + i] * h2[64 + i];
    const float sB = fold_sum_wave(h2 + 64, lane);
    const float qB = fold_sum_wave(tmp, lane);
    ssum[w][64 + lane] = sB; ssq[w][64 + lane] = qB;
    __syncthreads();
    if (t < 128) {
        dst[t] = ssum[0][t] + ssum[1][t] + ssum[2][t] + ssum[3][t];
        dst[128 + t] = ssq[0][t] + ssq[1][t] + ssq[2][t] + ssq[3][t];
    }
}
__device__ __forceinline__ void max_out_r1(float* h2, int lane, int w, int blk,
                                           float* __restrict__ out_np) {
    const int qq = blk * 8 + w * 2 + (lane >> 5);
    float r0, r1;
    fold_max_half(h2, lane, r0, r1);
    out_np[(size_t)qq * 128 + (lane & 31)] = r0;
    out_np[(size_t)qq * 128 + 32 + (lane & 31)] = r1;
    fold_max_half(h2 + 64, lane, r0, r1);
    out_np[(size_t)qq * 128 + 64 + (lane & 31)] = r0;
    out_np[(size_t)qq * 128 + 96 + (lane & 31)] = r1;
}

__global__ __launch_bounds__(TPB_) void k_s0r(
    const float* __restrict__ points, const float* __restrict__ xyz,
    const float* __restrict__ newxyz, const int* __restrict__ ball,
    const float* __restrict__ W0T, float* __restrict__ partials) {
    __shared__ float w0[67 * 64];
    __shared__ float ssum[4][64], ssq[4][64];
    const int t = threadIdx.x, lane = t & 63, w = t >> 6;
    stage_w(w0, W0T, 67 * 64, t);
    __syncthreads();
    const int r = blockIdx.x * TPB_ + t;
    float h0[64];
    g0_row(points, xyz, newxyz, ball, w0, r, h0);
    stats64_fold(h0, lane, w, t, ssum, ssq, partials + (size_t)blockIdx.x * 256);
}
__global__ __launch_bounds__(TPB_) void k_s1r(
    const float* __restrict__ points, const float* __restrict__ xyz,
    const float* __restrict__ newxyz, const int* __restrict__ ball,
    const float* __restrict__ W0T, const float* __restrict__ W1T,
    const float* __restrict__ bnp, float* __restrict__ partials) {
    __shared__ float w0[67 * 64];
    __shared__ float w1[64 * 64];
    __shared__ float ssum[4][64], ssq[4][64];
    const int t = threadIdx.x, lane = t & 63, w = t >> 6;
    stage_w(w0, W0T, 67 * 64, t);
    stage_w(w1, W1T, 64 * 64, t);
    __syncthreads();
    const int r = blockIdx.x * TPB_ + t;
    float h0[64];
    g0_row(points, xyz, newxyz, ball, w0, r, h0);
    bn_relu<64>(h0, bnp, 0);
    float h1[64];
    g1_row(h0, w1, h1);
    stats64_fold(h1, lane, w, t, ssum, ssq, partials + (size_t)blockIdx.x * 256);
}
__global__ __launch_bounds__(TPB_) void k_s2r(
    const float* __restrict__ points, const float* __restrict__ xyz,
    const float* __restrict__ newxyz, const int* __restrict__ ball,
    const float* __restrict__ W0T, const float* __restrict__ W1T,
    const float* __restrict__ W2T, const float* __restrict__ bnp,
    float* __restrict__ partials) {
    __shared__ float w0[67 * 64];
    __shared__ float w1[64 * 64];
    __shared__ float w2[64 * 128];
    __shared__ float ssum[4][128], ssq[4][128];
    const int t = threadIdx.x, lane = t & 63, w = t >> 6;
    stage_w(w0, W0T, 67 * 64, t);
    stage_w(w1, W1T, 64 * 64, t);
    stage_w(w2, W2T, 64 * 128, t);
    __syncthreads();
    const int r = blockIdx.x * TPB_ + t;
    float h0[64];
    g0_row(points, xyz, newxyz, ball, w0, r, h0);
    bn_relu<64>(h0, bnp, 0);
    float h1[64];
    g1_row(h0, w1, h1);
    bn_relu<64>(h1, bnp, 256);
    float h2[128];
    g2_row(h1, w2, h2);
    stats128_fold(h2, lane, w, t, ssum, ssq, partials + (size_t)blockIdx.x * 256);
}
__global__ __launch_bounds__(TPB_) void k_s3r(
    const float* __restrict__ points, const float* __restrict__ xyz,
    const float* __restrict__ newxyz, const int* __restrict__ ball,
    const float* __restrict__ W0T, const float* __restrict__ W1T,
    const float* __restrict__ W2T, const float* __restrict__ bnp,
    float* __restrict__ out_np) {
    __shared__ float w0[67 * 64];
    __shared__ float w1[64 * 64];
    __shared__ float w2[64 * 128];
    const int t = threadIdx.x, lane = t & 63, w = t >> 6;
    stage_w(w0, W0T, 67 * 64, t);
    stage_w(w1, W1T, 64 * 64, t);
    stage_w(w2, W2T, 64 * 128, t);
    __syncthreads();
    const int r = blockIdx.x * TPB_ + t;
    float h0[64];
    g0_row(points, xyz, newxyz, ball, w0, r, h0);
    bn_relu<64>(h0, bnp, 0);
    float h1[64];
    g1_row(h0, w1, h1);
    bn_relu<64>(h1, bnp, 256);
    float h2[128];
    g2_row(h1, w2, h2);
    bn_relu<128>(h2, bnp, 512);
    max_out_r1(h2, lane, w, blockIdx.x, out_np);
}

// ---------------------------------------------------------------- BN finalize
template <int C, int NB>
__global__ __launch_bounds__(128) void k_bnfin(const float* __restrict__ partials,
                                               const float* __restrict__ gw,
                                               const float* __restrict__ bw,
                                               float* __restrict__ bnpL) {
    const int t = threadIdx.x;
    if (t >= C) return;
    double Ssum = 0.0, Q = 0.0;
    for (int blk = 0; blk < NB; blk++) {
        Ssum += (double)partials[(size_t)blk * 256 + t];
        Q += (double)partials[(size_t)blk * 256 + 128 + t];
    }
    const double mean = Ssum / (double)NROWS_;
    const double var = Q / (double)NROWS_ - mean * mean;
    const float sc = (float)((double)gw[t] / sqrt(var + 1e-5));
    const float sh = (float)((double)bw[t] - mean * (double)sc);
    bnpL[t] = sc;
    bnpL[128 + t] = sh;
}

// ---------------------------------------------------------------- launch
extern "C" void kernel_launch(void* const* d_in, const int* in_sizes, int n_in,
                              void* d_out, int out_size, void* d_ws, size_t ws_size,
                              hipStream_t stream) {
    const float* xyz = (const float*)d_in[0];
    const float* points = (const float*)d_in[1];
    const float* W0 = (const float*)d_in[2];
    const float* g0 = (const float*)d_in[3];
    const float* b0 = (const float*)d_in[4];
    const float* W1 = (const float*)d_in[5];
    const float* g1 = (const float*)d_in[6];
    const float* b1 = (const float*)d_in[7];
    const float* W2 = (const float*)d_in[8];
    const float* g2 = (const float*)d_in[9];
    const float* b2 = (const float*)d_in[10];

    float* out = (float*)d_out;
    float* newxyz = out;
    float* out_np = out + B_ * M_ * 3;

    char* ws = (char*)d_ws;
    float* sqn = (float*)(ws + OFF_SQN);
    int* fps_idx = (int*)(ws + OFF_FPS);
    int* ball = (int*)(ws + OFF_BALL);
    float* W0T = (float*)(ws + OFF_W0T);
    float* W1T = (float*)(ws + OFF_W1T);
    float* W2T = (float*)(ws + OFF_W2T);
    float* partials = (float*)(ws + OFF_PART);
    float* bnp = (float*)(ws + OFF_BNP);
    float* Ebuf = (float*)(ws + OFF_E);
    float* Dbuf = (float*)(ws + OFF_D);
    float* h1f = (float*)(ws + OFF_H1);
    unsigned short* h1h = (unsigned short*)(ws + OFF_H1);
    // E is dead after k_s1 -> reuse its space for h2 max/min (8 MB each)
    float* maxb = (float*)(ws + OFF_E);
    float* minb = maxb + (size_t)B_ * M_ * 128;

    k_sqnorm<<<(B_ * N_ + 255) / 256, 256, 0, stream>>>(xyz, sqn);
    k_fps<<<B_, 512, 0, stream>>>(xyz, fps_idx);
    k_newxyz<<<(B_ * M_ + 255) / 256, 256, 0, stream>>>(xyz, fps_idx, newxyz);
    k_ball<<<B_ * M_ / 4, 256, 0, stream>>>(xyz, sqn, fps_idx, newxyz, ball);
    k_wtrans<<<32, 256, 0, stream>>>(W0, W1, W2, W0T, W1T, W2T);

    if (ws_size >= NEED_B) {
        k_e<<<B_ * N_ / TPB_, TPB_, 0, stream>>>(points, xyz, W0T, Ebuf);
        k_d<<<B_ * M_ / 256, 256, 0, stream>>>(newxyz, W0T, Dbuf);
        k_s0<<<NBLK2_, TPB_, 0, stream>>>(Ebuf, Dbuf, ball, partials);
        k_bnfin<64, NBLK2_><<<1, 128, 0, stream>>>(partials, g0, b0, bnp);
        if (ws_size >= NEED_A) {
            k_s1<1><<<NBLK2_, TPB_, 0, stream>>>(Ebuf, Dbuf, ball, W1T, bnp, partials, h1f, h1h);
            k_bnfin<64, NBLK2_><<<1, 128, 0, stream>>>(partials, g1, b1, bnp + 256);
            k_s2<1><<<NBLK2_, TPB_, 0, stream>>>(h1f, h1h, W2T, bnp, partials, maxb, minb);
            k_bnfin<128, NBLK2_><<<1, 128, 0, stream>>>(partials, g2, b2, bnp + 512);
            k_s3m<<<B_ * M_ * 128 / 256, 256, 0, stream>>>(maxb, minb, bnp, out_np);
        } else {
            k_s1<2><<<NBLK2_, TPB_, 0, stream>>>(Ebuf, Dbuf, ball, W1T, bnp, partials, h1f, h1h);
            k_bnfin<64, NBLK2_><<<1, 128, 0, stream>>>(partials, g1, b1, bnp + 256);
            k_s2<2><<<NBLK2_, TPB_, 0, stream>>>(h1f, h1h, W2T, bnp, partials, maxb, minb);
            k_bnfin<128, NBLK2_><<<1, 128, 0, stream>>>(partials, g2, b2, bnp + 512);
            k_s3m<<<B_ * M_ * 128 / 256, 256, 0, stream>>>(maxb, minb, bnp, out_np);
        }
    } else {
        // recompute fallback (R=1, known-good)
        k_s0r<<<NBLKM_, TPB_, 0, stream>>>(points, xyz, newxyz, ball, W0T, partials);
        k_bnfin<64, NBLKM_><<<1, 128, 0, stream>>>(partials, g0, b0, bnp);
        k_s1r<<<NBLKM_, TPB_, 0, stream>>>(points, xyz, newxyz, ball, W0T, W1T, bnp, partials);
        k_bnfin<64, NBLKM_><<<1, 128, 0, stream>>>(partials, g1, b1, bnp + 256);
        k_s2r<<<NBLKM_, TPB_, 0, stream>>>(points, xyz, newxyz, ball, W0T, W1T, W2T, bnp, partials);
        k_bnfin<128, NBLKM_><<<1, 128, 0, stream>>>(partials, g2, b2, bnp + 512);
        k_s3r<<<NBLKM_, TPB_, 0, stream>>>(points, xyz, newxyz, ball, W0T, W1T, W2T, bnp, out_np);
    }
}